// Round 9
// baseline (453.970 us; speedup 1.0000x reference)
//
#include <hip/hip_runtime.h>
#include <math.h>

// Problem constants
#define B_ 4
#define T_ 256
#define N_ 8
#define D_ 128
#define NH_ 4
#define HD_ 32
#define LENC_ 2
#define MLPH_ 32
#define NL_SCALE_ 0.1f

typedef __bf16 bf16;
typedef __attribute__((ext_vector_type(2))) __bf16 bf16x2;
typedef __attribute__((ext_vector_type(4))) __bf16 bf16x4;
typedef __attribute__((ext_vector_type(8))) __bf16 bf16x8;
typedef __attribute__((ext_vector_type(4))) float f32x4;

#if __has_builtin(__builtin_amdgcn_mfma_f32_16x16x16_bf16) || \
    __has_builtin(__builtin_amdgcn_mfma_f32_16x16x16bf16_1k)
#define HAVE_MFMA16 1
#else
#define HAVE_MFMA16 0
#endif

#if HAVE_MFMA16
__device__ __forceinline__ f32x4 pv_mfma16(bf16x4 a, bf16x4 b, f32x4 c) {
#if __has_builtin(__builtin_amdgcn_mfma_f32_16x16x16_bf16)
    return __builtin_amdgcn_mfma_f32_16x16x16_bf16(a, b, c, 0, 0, 0);
#else
    typedef __attribute__((ext_vector_type(4))) short s4;
    union U { bf16x4 h; s4 s; };
    U ua, ub; ua.h = a; ub.h = b;
    return __builtin_amdgcn_mfma_f32_16x16x16bf16_1k(ua.s, ub.s, c, 0, 0, 0);
#endif
}
#endif

__device__ __forceinline__ float gelu_f(float x) {
    return 0.5f * x * (1.0f + erff(x * 0.7071067811865476f));
}

// ---------------------------------------------------------------------------
// Merged prep: weight pack fp32->bf16, state_emb->bf16, bias pack.
__global__ void k_prep(const float* __restrict__ eqkvW, const float* __restrict__ eoutW,
                       const float* __restrict__ eff1, const float* __restrict__ eff2,
                       const float* __restrict__ wq, const float* __restrict__ wk,
                       const float* __restrict__ wv, const float* __restrict__ wo,
                       const float* __restrict__ cff1, const float* __restrict__ cff2,
                       const float* __restrict__ mlpW2, const float* __restrict__ semb,
                       const float* __restrict__ bk, const float* __restrict__ bv,
                       bf16* __restrict__ Wpk, bf16* __restrict__ sembh,
                       float* __restrict__ bpk) {
    int i = blockIdx.x * 256 + threadIdx.x;
    if (i < 540672) {
        const float* src; int off;
        if      (i < 98304)  { src = eqkvW; off = 0; }
        else if (i < 131072) { src = eoutW; off = 98304; }
        else if (i < 196608) { src = eff1;  off = 131072; }
        else if (i < 262144) { src = eff2;  off = 196608; }
        else if (i < 278528) { src = wq;    off = 262144; }
        else if (i < 294912) { src = wk;    off = 278528; }
        else if (i < 311296) { src = wv;    off = 294912; }
        else if (i < 327680) { src = wo;    off = 311296; }
        else if (i < 458752) { src = cff1;  off = 327680; }
        else if (i < 524288) { src = cff2;  off = 458752; }
        else                 { src = mlpW2; off = 524288; }
        Wpk[i] = (bf16)src[i - off];
    } else if (i < 540672 + 1048576) {
        int j = i - 540672;
        sembh[j] = (bf16)semb[j];
    } else if (i < 540672 + 1048576 + 256) {
        int t = i - 540672 - 1048576;
        bpk[t] = (t < 128) ? bk[t] : bv[t - 128];
    }
}

// ---------------------------------------------------------------------------
// K1: b1[b,t,m], t in [0,T-1)
__global__ void k_b1(const float* __restrict__ vs, const float* __restrict__ r5,
                     const float* __restrict__ A55, const float* __restrict__ bl_bias,
                     const float* __restrict__ nlW1, const float* __restrict__ nlb1,
                     const float* __restrict__ nlW2, const float* __restrict__ nlb2,
                     float* __restrict__ b1w) {
    int idx = blockIdx.x * blockDim.x + threadIdx.x;
    if (idx >= B_ * (T_ - 1)) return;
    int b = idx / (T_ - 1), t = idx % (T_ - 1);
    float x[N_];
    for (int n = 0; n < N_; n++) x[n] = vs[(b * T_ + t) * N_ + n];
    float h[MLPH_];
    for (int j = 0; j < MLPH_; j++) {
        float a = nlb1[j];
        for (int n = 0; n < N_; n++) a += x[n] * nlW1[j * N_ + n];
        h[j] = gelu_f(a);
    }
    for (int m = 0; m < N_; m++) {
        float lin = r5[m];
        for (int n = 0; n < N_; n++) lin += x[n] * A55[m * N_ + n];
        float nl = nlb2[m];
        for (int j = 0; j < MLPH_; j++) nl += h[j] * nlW2[m * MLPH_ + j];
        b1w[idx * N_ + m] = lin + NL_SCALE_ * nl + bl_bias[m];
    }
}

// ---------------------------------------------------------------------------
// K2: residuals[b,t,n,si] for SCALES = {1,2,3,5}
__global__ void k_resid(const float* __restrict__ vs, const float* __restrict__ b1w,
                        float* __restrict__ resid) {
    int idx = blockIdx.x * blockDim.x + threadIdx.x;
    if (idx >= B_ * T_ * N_) return;
    int b = idx / (T_ * N_);
    int t = (idx / N_) % T_;
    int n = idx % N_;
    const int SC[4] = {1, 2, 3, 5};
    float lx0 = logf(fmaxf(vs[(b * T_ + t) * N_ + n], 1e-6f));
    for (int si = 0; si < 4; si++) {
        int k = SC[si];
        float r = 0.0f;
        if (t < T_ - k) {
            float lx1 = logf(fmaxf(vs[(b * T_ + t + k) * N_ + n], 1e-6f));
            float a = lx1 - lx0;
            float cmin = -2.5f * (float)k, cmax = 2.0f * (float)k;
            a = fminf(fmaxf(a, cmin), cmax);
            float bk = 0.0f;
            for (int i = 0; i < k; i++) bk += b1w[(b * (T_ - 1) + t + i) * N_ + n];
            r = a - bk;
        }
        resid[idx * 4 + si] = r;
    }
}

// ---------------------------------------------------------------------------
// K3a: per-token MLP layer1 (16 -> 128, gelu), output bf16 in (b,t,n) order.
__global__ void k_mlp1(const float* __restrict__ resid, const float* __restrict__ W1,
                       const float* __restrict__ b1, bf16* __restrict__ H1h) {
    int tok = blockIdx.x;                  // b*2048 + t*8 + n
    int d = threadIdx.x;                   // 128
    int b = tok >> 11, t = (tok >> 3) & 255, n = tok & 7;
    __shared__ float f[16];
    if (d < 16) {
        int g = d >> 2, si = d & 3;
        f[d] = (t - g >= 0) ? resid[((b * T_ + (t - g)) * N_ + n) * 4 + si] : 0.0f;
    }
    __syncthreads();
    float a = b1[d];
    const float* w = W1 + d * 16;
#pragma unroll
    for (int c = 0; c < 16; c++) a += f[c] * w[c];
    H1h[(size_t)tok * 128 + d] = (bf16)gelu_f(a);
}

// ---------------------------------------------------------------------------
// MFMA GEMM: C[M x N] = act(A @ W^T + bias). A bf16 [MxK] rowmajor,
// W bf16 [NxK] rowmajor. One 16x16 C tile per wave; 4 waves/block.
// mode 0: row-major write (Cf fp32 / Ch bf16).
// mode 1 (enc QKV, N=384): scatter to Qh/Kh [sh][256][32], Vth [sh][32][256].
// mode 2 (cross Q, N=128): scatter to Qh [sh][2048][32].
// mode 3 (cross KV, N=256): scatter K->Kh [sh][2048][32], V->Vth [sh][32][2048],
//         with l = t*8+n remap from xt row order.
__global__ __launch_bounds__(256) void k_gemm(
    const bf16* __restrict__ A, const bf16* __restrict__ W,
    const float* __restrict__ bias, float* __restrict__ Cf,
    bf16* __restrict__ Ch, bf16* __restrict__ dq, bf16* __restrict__ dk,
    bf16* __restrict__ dvv, int M, int N, int K, int act, int mode) {
    int lane = threadIdx.x & 63;
    int wv = threadIdx.x >> 6;
    int wtile = blockIdx.x * 4 + wv;
    int nN = N >> 4;
    int tn = wtile % nN, tm = wtile / nN;
    if (tm >= (M >> 4)) return;
    int mrow = tm * 16 + (lane & 15);
    int nrow = tn * 16 + (lane & 15);
    int g = lane >> 4;
    const bf16x8* Ap = (const bf16x8*)(A + (size_t)mrow * K) + g;
    const bf16x8* Wp = (const bf16x8*)(W + (size_t)nrow * K) + g;
    f32x4 acc = {0.0f, 0.0f, 0.0f, 0.0f};
    int nk = K >> 5;
    for (int k = 0; k < nk; k++) {
        bf16x8 av = Ap[k * 4];
        bf16x8 bv8 = Wp[k * 4];
        acc = __builtin_amdgcn_mfma_f32_16x16x32_bf16(av, bv8, acc, 0, 0, 0);
    }
    int col = tn * 16 + (lane & 15);
    int row0 = tm * 16 + g * 4;
    float bvv = bias[col];
#pragma unroll
    for (int i = 0; i < 4; i++) {
        float v = acc[i] + bvv;
        if (act) v = gelu_f(v);
        int row = row0 + i;
        if (mode == 0) {
            if (Cf) Cf[(size_t)row * N + col] = v;
            if (Ch) Ch[(size_t)row * N + col] = (bf16)v;
        } else if (mode == 1) {
            int s = row >> 8, t = row & 255;
            int h = (col >> 5) & 3, d = col & 31;
            int sh = s * 4 + h;
            if (col < 128)      dq[((size_t)sh * 256 + t) * 32 + d] = (bf16)v;
            else if (col < 256) dk[((size_t)sh * 256 + t) * 32 + d] = (bf16)v;
            else                dvv[((size_t)sh * 32 + d) * 256 + t] = (bf16)v;
        } else if (mode == 2) {
            int b = row >> 11, ll = row & 2047;
            int h = col >> 5, d = col & 31;
            dq[((size_t)(b * 4 + h) * 2048 + ll) * 32 + d] = (bf16)v;
        } else {
            int b = row >> 11, n = (row >> 8) & 7, t = row & 255;
            int ll = t * 8 + n;
            int h = (col >> 5) & 3, d = col & 31;
            if (col < 128) dk[((size_t)(b * 4 + h) * 2048 + ll) * 32 + d] = (bf16)v;
            else           dvv[((size_t)(b * 4 + h) * 32 + d) * 2048 + ll] = (bf16)v;
        }
    }
}

// ---------------------------------------------------------------------------
// Fused GEMM(N=128) + [gelu] + [residual] + LayerNorm + [PE] + writes.
// flags: 1=gelu-before-LN, 2=add-PE-after-LN, 4=transpose-out-row (xt order).
__global__ __launch_bounds__(256) void k_gemm_ln(
    const bf16* __restrict__ A, const bf16* __restrict__ W,
    const float* __restrict__ bias, int K,
    const float* __restrict__ resf,
    const float* __restrict__ g, const float* __restrict__ be,
    float* __restrict__ outf, bf16* __restrict__ outh, int hs,
    const bf16* __restrict__ catsrc, int flags) {
    __shared__ float S[32][132];
    int tid = threadIdx.x;
    int w = tid >> 6, lane = tid & 63;
    int c = lane & 15, gq = lane >> 4;
    int r0 = blockIdx.x * 32 + (w >> 1) * 16;
    int cb = (w & 1) * 64;

    const bf16x8* Ap  = (const bf16x8*)(A + (size_t)(r0 + c) * K) + gq;
    const bf16x8* Wp0 = (const bf16x8*)(W + (size_t)(cb + c) * K) + gq;
    const bf16x8* Wp1 = (const bf16x8*)(W + (size_t)(cb + 16 + c) * K) + gq;
    const bf16x8* Wp2 = (const bf16x8*)(W + (size_t)(cb + 32 + c) * K) + gq;
    const bf16x8* Wp3 = (const bf16x8*)(W + (size_t)(cb + 48 + c) * K) + gq;
    f32x4 a0 = {0, 0, 0, 0}, a1 = {0, 0, 0, 0};
    f32x4 a2 = {0, 0, 0, 0}, a3 = {0, 0, 0, 0};
    int nk = K >> 5;
    for (int k = 0; k < nk; k++) {
        bf16x8 av = Ap[k * 4];
        a0 = __builtin_amdgcn_mfma_f32_16x16x32_bf16(av, Wp0[k * 4], a0, 0, 0, 0);
        a1 = __builtin_amdgcn_mfma_f32_16x16x32_bf16(av, Wp1[k * 4], a1, 0, 0, 0);
        a2 = __builtin_amdgcn_mfma_f32_16x16x32_bf16(av, Wp2[k * 4], a2, 0, 0, 0);
        a3 = __builtin_amdgcn_mfma_f32_16x16x32_bf16(av, Wp3[k * 4], a3, 0, 0, 0);
    }
    int lrow = (w >> 1) * 16 + gq * 4;
    float b0 = bias[cb + c], b1v = bias[cb + 16 + c];
    float b2v = bias[cb + 32 + c], b3v = bias[cb + 48 + c];
#pragma unroll
    for (int r = 0; r < 4; r++) {
        float v0 = a0[r] + b0, v1 = a1[r] + b1v;
        float v2 = a2[r] + b2v, v3 = a3[r] + b3v;
        if (flags & 1) {
            v0 = gelu_f(v0); v1 = gelu_f(v1); v2 = gelu_f(v2); v3 = gelu_f(v3);
        }
        S[lrow + r][cb + c] = v0;       S[lrow + r][cb + 16 + c] = v1;
        S[lrow + r][cb + 32 + c] = v2;  S[lrow + r][cb + 48 + c] = v3;
    }
    __syncthreads();

    int row = tid >> 3, cg = tid & 7;          // 32 rows x 8 col-groups of 16
    int grow = blockIdx.x * 32 + row;
    int b = grow >> 11, t = (grow >> 3) & 255, n = grow & 7;
    int orow = (flags & 4) ? ((b * 8 + n) * 256 + t) : grow;
    float v[16];
#pragma unroll
    for (int j = 0; j < 16; j++) v[j] = S[row][cg * 16 + j];
    if (resf) {
        const float4* rp = (const float4*)(resf + (size_t)grow * 128 + cg * 16);
#pragma unroll
        for (int j4 = 0; j4 < 4; j4++) {
            float4 rv = rp[j4];
            v[4 * j4 + 0] += rv.x; v[4 * j4 + 1] += rv.y;
            v[4 * j4 + 2] += rv.z; v[4 * j4 + 3] += rv.w;
        }
    }
    float s = 0.0f;
#pragma unroll
    for (int j = 0; j < 16; j++) s += v[j];
    s += __shfl_xor(s, 1); s += __shfl_xor(s, 2); s += __shfl_xor(s, 4);
    float mean = s * (1.0f / 128.0f);
    float vs = 0.0f;
#pragma unroll
    for (int j = 0; j < 16; j++) { float d = v[j] - mean; vs += d * d; }
    vs += __shfl_xor(vs, 1); vs += __shfl_xor(vs, 2); vs += __shfl_xor(vs, 4);
    float rstd = rsqrtf(vs * (1.0f / 128.0f) + 1e-5f);
    float y[16];
#pragma unroll
    for (int j = 0; j < 16; j++) {
        int col = cg * 16 + j;
        y[j] = (v[j] - mean) * rstd * g[col] + be[col];
    }
    if (flags & 2) {                    // sinusoidal PE, added after LN
#pragma unroll
        for (int jj = 0; jj < 8; jj++) {
            int j2 = cg * 8 + jj;       // pair index = col>>1
            float freq = expf((float)(2 * j2) * (-9.210340371976184f / 128.0f));
            float ang = (float)t * freq;
            y[2 * jj] += sinf(ang);
            y[2 * jj + 1] += cosf(ang);
        }
    }
    if (outf) {
        float4* op = (float4*)(outf + (size_t)orow * 128 + cg * 16);
#pragma unroll
        for (int j4 = 0; j4 < 4; j4++) {
            float4 o; o.x = y[4 * j4]; o.y = y[4 * j4 + 1];
            o.z = y[4 * j4 + 2]; o.w = y[4 * j4 + 3];
            op[j4] = o;
        }
    }
    if (outh) {
        bf16x8* op = (bf16x8*)(outh + (size_t)orow * hs + cg * 16);
#pragma unroll
        for (int j8 = 0; j8 < 2; j8++) {
            bf16x8 o;
#pragma unroll
            for (int e = 0; e < 8; e++) o[e] = (bf16)y[8 * j8 + e];
            op[j8] = o;
        }
        if (catsrc) {                   // fill CAT[:,128:256] from xt order
            const bf16x8* cp = (const bf16x8*)(
                catsrc + ((size_t)(b * 8 + n) * 256 + t) * 128 + cg * 16);
            bf16x8* dp = (bf16x8*)(outh + (size_t)orow * 256 + 128 + cg * 16);
            dp[0] = cp[0]; dp[1] = cp[1];
        }
    }
}

// ---------------------------------------------------------------------------
// MFMA flash attention v5: chain-free, LDS-free.
// S^T = K·Q^T via 16x16x32 (A=K rows, B=Q rows): lane (c,g) gets
// S^T[key=g*4+r][q=c] — after exp this IS the 16x16x16 B-fragment
// (B[k=g*4+j][n=c]), so PV runs as O^T = V^T·P^T with V A-frags straight
// from Vth [sh][32][Lk]. No cross-lane transform, no LDS, no running max
// (scores bounded << 88). XCD swizzle: sh = bid % NSH.
// grid = NSH * (Lq/64); 4 waves/block, wave = 16 queries.
// Output ATTh[((sh>>2)*Lq + q)*128 + (sh&3)*32 + d] (bf16).
__global__ __launch_bounds__(256) void k_mattn(
    const bf16* __restrict__ Qh, const bf16* __restrict__ Kh,
    const bf16* __restrict__ Vth, bf16* __restrict__ ATTh,
    int Lq, int Lk, int NSH) {
    int sh = blockIdx.x % NSH;
    int qblk = blockIdx.x / NSH;
    int wv = threadIdx.x >> 6;
    int lane = threadIdx.x & 63;
    int c = lane & 15, g = lane >> 4;
    int q0 = qblk * 64 + wv * 16;

    const float scale = 0.17677669529663687f;  // 1/sqrt(32)
    const f32x4 zero = {0, 0, 0, 0};
    // Q B-frag: n=q=c, k=dim=g*8+j
    bf16x8 bq = *(const bf16x8*)(Qh + ((size_t)sh * Lq + q0 + c) * 32 + g * 8);
    const bf16* Kbase = Kh + (size_t)sh * Lk * 32;
    const bf16* Vbase = Vth + (size_t)sh * 32 * Lk;

#if HAVE_MFMA16
    f32x4 oT0 = {0, 0, 0, 0}, oT1 = {0, 0, 0, 0};  // O^T[d][q=c], d-tiles 0/1
    float lsum = 0.0f;
    int ntiles = Lk >> 5;
    // prefetch tile 0: K A-frags (keys c, 16+c), V A-frags (d=c, 16+c)
    bf16x8 ka = *(const bf16x8*)(Kbase + (size_t)c * 32 + g * 8);
    bf16x8 kb = *(const bf16x8*)(Kbase + (size_t)(16 + c) * 32 + g * 8);
    bf16x4 va0 = *(const bf16x4*)(Vbase + (size_t)c * Lk + g * 4);
    bf16x4 va1 = *(const bf16x4*)(Vbase + (size_t)c * Lk + 16 + g * 4);
    bf16x4 vb0 = *(const bf16x4*)(Vbase + (size_t)(16 + c) * Lk + g * 4);
    bf16x4 vb1 = *(const bf16x4*)(Vbase + (size_t)(16 + c) * Lk + 16 + g * 4);

    for (int t = 0; t < ntiles; t++) {
        bf16x8 cka = ka, ckb = kb;
        bf16x4 cva0 = va0, cva1 = va1, cvb0 = vb0, cvb1 = vb1;
        int nk0 = ((t + 1 < ntiles) ? (t + 1) : t) << 5;
        ka = *(const bf16x8*)(Kbase + (size_t)(nk0 + c) * 32 + g * 8);
        kb = *(const bf16x8*)(Kbase + (size_t)(nk0 + 16 + c) * 32 + g * 8);
        va0 = *(const bf16x4*)(Vbase + (size_t)c * Lk + nk0 + g * 4);
        va1 = *(const bf16x4*)(Vbase + (size_t)c * Lk + nk0 + 16 + g * 4);
        vb0 = *(const bf16x4*)(Vbase + (size_t)(16 + c) * Lk + nk0 + g * 4);
        vb1 = *(const bf16x4*)(Vbase + (size_t)(16 + c) * Lk + nk0 + 16 + g * 4);

        // S^T sub-tiles: keys 0-15 (s0), 16-31 (s1); row=key=g*4+r, col=q=c
        f32x4 s0 = __builtin_amdgcn_mfma_f32_16x16x32_bf16(cka, bq, zero, 0, 0, 0);
        f32x4 s1 = __builtin_amdgcn_mfma_f32_16x16x32_bf16(ckb, bq, zero, 0, 0, 0);
        bf16x4 p0, p1;
#pragma unroll
        for (int r = 0; r < 4; r++) {
            float e0 = __expf(s0[r] * scale);
            float e1 = __expf(s1[r] * scale);
            lsum += e0 + e1;
            p0[r] = (bf16)e0;
            p1[r] = (bf16)e1;
        }
        // O^T += V^T · P^T  (16x16x16: A k=g*4+j keys, B n=c=q)
        oT0 = pv_mfma16(cva0, p0, oT0);
        oT0 = pv_mfma16(cva1, p1, oT0);
        oT1 = pv_mfma16(cvb0, p0, oT1);
        oT1 = pv_mfma16(cvb1, p1, oT1);
    }
    // lsum is partial over this lane's keys for q=c; reduce across quads
    lsum += __shfl_xor(lsum, 16);
    lsum += __shfl_xor(lsum, 32);
    float inv = 1.0f / lsum;
    int h = sh & 3, sb = sh >> 2;
    size_t rowoff = ((size_t)sb * Lq + q0 + c) * 128 + h * 32;
    bf16x4 w0, w1;
#pragma unroll
    for (int r = 0; r < 4; r++) {
        w0[r] = (bf16)(oT0[r] * inv);   // d = g*4+r
        w1[r] = (bf16)(oT1[r] * inv);   // d = 16+g*4+r
    }
    *(bf16x4*)(ATTh + rowoff + g * 4) = w0;
    *(bf16x4*)(ATTh + rowoff + 16 + g * 4) = w1;
#else
    // Fallback: R8-proven LDS round-trip path.
    __shared__ __align__(16) bf16x2 P_lds[2][4][16][20];
    f32x4 o0 = {0, 0, 0, 0}, o1 = {0, 0, 0, 0};
    float l[4] = {0, 0, 0, 0};
    int ntiles = Lk >> 5;
    bf16x8 ka = *(const bf16x8*)(Kbase + (size_t)(2 * c) * 32 + g * 8);
    bf16x8 kb = *(const bf16x8*)(Kbase + (size_t)(2 * c + 1) * 32 + g * 8);
    bf16x8 va = *(const bf16x8*)(Vbase + (size_t)c * Lk + g * 8);
    bf16x8 vb = *(const bf16x8*)(Vbase + (size_t)(16 + c) * Lk + g * 8);
    for (int t = 0; t < ntiles; t++) {
        bf16x8 cka = ka, ckb = kb, cva = va, cvb = vb;
        int nk0 = ((t + 1 < ntiles) ? (t + 1) : t) << 5;
        ka = *(const bf16x8*)(Kbase + (size_t)(nk0 + 2 * c) * 32 + g * 8);
        kb = *(const bf16x8*)(Kbase + (size_t)(nk0 + 2 * c + 1) * 32 + g * 8);
        va = *(const bf16x8*)(Vbase + (size_t)c * Lk + nk0 + g * 8);
        vb = *(const bf16x8*)(Vbase + (size_t)(16 + c) * Lk + nk0 + g * 8);
        f32x4 s0 = __builtin_amdgcn_mfma_f32_16x16x32_bf16(bq, cka, zero, 0, 0, 0);
        f32x4 s1 = __builtin_amdgcn_mfma_f32_16x16x32_bf16(bq, ckb, zero, 0, 0, 0);
        int buf = t & 1;
#pragma unroll
        for (int r = 0; r < 4; r++) {
            float e0 = __expf(s0[r] * scale);
            float e1 = __expf(s1[r] * scale);
            l[r] += e0 + e1;
            bf16x2 pk; pk[0] = (bf16)e0; pk[1] = (bf16)e1;
            P_lds[buf][wv][g * 4 + r][c] = pk;
        }
        bf16x8 ap = *(const bf16x8*)&P_lds[buf][wv][c][g * 4];
        o0 = __builtin_amdgcn_mfma_f32_16x16x32_bf16(ap, cva, o0, 0, 0, 0);
        o1 = __builtin_amdgcn_mfma_f32_16x16x32_bf16(ap, cvb, o1, 0, 0, 0);
    }
#pragma unroll
    for (int r = 0; r < 4; r++) {
        float s = l[r];
        s += __shfl_xor(s, 1); s += __shfl_xor(s, 2);
        s += __shfl_xor(s, 4); s += __shfl_xor(s, 8);
        l[r] = 1.0f / s;
    }
    int h = sh & 3, sb = sh >> 2;
#pragma unroll
    for (int r = 0; r < 4; r++) {
        size_t row = (size_t)sb * Lq + q0 + g * 4 + r;
        ATTh[row * 128 + h * 32 + c] = (bf16)(o0[r] * l[r]);
        ATTh[row * 128 + h * 32 + 16 + c] = (bf16)(o1[r] * l[r]);
    }
#endif
}

// ---------------------------------------------------------------------------
extern "C" void kernel_launch(void* const* d_in, const int* in_sizes, int n_in,
                              void* d_out, int out_size, void* d_ws, size_t ws_size,
                              hipStream_t stream) {
    const float* vs       = (const float*)d_in[0];
    const float* semb     = (const float*)d_in[1];
    const float* r5       = (const float*)d_in[2];
    const float* A55      = (const float*)d_in[3];
    const float* bl_bias  = (const float*)d_in[4];
    const float* nl_W1    = (const float*)d_in[5];
    const float* nl_b1    = (const float*)d_in[6];
    const float* nl_W2    = (const float*)d_in[7];
    const float* nl_b2    = (const float*)d_in[8];
    const float* mlp_W1   = (const float*)d_in[9];
    const float* mlp_b1   = (const float*)d_in[10];
    const float* mlp_W2   = (const float*)d_in[11];
    const float* mlp_b2   = (const float*)d_in[12];
    const float* mlp_ln_g = (const float*)d_in[13];
    const float* mlp_ln_b = (const float*)d_in[14];
    const float* enc_qkv_W = (const float*)d_in[15];
    const float* enc_qkv_b = (const float*)d_in[16];
    const float* enc_out_W = (const float*)d_in[17];
    const float* enc_out_b = (const float*)d_in[18];
    const float* enc_ln1_g = (const float*)d_in[19];
    const float* enc_ln1_b = (const float*)d_in[20];
    const float* enc_ff_W1 = (const float*)d_in[21];
    const float* enc_ff_b1 = (const float*)d_in[22];
    const float* enc_ff_W2 = (const float*)d_in[23];
    const float* enc_ff_b2 = (const float*)d_in[24];
    const float* enc_ln2_g = (const float*)d_in[25];
    const float* enc_ln2_b = (const float*)d_in[26];
    const float* ca_Wq = (const float*)d_in[27];
    const float* ca_bq = (const float*)d_in[28];
    const float* ca_Wk = (const float*)d_in[29];
    const float* ca_bk = (const float*)d_in[30];
    const float* ca_Wv = (const float*)d_in[31];
    const float* ca_bv = (const float*)d_in[32];
    const float* ca_Wo = (const float*)d_in[33];
    const float* ca_bo = (const float*)d_in[34];
    const float* ca_ln1_g = (const float*)d_in[35];
    const float* ca_ln1_b = (const float*)d_in[36];
    const float* ca_ff_W1 = (const float*)d_in[37];
    const float* ca_ff_b1 = (const float*)d_in[38];
    const float* ca_ff_W2 = (const float*)d_in[39];
    const float* ca_ff_b2 = (const float*)d_in[40];
    const float* ca_ln2_g = (const float*)d_in[41];
    const float* ca_ln2_b = (const float*)d_in[42];
    float* out = (float*)d_out;

    // Workspace layout (byte offsets, 256-aligned)
    char* base = (char*)d_ws;
    float* b1w   = (float*)(base + 0);          //  32 KB
    float* resid = (float*)(base + 32768);      // 128 KB
    float* X0    = (float*)(base + 163840);     //   4 MB
    float* X1    = (float*)(base + 4358144);    //   4 MB
    char*  QKVr  = base + 8552448;              //  12 MB region
    bf16*  Wpk   = (bf16*) (base + 25329664);   // 1.03 MB
    float* bpk   = (float*)(base + 26411008);   //   1 KB
    bf16*  X0h   = (bf16*) (base + 26412032);   //   2 MB
    bf16*  X1h   = (bf16*) (base + 28509184);   //   2 MB
    bf16*  sembh = (bf16*) (base + 30606336);   //   2 MB
    bf16*  ATTh  = (bf16*) (base + 32703488);   //   2 MB
    bf16*  Qh    = (bf16*)QKVr;                 //   2 MB
    bf16*  Kh    = (bf16*)(QKVr + 2097152);     //   2 MB
    bf16*  Vth   = (bf16*)(QKVr + 4194304);     //   2 MB
    bf16*  CATh  = (bf16*)QKVr;                 //   4 MB (after attn done)
    bf16*  Hh    = (bf16*)(QKVr + 4194304);     //  <=8 MB (after attn done)

    const int NTOK = B_ * T_ * N_;  // 8192

    // Prep (weights + semb cast + bias pack), one launch
    k_prep<<<dim3(6209), dim3(256), 0, stream>>>(
        enc_qkv_W, enc_out_W, enc_ff_W1, enc_ff_W2, ca_Wq, ca_Wk, ca_Wv, ca_Wo,
        ca_ff_W1, ca_ff_W2, mlp_W2, semb, ca_bk, ca_bv, Wpk, sembh, bpk);

    // Residual features + token MLP (mlp gemm fused with gelu+LN+PE+transpose)
    k_b1<<<dim3((B_ * (T_ - 1) + 63) / 64), dim3(64), 0, stream>>>(
        vs, r5, A55, bl_bias, nl_W1, nl_b1, nl_W2, nl_b2, b1w);
    k_resid<<<dim3(NTOK / 64), dim3(64), 0, stream>>>(vs, b1w, resid);
    k_mlp1<<<dim3(NTOK), dim3(128), 0, stream>>>(resid, mlp_W1, mlp_b1, (bf16*)X1h);
    k_gemm_ln<<<dim3(256), dim3(256), 0, stream>>>(
        (bf16*)X1h, Wpk + 524288, mlp_b2, 128, nullptr, mlp_ln_g, mlp_ln_b,
        X0, X0h, 128, nullptr, 1 | 2 | 4);

    // Encoder layers
    for (int i = 0; i < LENC_; i++) {
        k_gemm<<<dim3(3072), dim3(256), 0, stream>>>(
            X0h, Wpk + i * 49152, enc_qkv_b + i * 384, nullptr, nullptr,
            Qh, Kh, Vth, NTOK, 384, 128, 0, 1);
        k_mattn<<<dim3(512), dim3(256), 0, stream>>>(
            Qh, Kh, Vth, ATTh, 256, 256, 128);
        k_gemm_ln<<<dim3(256), dim3(256), 0, stream>>>(
            ATTh, Wpk + 98304 + i * 16384, enc_out_b + i * 128, 128, X0,
            enc_ln1_g + i * 128, enc_ln1_b + i * 128, X1, X1h, 128, nullptr, 0);
        k_gemm<<<dim3(2048), dim3(256), 0, stream>>>(
            X1h, Wpk + 131072 + i * 32768, enc_ff_b1 + i * 256, nullptr, Hh,
            nullptr, nullptr, nullptr, NTOK, 256, 128, 1, 0);
        k_gemm_ln<<<dim3(256), dim3(256), 0, stream>>>(
            Hh, Wpk + 196608 + i * 32768, enc_ff_b2 + i * 128, 256, X1,
            enc_ln2_g + i * 128, enc_ln2_b + i * 128, X0, X0h, 128, nullptr, 0);
    }

    // Cross-attention (NSH = 16, Lq = Lk = 2048)
    k_gemm<<<dim3(1024), dim3(256), 0, stream>>>(
        sembh, Wpk + 262144, ca_bq, nullptr, nullptr, Qh, nullptr, nullptr,
        NTOK, 128, 128, 0, 2);
    k_gemm<<<dim3(2048), dim3(256), 0, stream>>>(
        X0h, Wpk + 278528, bpk, nullptr, nullptr, nullptr, Kh, Vth,
        NTOK, 256, 128, 0, 3);
    k_mattn<<<dim3(512), dim3(256), 0, stream>>>(
        Qh, Kh, Vth, ATTh, 2048, 2048, 16);
    // out-proj + residual(semb) + LN -> X1 fp32, CATh[:, :128] bf16 + cat fill
    k_gemm_ln<<<dim3(256), dim3(256), 0, stream>>>(
        ATTh, Wpk + 311296, ca_bo, 128, semb, ca_ln1_g, ca_ln1_b,
        X1, CATh, 256, X0h, 0);
    k_gemm<<<dim3(4096), dim3(256), 0, stream>>>(
        CATh, Wpk + 327680, ca_ff_b1, nullptr, Hh, nullptr, nullptr, nullptr,
        NTOK, 512, 256, 1, 0);
    k_gemm_ln<<<dim3(256), dim3(256), 0, stream>>>(
        Hh, Wpk + 458752, ca_ff_b2, 512, X1, ca_ln2_g, ca_ln2_b,
        out, nullptr, 128, nullptr, 0);
}

// Round 10
// 391.517 us; speedup vs baseline: 1.1595x; 1.1595x over previous
//
#include <hip/hip_runtime.h>
#include <math.h>

// Problem constants
#define B_ 4
#define T_ 256
#define N_ 8
#define D_ 128
#define NH_ 4
#define HD_ 32
#define LENC_ 2
#define MLPH_ 32
#define NL_SCALE_ 0.1f

typedef __bf16 bf16;
typedef __attribute__((ext_vector_type(2))) __bf16 bf16x2;
typedef __attribute__((ext_vector_type(4))) __bf16 bf16x4;
typedef __attribute__((ext_vector_type(8))) __bf16 bf16x8;
typedef __attribute__((ext_vector_type(4))) float f32x4;

__device__ __forceinline__ f32x4 pv_mfma16(bf16x4 a, bf16x4 b, f32x4 c) {
#if __has_builtin(__builtin_amdgcn_mfma_f32_16x16x16_bf16)
    return __builtin_amdgcn_mfma_f32_16x16x16_bf16(a, b, c, 0, 0, 0);
#else
    typedef __attribute__((ext_vector_type(4))) short s4;
    union U { bf16x4 h; s4 s; };
    U ua, ub; ua.h = a; ub.h = b;
    return __builtin_amdgcn_mfma_f32_16x16x16bf16_1k(ua.s, ub.s, c, 0, 0, 0);
#endif
}

__device__ __forceinline__ float gelu_f(float x) {
    return 0.5f * x * (1.0f + erff(x * 0.7071067811865476f));
}

// ---------------------------------------------------------------------------
// Merged prep: weight pack fp32->bf16, state_emb->bf16, bias pack.
__global__ void k_prep(const float* __restrict__ eqkvW, const float* __restrict__ eoutW,
                       const float* __restrict__ eff1, const float* __restrict__ eff2,
                       const float* __restrict__ wq, const float* __restrict__ wk,
                       const float* __restrict__ wv, const float* __restrict__ wo,
                       const float* __restrict__ cff1, const float* __restrict__ cff2,
                       const float* __restrict__ mlpW2, const float* __restrict__ semb,
                       const float* __restrict__ bk, const float* __restrict__ bv,
                       bf16* __restrict__ Wpk, bf16* __restrict__ sembh,
                       float* __restrict__ bpk) {
    int i = blockIdx.x * 256 + threadIdx.x;
    if (i < 540672) {
        const float* src; int off;
        if      (i < 98304)  { src = eqkvW; off = 0; }
        else if (i < 131072) { src = eoutW; off = 98304; }
        else if (i < 196608) { src = eff1;  off = 131072; }
        else if (i < 262144) { src = eff2;  off = 196608; }
        else if (i < 278528) { src = wq;    off = 262144; }
        else if (i < 294912) { src = wk;    off = 278528; }
        else if (i < 311296) { src = wv;    off = 294912; }
        else if (i < 327680) { src = wo;    off = 311296; }
        else if (i < 458752) { src = cff1;  off = 327680; }
        else if (i < 524288) { src = cff2;  off = 458752; }
        else                 { src = mlpW2; off = 524288; }
        Wpk[i] = (bf16)src[i - off];
    } else if (i < 540672 + 1048576) {
        int j = i - 540672;
        sembh[j] = (bf16)semb[j];
    } else if (i < 540672 + 1048576 + 256) {
        int t = i - 540672 - 1048576;
        bpk[t] = (t < 128) ? bk[t] : bv[t - 128];
    }
}

// ---------------------------------------------------------------------------
// K1: b1[b,t,m], t in [0,T-1)
__global__ void k_b1(const float* __restrict__ vs, const float* __restrict__ r5,
                     const float* __restrict__ A55, const float* __restrict__ bl_bias,
                     const float* __restrict__ nlW1, const float* __restrict__ nlb1,
                     const float* __restrict__ nlW2, const float* __restrict__ nlb2,
                     float* __restrict__ b1w) {
    int idx = blockIdx.x * blockDim.x + threadIdx.x;
    if (idx >= B_ * (T_ - 1)) return;
    int b = idx / (T_ - 1), t = idx % (T_ - 1);
    float x[N_];
    for (int n = 0; n < N_; n++) x[n] = vs[(b * T_ + t) * N_ + n];
    float h[MLPH_];
    for (int j = 0; j < MLPH_; j++) {
        float a = nlb1[j];
        for (int n = 0; n < N_; n++) a += x[n] * nlW1[j * N_ + n];
        h[j] = gelu_f(a);
    }
    for (int m = 0; m < N_; m++) {
        float lin = r5[m];
        for (int n = 0; n < N_; n++) lin += x[n] * A55[m * N_ + n];
        float nl = nlb2[m];
        for (int j = 0; j < MLPH_; j++) nl += h[j] * nlW2[m * MLPH_ + j];
        b1w[idx * N_ + m] = lin + NL_SCALE_ * nl + bl_bias[m];
    }
}

// ---------------------------------------------------------------------------
// K2: residuals[b,t,n,si] for SCALES = {1,2,3,5}
__global__ void k_resid(const float* __restrict__ vs, const float* __restrict__ b1w,
                        float* __restrict__ resid) {
    int idx = blockIdx.x * blockDim.x + threadIdx.x;
    if (idx >= B_ * T_ * N_) return;
    int b = idx / (T_ * N_);
    int t = (idx / N_) % T_;
    int n = idx % N_;
    const int SC[4] = {1, 2, 3, 5};
    float lx0 = logf(fmaxf(vs[(b * T_ + t) * N_ + n], 1e-6f));
    for (int si = 0; si < 4; si++) {
        int k = SC[si];
        float r = 0.0f;
        if (t < T_ - k) {
            float lx1 = logf(fmaxf(vs[(b * T_ + t + k) * N_ + n], 1e-6f));
            float a = lx1 - lx0;
            float cmin = -2.5f * (float)k, cmax = 2.0f * (float)k;
            a = fminf(fmaxf(a, cmin), cmax);
            float bk = 0.0f;
            for (int i = 0; i < k; i++) bk += b1w[(b * (T_ - 1) + t + i) * N_ + n];
            r = a - bk;
        }
        resid[idx * 4 + si] = r;
    }
}

// ---------------------------------------------------------------------------
// K3a: per-token MLP layer1 (16 -> 128, gelu), output bf16 in (b,t,n) order.
__global__ void k_mlp1(const float* __restrict__ resid, const float* __restrict__ W1,
                       const float* __restrict__ b1, bf16* __restrict__ H1h) {
    int tok = blockIdx.x;                  // b*2048 + t*8 + n
    int d = threadIdx.x;                   // 128
    int b = tok >> 11, t = (tok >> 3) & 255, n = tok & 7;
    __shared__ float f[16];
    if (d < 16) {
        int g = d >> 2, si = d & 3;
        f[d] = (t - g >= 0) ? resid[((b * T_ + (t - g)) * N_ + n) * 4 + si] : 0.0f;
    }
    __syncthreads();
    float a = b1[d];
    const float* w = W1 + d * 16;
#pragma unroll
    for (int c = 0; c < 16; c++) a += f[c] * w[c];
    H1h[(size_t)tok * 128 + d] = (bf16)gelu_f(a);
}

// ---------------------------------------------------------------------------
// MFMA GEMM: C[M x N] = act(A @ W^T + bias). A bf16 [MxK] rowmajor,
// W bf16 [NxK] rowmajor. One 16x16 C tile per wave; 4 waves/block.
// mode 0: row-major write (Cf fp32 / Ch bf16).
// mode 1 (enc QKV, N=384): scatter to Qh/Kh [sh][256][32], Vth [sh][32][256].
// mode 2 (cross Q, N=128): scatter to Qh [sh][2048][32].
// mode 3 (cross KV, N=256): scatter K->Kh [sh][2048][32], V->Vth [sh][32][2048],
//         with l = t*8+n remap from xt row order.
__global__ __launch_bounds__(256) void k_gemm(
    const bf16* __restrict__ A, const bf16* __restrict__ W,
    const float* __restrict__ bias, float* __restrict__ Cf,
    bf16* __restrict__ Ch, bf16* __restrict__ dq, bf16* __restrict__ dk,
    bf16* __restrict__ dvv, int M, int N, int K, int act, int mode) {
    int lane = threadIdx.x & 63;
    int wv = threadIdx.x >> 6;
    int wtile = blockIdx.x * 4 + wv;
    int nN = N >> 4;
    int tn = wtile % nN, tm = wtile / nN;
    if (tm >= (M >> 4)) return;
    int mrow = tm * 16 + (lane & 15);
    int nrow = tn * 16 + (lane & 15);
    int g = lane >> 4;
    const bf16x8* Ap = (const bf16x8*)(A + (size_t)mrow * K) + g;
    const bf16x8* Wp = (const bf16x8*)(W + (size_t)nrow * K) + g;
    f32x4 acc = {0.0f, 0.0f, 0.0f, 0.0f};
    int nk = K >> 5;
    for (int k = 0; k < nk; k++) {
        bf16x8 av = Ap[k * 4];
        bf16x8 bv8 = Wp[k * 4];
        acc = __builtin_amdgcn_mfma_f32_16x16x32_bf16(av, bv8, acc, 0, 0, 0);
    }
    int col = tn * 16 + (lane & 15);
    int row0 = tm * 16 + g * 4;
    float bvv = bias[col];
#pragma unroll
    for (int i = 0; i < 4; i++) {
        float v = acc[i] + bvv;
        if (act) v = gelu_f(v);
        int row = row0 + i;
        if (mode == 0) {
            if (Cf) Cf[(size_t)row * N + col] = v;
            if (Ch) Ch[(size_t)row * N + col] = (bf16)v;
        } else if (mode == 1) {
            int s = row >> 8, t = row & 255;
            int h = (col >> 5) & 3, d = col & 31;
            int sh = s * 4 + h;
            if (col < 128)      dq[((size_t)sh * 256 + t) * 32 + d] = (bf16)v;
            else if (col < 256) dk[((size_t)sh * 256 + t) * 32 + d] = (bf16)v;
            else                dvv[((size_t)sh * 32 + d) * 256 + t] = (bf16)v;
        } else if (mode == 2) {
            int b = row >> 11, ll = row & 2047;
            int h = col >> 5, d = col & 31;
            dq[((size_t)(b * 4 + h) * 2048 + ll) * 32 + d] = (bf16)v;
        } else {
            int b = row >> 11, n = (row >> 8) & 7, t = row & 255;
            int ll = t * 8 + n;
            int h = (col >> 5) & 3, d = col & 31;
            if (col < 128) dk[((size_t)(b * 4 + h) * 2048 + ll) * 32 + d] = (bf16)v;
            else           dvv[((size_t)(b * 4 + h) * 32 + d) * 2048 + ll] = (bf16)v;
        }
    }
}

// ---------------------------------------------------------------------------
// Fused GEMM(N=128) + [gelu] + [residual] + LayerNorm + [PE] + writes.
// flags: 1=gelu-before-LN, 2=add-PE-after-LN, 4=transpose-out-row (xt order).
__global__ __launch_bounds__(256) void k_gemm_ln(
    const bf16* __restrict__ A, const bf16* __restrict__ W,
    const float* __restrict__ bias, int K,
    const float* __restrict__ resf,
    const float* __restrict__ g, const float* __restrict__ be,
    float* __restrict__ outf, bf16* __restrict__ outh, int hs,
    const bf16* __restrict__ catsrc, int flags) {
    __shared__ float S[32][132];
    int tid = threadIdx.x;
    int w = tid >> 6, lane = tid & 63;
    int c = lane & 15, gq = lane >> 4;
    int r0 = blockIdx.x * 32 + (w >> 1) * 16;
    int cb = (w & 1) * 64;

    const bf16x8* Ap  = (const bf16x8*)(A + (size_t)(r0 + c) * K) + gq;
    const bf16x8* Wp0 = (const bf16x8*)(W + (size_t)(cb + c) * K) + gq;
    const bf16x8* Wp1 = (const bf16x8*)(W + (size_t)(cb + 16 + c) * K) + gq;
    const bf16x8* Wp2 = (const bf16x8*)(W + (size_t)(cb + 32 + c) * K) + gq;
    const bf16x8* Wp3 = (const bf16x8*)(W + (size_t)(cb + 48 + c) * K) + gq;
    f32x4 a0 = {0, 0, 0, 0}, a1 = {0, 0, 0, 0};
    f32x4 a2 = {0, 0, 0, 0}, a3 = {0, 0, 0, 0};
    int nk = K >> 5;
    for (int k = 0; k < nk; k++) {
        bf16x8 av = Ap[k * 4];
        a0 = __builtin_amdgcn_mfma_f32_16x16x32_bf16(av, Wp0[k * 4], a0, 0, 0, 0);
        a1 = __builtin_amdgcn_mfma_f32_16x16x32_bf16(av, Wp1[k * 4], a1, 0, 0, 0);
        a2 = __builtin_amdgcn_mfma_f32_16x16x32_bf16(av, Wp2[k * 4], a2, 0, 0, 0);
        a3 = __builtin_amdgcn_mfma_f32_16x16x32_bf16(av, Wp3[k * 4], a3, 0, 0, 0);
    }
    int lrow = (w >> 1) * 16 + gq * 4;
    float b0 = bias[cb + c], b1v = bias[cb + 16 + c];
    float b2v = bias[cb + 32 + c], b3v = bias[cb + 48 + c];
#pragma unroll
    for (int r = 0; r < 4; r++) {
        float v0 = a0[r] + b0, v1 = a1[r] + b1v;
        float v2 = a2[r] + b2v, v3 = a3[r] + b3v;
        if (flags & 1) {
            v0 = gelu_f(v0); v1 = gelu_f(v1); v2 = gelu_f(v2); v3 = gelu_f(v3);
        }
        S[lrow + r][cb + c] = v0;       S[lrow + r][cb + 16 + c] = v1;
        S[lrow + r][cb + 32 + c] = v2;  S[lrow + r][cb + 48 + c] = v3;
    }
    __syncthreads();

    int row = tid >> 3, cg = tid & 7;          // 32 rows x 8 col-groups of 16
    int grow = blockIdx.x * 32 + row;
    int b = grow >> 11, t = (grow >> 3) & 255, n = grow & 7;
    int orow = (flags & 4) ? ((b * 8 + n) * 256 + t) : grow;
    float v[16];
#pragma unroll
    for (int j = 0; j < 16; j++) v[j] = S[row][cg * 16 + j];
    if (resf) {
        const float4* rp = (const float4*)(resf + (size_t)grow * 128 + cg * 16);
#pragma unroll
        for (int j4 = 0; j4 < 4; j4++) {
            float4 rv = rp[j4];
            v[4 * j4 + 0] += rv.x; v[4 * j4 + 1] += rv.y;
            v[4 * j4 + 2] += rv.z; v[4 * j4 + 3] += rv.w;
        }
    }
    float s = 0.0f;
#pragma unroll
    for (int j = 0; j < 16; j++) s += v[j];
    s += __shfl_xor(s, 1); s += __shfl_xor(s, 2); s += __shfl_xor(s, 4);
    float mean = s * (1.0f / 128.0f);
    float vs = 0.0f;
#pragma unroll
    for (int j = 0; j < 16; j++) { float d = v[j] - mean; vs += d * d; }
    vs += __shfl_xor(vs, 1); vs += __shfl_xor(vs, 2); vs += __shfl_xor(vs, 4);
    float rstd = rsqrtf(vs * (1.0f / 128.0f) + 1e-5f);
    float y[16];
#pragma unroll
    for (int j = 0; j < 16; j++) {
        int col = cg * 16 + j;
        y[j] = (v[j] - mean) * rstd * g[col] + be[col];
    }
    if (flags & 2) {                    // sinusoidal PE, added after LN
#pragma unroll
        for (int jj = 0; jj < 8; jj++) {
            int j2 = cg * 8 + jj;       // pair index = col>>1
            float freq = expf((float)(2 * j2) * (-9.210340371976184f / 128.0f));
            float ang = (float)t * freq;
            y[2 * jj] += sinf(ang);
            y[2 * jj + 1] += cosf(ang);
        }
    }
    if (outf) {
        float4* op = (float4*)(outf + (size_t)orow * 128 + cg * 16);
#pragma unroll
        for (int j4 = 0; j4 < 4; j4++) {
            float4 o; o.x = y[4 * j4]; o.y = y[4 * j4 + 1];
            o.z = y[4 * j4 + 2]; o.w = y[4 * j4 + 3];
            op[j4] = o;
        }
    }
    if (outh) {
        bf16x8* op = (bf16x8*)(outh + (size_t)orow * hs + cg * 16);
#pragma unroll
        for (int j8 = 0; j8 < 2; j8++) {
            bf16x8 o;
#pragma unroll
            for (int e = 0; e < 8; e++) o[e] = (bf16)y[8 * j8 + e];
            op[j8] = o;
        }
        if (catsrc) {                   // fill CAT[:,128:256] from xt order
            const bf16x8* cp = (const bf16x8*)(
                catsrc + ((size_t)(b * 8 + n) * 256 + t) * 128 + cg * 16);
            bf16x8* dp = (bf16x8*)(outh + (size_t)orow * 256 + 128 + cg * 16);
            dp[0] = cp[0]; dp[1] = cp[1];
        }
    }
}

// ---------------------------------------------------------------------------
// MFMA flash attention v6: chain-free math (R9) + 64 q/wave (4 Q frags per
// K/V load: 4x less K/V traffic) + intra-block key-split (4 waves each take
// Lk/4 keys: 4x shorter serial loop). No running max -> partials are plain
// sums; one LDS combine + single barrier per block. XCD swizzle sh=bid%NSH.
// grid = NSH * (Lq/64); block = 256 thr = 4 waves, each wave: 64 q x Lk/4 k.
// Qh [sh][Lq][32], Kh [sh][Lk][32], Vth [sh][32][Lk] (bf16, V transposed).
// Output ATTh[((sh>>2)*Lq + q)*128 + (sh&3)*32 + d] (bf16).
__global__ __launch_bounds__(256) void k_mattn(
    const bf16* __restrict__ Qh, const bf16* __restrict__ Kh,
    const bf16* __restrict__ Vth, bf16* __restrict__ ATTh,
    int Lq, int Lk, int NSH) {
    int sh = blockIdx.x % NSH;
    int qblk = blockIdx.x / NSH;
    int wv = threadIdx.x >> 6;
    int lane = threadIdx.x & 63;
    int c = lane & 15, g = lane >> 4;
    int q0 = qblk * 64;

    __shared__ float O_lds[4][64][36];   // +4 pad: b128 rw <=2-way aliased
    __shared__ float L_lds[4][64];

    const float scale = 0.17677669529663687f;  // 1/sqrt(32)
    const f32x4 zero = {0, 0, 0, 0};

    // 4 Q B-frags: q-subtiles q0 + qt*16 + c, k=dim=g*8+j
    bf16x8 bq[4];
#pragma unroll
    for (int qt = 0; qt < 4; qt++)
        bq[qt] = *(const bf16x8*)(
            Qh + ((size_t)sh * Lq + q0 + qt * 16 + c) * 32 + g * 8);

    int klen = Lk >> 2;                  // keys per wave
    int kbeg = wv * klen;
    const bf16* Kbase = Kh + (size_t)sh * Lk * 32 + (size_t)kbeg * 32;
    const bf16* Vbase = Vth + (size_t)sh * 32 * Lk + kbeg;

    f32x4 oT[4][2];
#pragma unroll
    for (int qt = 0; qt < 4; qt++) { oT[qt][0] = zero; oT[qt][1] = zero; }
    float lsum[4] = {0, 0, 0, 0};

    int ntiles = klen >> 5;              // enc: 2, cross: 16
    // prefetch tile 0: K A-frags (keys c, 16+c), V A-frags (d=c, 16+c)
    bf16x8 ka = *(const bf16x8*)(Kbase + (size_t)c * 32 + g * 8);
    bf16x8 kb = *(const bf16x8*)(Kbase + (size_t)(16 + c) * 32 + g * 8);
    bf16x4 va0 = *(const bf16x4*)(Vbase + (size_t)c * Lk + g * 4);
    bf16x4 va1 = *(const bf16x4*)(Vbase + (size_t)c * Lk + 16 + g * 4);
    bf16x4 vb0 = *(const bf16x4*)(Vbase + (size_t)(16 + c) * Lk + g * 4);
    bf16x4 vb1 = *(const bf16x4*)(Vbase + (size_t)(16 + c) * Lk + 16 + g * 4);

    for (int t = 0; t < ntiles; t++) {
        bf16x8 cka = ka, ckb = kb;
        bf16x4 cva0 = va0, cva1 = va1, cvb0 = vb0, cvb1 = vb1;
        int nk0 = ((t + 1 < ntiles) ? (t + 1) : t) << 5;
        ka = *(const bf16x8*)(Kbase + (size_t)(nk0 + c) * 32 + g * 8);
        kb = *(const bf16x8*)(Kbase + (size_t)(nk0 + 16 + c) * 32 + g * 8);
        va0 = *(const bf16x4*)(Vbase + (size_t)c * Lk + nk0 + g * 4);
        va1 = *(const bf16x4*)(Vbase + (size_t)c * Lk + nk0 + 16 + g * 4);
        vb0 = *(const bf16x4*)(Vbase + (size_t)(16 + c) * Lk + nk0 + g * 4);
        vb1 = *(const bf16x4*)(Vbase + (size_t)(16 + c) * Lk + nk0 + 16 + g * 4);

#pragma unroll
        for (int qt = 0; qt < 4; qt++) {
            // S^T sub-tiles: row=key=g*4+r, col=q=c
            f32x4 s0 = __builtin_amdgcn_mfma_f32_16x16x32_bf16(cka, bq[qt], zero, 0, 0, 0);
            f32x4 s1 = __builtin_amdgcn_mfma_f32_16x16x32_bf16(ckb, bq[qt], zero, 0, 0, 0);
            bf16x4 p0, p1;
#pragma unroll
            for (int r = 0; r < 4; r++) {
                float e0 = __expf(s0[r] * scale);
                float e1 = __expf(s1[r] * scale);
                lsum[qt] += e0 + e1;
                p0[r] = (bf16)e0;
                p1[r] = (bf16)e1;
            }
            // O^T += V^T · P^T  (16x16x16: A k=g*4+j keys, B n=c=q)
            oT[qt][0] = pv_mfma16(cva0, p0, oT[qt][0]);
            oT[qt][0] = pv_mfma16(cva1, p1, oT[qt][0]);
            oT[qt][1] = pv_mfma16(cvb0, p0, oT[qt][1]);
            oT[qt][1] = pv_mfma16(cvb1, p1, oT[qt][1]);
        }
    }

    // write per-wave partials; l reduced over the 4 g-lanes first
#pragma unroll
    for (int qt = 0; qt < 4; qt++) {
        float s = lsum[qt];
        s += __shfl_xor(s, 16);
        s += __shfl_xor(s, 32);
        if (g == 0) L_lds[wv][qt * 16 + c] = s;
        *(f32x4*)&O_lds[wv][qt * 16 + c][g * 4] = oT[qt][0];
        *(f32x4*)&O_lds[wv][qt * 16 + c][16 + g * 4] = oT[qt][1];
    }
    __syncthreads();

    // combine: thread tid -> (q_local = tid>>2, 8 dims at (tid&3)*8)
    int tid = threadIdx.x;
    int ql = tid >> 2, dq = (tid & 3) * 8;
    float ltot = L_lds[0][ql] + L_lds[1][ql] + L_lds[2][ql] + L_lds[3][ql];
    float inv = 1.0f / ltot;
    float acc[8];
#pragma unroll
    for (int j = 0; j < 8; j++) acc[j] = 0.0f;
#pragma unroll
    for (int w = 0; w < 4; w++) {
        const float* p = &O_lds[w][ql][dq];
#pragma unroll
        for (int j = 0; j < 8; j++) acc[j] += p[j];
    }
    int h = sh & 3, sb = sh >> 2;
    bf16x8 o;
#pragma unroll
    for (int j = 0; j < 8; j++) o[j] = (bf16)(acc[j] * inv);
    *(bf16x8*)(ATTh + ((size_t)sb * Lq + q0 + ql) * 128 + h * 32 + dq) = o;
}

// ---------------------------------------------------------------------------
extern "C" void kernel_launch(void* const* d_in, const int* in_sizes, int n_in,
                              void* d_out, int out_size, void* d_ws, size_t ws_size,
                              hipStream_t stream) {
    const float* vs       = (const float*)d_in[0];
    const float* semb     = (const float*)d_in[1];
    const float* r5       = (const float*)d_in[2];
    const float* A55      = (const float*)d_in[3];
    const float* bl_bias  = (const float*)d_in[4];
    const float* nl_W1    = (const float*)d_in[5];
    const float* nl_b1    = (const float*)d_in[6];
    const float* nl_W2    = (const float*)d_in[7];
    const float* nl_b2    = (const float*)d_in[8];
    const float* mlp_W1   = (const float*)d_in[9];
    const float* mlp_b1   = (const float*)d_in[10];
    const float* mlp_W2   = (const float*)d_in[11];
    const float* mlp_b2   = (const float*)d_in[12];
    const float* mlp_ln_g = (const float*)d_in[13];
    const float* mlp_ln_b = (const float*)d_in[14];
    const float* enc_qkv_W = (const float*)d_in[15];
    const float* enc_qkv_b = (const float*)d_in[16];
    const float* enc_out_W = (const float*)d_in[17];
    const float* enc_out_b = (const float*)d_in[18];
    const float* enc_ln1_g = (const float*)d_in[19];
    const float* enc_ln1_b = (const float*)d_in[20];
    const float* enc_ff_W1 = (const float*)d_in[21];
    const float* enc_ff_b1 = (const float*)d_in[22];
    const float* enc_ff_W2 = (const float*)d_in[23];
    const float* enc_ff_b2 = (const float*)d_in[24];
    const float* enc_ln2_g = (const float*)d_in[25];
    const float* enc_ln2_b = (const float*)d_in[26];
    const float* ca_Wq = (const float*)d_in[27];
    const float* ca_bq = (const float*)d_in[28];
    const float* ca_Wk = (const float*)d_in[29];
    const float* ca_bk = (const float*)d_in[30];
    const float* ca_Wv = (const float*)d_in[31];
    const float* ca_bv = (const float*)d_in[32];
    const float* ca_Wo = (const float*)d_in[33];
    const float* ca_bo = (const float*)d_in[34];
    const float* ca_ln1_g = (const float*)d_in[35];
    const float* ca_ln1_b = (const float*)d_in[36];
    const float* ca_ff_W1 = (const float*)d_in[37];
    const float* ca_ff_b1 = (const float*)d_in[38];
    const float* ca_ff_W2 = (const float*)d_in[39];
    const float* ca_ff_b2 = (const float*)d_in[40];
    const float* ca_ln2_g = (const float*)d_in[41];
    const float* ca_ln2_b = (const float*)d_in[42];
    float* out = (float*)d_out;

    // Workspace layout (byte offsets, 256-aligned)
    char* base = (char*)d_ws;
    float* b1w   = (float*)(base + 0);          //  32 KB
    float* resid = (float*)(base + 32768);      // 128 KB
    float* X0    = (float*)(base + 163840);     //   4 MB
    float* X1    = (float*)(base + 4358144);    //   4 MB
    char*  QKVr  = base + 8552448;              //  12 MB region
    bf16*  Wpk   = (bf16*) (base + 25329664);   // 1.03 MB
    float* bpk   = (float*)(base + 26411008);   //   1 KB
    bf16*  X0h   = (bf16*) (base + 26412032);   //   2 MB
    bf16*  X1h   = (bf16*) (base + 28509184);   //   2 MB
    bf16*  sembh = (bf16*) (base + 30606336);   //   2 MB
    bf16*  ATTh  = (bf16*) (base + 32703488);   //   2 MB
    bf16*  Qh    = (bf16*)QKVr;                 //   2 MB
    bf16*  Kh    = (bf16*)(QKVr + 2097152);     //   2 MB
    bf16*  Vth   = (bf16*)(QKVr + 4194304);     //   2 MB
    bf16*  CATh  = (bf16*)QKVr;                 //   4 MB (after attn done)
    bf16*  Hh    = (bf16*)(QKVr + 4194304);     //  <=8 MB (after attn done)

    const int NTOK = B_ * T_ * N_;  // 8192

    // Prep (weights + semb cast + bias pack), one launch
    k_prep<<<dim3(6209), dim3(256), 0, stream>>>(
        enc_qkv_W, enc_out_W, enc_ff_W1, enc_ff_W2, ca_Wq, ca_Wk, ca_Wv, ca_Wo,
        ca_ff_W1, ca_ff_W2, mlp_W2, semb, ca_bk, ca_bv, Wpk, sembh, bpk);

    // Residual features + token MLP (mlp gemm fused with gelu+LN+PE+transpose)
    k_b1<<<dim3((B_ * (T_ - 1) + 63) / 64), dim3(64), 0, stream>>>(
        vs, r5, A55, bl_bias, nl_W1, nl_b1, nl_W2, nl_b2, b1w);
    k_resid<<<dim3(NTOK / 64), dim3(64), 0, stream>>>(vs, b1w, resid);
    k_mlp1<<<dim3(NTOK), dim3(128), 0, stream>>>(resid, mlp_W1, mlp_b1, (bf16*)X1h);
    k_gemm_ln<<<dim3(256), dim3(256), 0, stream>>>(
        (bf16*)X1h, Wpk + 524288, mlp_b2, 128, nullptr, mlp_ln_g, mlp_ln_b,
        X0, X0h, 128, nullptr, 1 | 2 | 4);

    // Encoder layers
    for (int i = 0; i < LENC_; i++) {
        k_gemm<<<dim3(3072), dim3(256), 0, stream>>>(
            X0h, Wpk + i * 49152, enc_qkv_b + i * 384, nullptr, nullptr,
            Qh, Kh, Vth, NTOK, 384, 128, 0, 1);
        k_mattn<<<dim3(512), dim3(256), 0, stream>>>(
            Qh, Kh, Vth, ATTh, 256, 256, 128);
        k_gemm_ln<<<dim3(256), dim3(256), 0, stream>>>(
            ATTh, Wpk + 98304 + i * 16384, enc_out_b + i * 128, 128, X0,
            enc_ln1_g + i * 128, enc_ln1_b + i * 128, X1, X1h, 128, nullptr, 0);
        k_gemm<<<dim3(2048), dim3(256), 0, stream>>>(
            X1h, Wpk + 131072 + i * 32768, enc_ff_b1 + i * 256, nullptr, Hh,
            nullptr, nullptr, nullptr, NTOK, 256, 128, 1, 0);
        k_gemm_ln<<<dim3(256), dim3(256), 0, stream>>>(
            Hh, Wpk + 196608 + i * 32768, enc_ff_b2 + i * 128, 256, X1,
            enc_ln2_g + i * 128, enc_ln2_b + i * 128, X0, X0h, 128, nullptr, 0);
    }

    // Cross-attention (NSH = 16, Lq = Lk = 2048)
    k_gemm<<<dim3(1024), dim3(256), 0, stream>>>(
        sembh, Wpk + 262144, ca_bq, nullptr, nullptr, Qh, nullptr, nullptr,
        NTOK, 128, 128, 0, 2);
    k_gemm<<<dim3(2048), dim3(256), 0, stream>>>(
        X0h, Wpk + 278528, bpk, nullptr, nullptr, nullptr, Kh, Vth,
        NTOK, 256, 128, 0, 3);
    k_mattn<<<dim3(512), dim3(256), 0, stream>>>(
        Qh, Kh, Vth, ATTh, 2048, 2048, 16);
    // out-proj + residual(semb) + LN -> X1 fp32, CATh[:, :128] bf16 + cat fill
    k_gemm_ln<<<dim3(256), dim3(256), 0, stream>>>(
        ATTh, Wpk + 311296, ca_bo, 128, semb, ca_ln1_g, ca_ln1_b,
        X1, CATh, 256, X0h, 0);
    k_gemm<<<dim3(4096), dim3(256), 0, stream>>>(
        CATh, Wpk + 327680, ca_ff_b1, nullptr, Hh, nullptr, nullptr, nullptr,
        NTOK, 512, 256, 1, 0);
    k_gemm_ln<<<dim3(256), dim3(256), 0, stream>>>(
        Hh, Wpk + 458752, ca_ff_b2, 512, X1, ca_ln2_g, ca_ln2_b,
        out, nullptr, 128, nullptr, 0);
}

// Round 11
// 373.904 us; speedup vs baseline: 1.2141x; 1.0471x over previous
//
#include <hip/hip_runtime.h>
#include <math.h>

// Problem constants
#define B_ 4
#define T_ 256
#define N_ 8
#define D_ 128
#define NH_ 4
#define HD_ 32
#define LENC_ 2
#define MLPH_ 32
#define NL_SCALE_ 0.1f

typedef __bf16 bf16;
typedef __attribute__((ext_vector_type(2))) __bf16 bf16x2;
typedef __attribute__((ext_vector_type(4))) __bf16 bf16x4;
typedef __attribute__((ext_vector_type(8))) __bf16 bf16x8;
typedef __attribute__((ext_vector_type(4))) float f32x4;

__device__ __forceinline__ f32x4 pv_mfma16(bf16x4 a, bf16x4 b, f32x4 c) {
#if __has_builtin(__builtin_amdgcn_mfma_f32_16x16x16_bf16)
    return __builtin_amdgcn_mfma_f32_16x16x16_bf16(a, b, c, 0, 0, 0);
#else
    typedef __attribute__((ext_vector_type(4))) short s4;
    union U { bf16x4 h; s4 s; };
    U ua, ub; ua.h = a; ub.h = b;
    return __builtin_amdgcn_mfma_f32_16x16x16bf16_1k(ua.s, ub.s, c, 0, 0, 0);
#endif
}

__device__ __forceinline__ float gelu_f(float x) {
    return 0.5f * x * (1.0f + erff(x * 0.7071067811865476f));
}

// ---------------------------------------------------------------------------
// Merged prep: weight pack fp32->bf16, state_emb->bf16, bias pack.
__global__ void k_prep(const float* __restrict__ eqkvW, const float* __restrict__ eoutW,
                       const float* __restrict__ eff1, const float* __restrict__ eff2,
                       const float* __restrict__ wq, const float* __restrict__ wk,
                       const float* __restrict__ wv, const float* __restrict__ wo,
                       const float* __restrict__ cff1, const float* __restrict__ cff2,
                       const float* __restrict__ mlpW2, const float* __restrict__ semb,
                       const float* __restrict__ bk, const float* __restrict__ bv,
                       bf16* __restrict__ Wpk, bf16* __restrict__ sembh,
                       float* __restrict__ bpk) {
    int i = blockIdx.x * 256 + threadIdx.x;
    if (i < 540672) {
        const float* src; int off;
        if      (i < 98304)  { src = eqkvW; off = 0; }
        else if (i < 131072) { src = eoutW; off = 98304; }
        else if (i < 196608) { src = eff1;  off = 131072; }
        else if (i < 262144) { src = eff2;  off = 196608; }
        else if (i < 278528) { src = wq;    off = 262144; }
        else if (i < 294912) { src = wk;    off = 278528; }
        else if (i < 311296) { src = wv;    off = 294912; }
        else if (i < 327680) { src = wo;    off = 311296; }
        else if (i < 458752) { src = cff1;  off = 327680; }
        else if (i < 524288) { src = cff2;  off = 458752; }
        else                 { src = mlpW2; off = 524288; }
        Wpk[i] = (bf16)src[i - off];
    } else if (i < 540672 + 1048576) {
        int j = i - 540672;
        sembh[j] = (bf16)semb[j];
    } else if (i < 540672 + 1048576 + 256) {
        int t = i - 540672 - 1048576;
        bpk[t] = (t < 128) ? bk[t] : bv[t - 128];
    }
}

// ---------------------------------------------------------------------------
// K1: b1[b,t,m], t in [0,T-1)
__global__ void k_b1(const float* __restrict__ vs, const float* __restrict__ r5,
                     const float* __restrict__ A55, const float* __restrict__ bl_bias,
                     const float* __restrict__ nlW1, const float* __restrict__ nlb1,
                     const float* __restrict__ nlW2, const float* __restrict__ nlb2,
                     float* __restrict__ b1w) {
    int idx = blockIdx.x * blockDim.x + threadIdx.x;
    if (idx >= B_ * (T_ - 1)) return;
    int b = idx / (T_ - 1), t = idx % (T_ - 1);
    float x[N_];
    for (int n = 0; n < N_; n++) x[n] = vs[(b * T_ + t) * N_ + n];
    float h[MLPH_];
    for (int j = 0; j < MLPH_; j++) {
        float a = nlb1[j];
        for (int n = 0; n < N_; n++) a += x[n] * nlW1[j * N_ + n];
        h[j] = gelu_f(a);
    }
    for (int m = 0; m < N_; m++) {
        float lin = r5[m];
        for (int n = 0; n < N_; n++) lin += x[n] * A55[m * N_ + n];
        float nl = nlb2[m];
        for (int j = 0; j < MLPH_; j++) nl += h[j] * nlW2[m * MLPH_ + j];
        b1w[idx * N_ + m] = lin + NL_SCALE_ * nl + bl_bias[m];
    }
}

// ---------------------------------------------------------------------------
// K3a: per-token MLP layer1 (16 -> 128, gelu) with the 16 lag/scale residual
// features computed inline from vs/b1w (k_resid fused away).
__global__ void k_mlp1(const float* __restrict__ vs, const float* __restrict__ b1w,
                       const float* __restrict__ W1, const float* __restrict__ b1,
                       bf16* __restrict__ H1h) {
    int tok = blockIdx.x;                  // b*2048 + t*8 + n
    int d = threadIdx.x;                   // 128
    int b = tok >> 11, t = (tok >> 3) & 255, n = tok & 7;
    __shared__ float f[16];
    if (d < 16) {
        const int SC[4] = {1, 2, 3, 5};
        int lag = d >> 2, si = d & 3, k = SC[si];
        int tp = t - lag;
        float r = 0.0f;
        if (tp >= 0 && tp < T_ - k) {
            float lx0 = logf(fmaxf(vs[(b * T_ + tp) * N_ + n], 1e-6f));
            float lx1 = logf(fmaxf(vs[(b * T_ + tp + k) * N_ + n], 1e-6f));
            float a = lx1 - lx0;
            a = fminf(fmaxf(a, -2.5f * (float)k), 2.0f * (float)k);
            float bk = 0.0f;
            for (int i = 0; i < k; i++) bk += b1w[(b * (T_ - 1) + tp + i) * N_ + n];
            r = a - bk;
        }
        f[d] = r;
    }
    __syncthreads();
    float a = b1[d];
    const float* w = W1 + d * 16;
#pragma unroll
    for (int c = 0; c < 16; c++) a += f[c] * w[c];
    H1h[(size_t)tok * 128 + d] = (bf16)gelu_f(a);
}

// ---------------------------------------------------------------------------
// Wide MFMA GEMM: block = 64 rows x 64 cols (wave = 16 rows x 64 cols; one
// A-frag feeds 4 MFMAs per k-step). A bf16 [MxK], W bf16 [NxK] rowmajor.
// grid = (M/64)*(N/64). Modes as before:
// 0: row-major write (Cf fp32 stride N / Ch bf16 stride N).
// 1 (enc QKV, N=384): scatter Qh/Kh [sh][256][32], Vth [sh][32][256].
// 2 (cross Q, N=128): scatter Qh [sh][2048][32].
// 3 (cross KV, N=256): K->Kh [sh][2048][32], V->Vth [sh][32][2048], l=t*8+n.
__global__ __launch_bounds__(256) void k_gemm4(
    const bf16* __restrict__ A, const bf16* __restrict__ W,
    const float* __restrict__ bias, float* __restrict__ Cf,
    bf16* __restrict__ Ch, bf16* __restrict__ dq, bf16* __restrict__ dk,
    bf16* __restrict__ dvv, int M, int N, int K, int act, int mode) {
    int lane = threadIdx.x & 63;
    int wv = threadIdx.x >> 6;
    int c = lane & 15, g = lane >> 4;
    int nN = N >> 6;
    int tn = blockIdx.x % nN, tm = blockIdx.x / nN;
    int row0 = tm * 64 + wv * 16;
    int cb = tn * 64;

    const bf16x8* Ap  = (const bf16x8*)(A + (size_t)(row0 + c) * K) + g;
    const bf16x8* Wp0 = (const bf16x8*)(W + (size_t)(cb + c) * K) + g;
    const bf16x8* Wp1 = (const bf16x8*)(W + (size_t)(cb + 16 + c) * K) + g;
    const bf16x8* Wp2 = (const bf16x8*)(W + (size_t)(cb + 32 + c) * K) + g;
    const bf16x8* Wp3 = (const bf16x8*)(W + (size_t)(cb + 48 + c) * K) + g;
    f32x4 a0 = {0, 0, 0, 0}, a1 = {0, 0, 0, 0};
    f32x4 a2 = {0, 0, 0, 0}, a3 = {0, 0, 0, 0};
    int nk = K >> 5;
    for (int k = 0; k < nk; k++) {
        bf16x8 av = Ap[k * 4];
        a0 = __builtin_amdgcn_mfma_f32_16x16x32_bf16(av, Wp0[k * 4], a0, 0, 0, 0);
        a1 = __builtin_amdgcn_mfma_f32_16x16x32_bf16(av, Wp1[k * 4], a1, 0, 0, 0);
        a2 = __builtin_amdgcn_mfma_f32_16x16x32_bf16(av, Wp2[k * 4], a2, 0, 0, 0);
        a3 = __builtin_amdgcn_mfma_f32_16x16x32_bf16(av, Wp3[k * 4], a3, 0, 0, 0);
    }
    int rowb = row0 + g * 4;
#pragma unroll
    for (int ct = 0; ct < 4; ct++) {
        f32x4 acc = (ct == 0) ? a0 : (ct == 1) ? a1 : (ct == 2) ? a2 : a3;
        int col = cb + ct * 16 + c;
        float bvv = bias[col];
#pragma unroll
        for (int i = 0; i < 4; i++) {
            float v = acc[i] + bvv;
            if (act) v = gelu_f(v);
            int row = rowb + i;
            if (mode == 0) {
                if (Cf) Cf[(size_t)row * N + col] = v;
                if (Ch) Ch[(size_t)row * N + col] = (bf16)v;
            } else if (mode == 1) {
                int s = row >> 8, t = row & 255;
                int h = (col >> 5) & 3, d = col & 31;
                int sh = s * 4 + h;
                if (col < 128)      dq[((size_t)sh * 256 + t) * 32 + d] = (bf16)v;
                else if (col < 256) dk[((size_t)sh * 256 + t) * 32 + d] = (bf16)v;
                else                dvv[((size_t)sh * 32 + d) * 256 + t] = (bf16)v;
            } else if (mode == 2) {
                int b = row >> 11, ll = row & 2047;
                int h = col >> 5, d = col & 31;
                dq[((size_t)(b * 4 + h) * 2048 + ll) * 32 + d] = (bf16)v;
            } else {
                int b = row >> 11, n = (row >> 8) & 7, t = row & 255;
                int ll = t * 8 + n;
                int h = (col >> 5) & 3, d = col & 31;
                if (col < 128) dk[((size_t)(b * 4 + h) * 2048 + ll) * 32 + d] = (bf16)v;
                else           dvv[((size_t)(b * 4 + h) * 32 + d) * 2048 + ll] = (bf16)v;
            }
        }
    }
}

// ---------------------------------------------------------------------------
// Fused GEMM(N=128) + [gelu] + [residual] + LayerNorm + [PE] + writes.
// flags: 1=gelu-before-LN, 2=add-PE-after-LN, 4=transpose-out-row (xt order).
__global__ __launch_bounds__(256) void k_gemm_ln(
    const bf16* __restrict__ A, const bf16* __restrict__ W,
    const float* __restrict__ bias, int K,
    const float* __restrict__ resf,
    const float* __restrict__ g, const float* __restrict__ be,
    float* __restrict__ outf, bf16* __restrict__ outh, int hs,
    const bf16* __restrict__ catsrc, int flags) {
    __shared__ float S[32][132];
    int tid = threadIdx.x;
    int w = tid >> 6, lane = tid & 63;
    int c = lane & 15, gq = lane >> 4;
    int r0 = blockIdx.x * 32 + (w >> 1) * 16;
    int cb = (w & 1) * 64;

    const bf16x8* Ap  = (const bf16x8*)(A + (size_t)(r0 + c) * K) + gq;
    const bf16x8* Wp0 = (const bf16x8*)(W + (size_t)(cb + c) * K) + gq;
    const bf16x8* Wp1 = (const bf16x8*)(W + (size_t)(cb + 16 + c) * K) + gq;
    const bf16x8* Wp2 = (const bf16x8*)(W + (size_t)(cb + 32 + c) * K) + gq;
    const bf16x8* Wp3 = (const bf16x8*)(W + (size_t)(cb + 48 + c) * K) + gq;
    f32x4 a0 = {0, 0, 0, 0}, a1 = {0, 0, 0, 0};
    f32x4 a2 = {0, 0, 0, 0}, a3 = {0, 0, 0, 0};
    int nk = K >> 5;
    for (int k = 0; k < nk; k++) {
        bf16x8 av = Ap[k * 4];
        a0 = __builtin_amdgcn_mfma_f32_16x16x32_bf16(av, Wp0[k * 4], a0, 0, 0, 0);
        a1 = __builtin_amdgcn_mfma_f32_16x16x32_bf16(av, Wp1[k * 4], a1, 0, 0, 0);
        a2 = __builtin_amdgcn_mfma_f32_16x16x32_bf16(av, Wp2[k * 4], a2, 0, 0, 0);
        a3 = __builtin_amdgcn_mfma_f32_16x16x32_bf16(av, Wp3[k * 4], a3, 0, 0, 0);
    }
    int lrow = (w >> 1) * 16 + gq * 4;
    float b0 = bias[cb + c], b1v = bias[cb + 16 + c];
    float b2v = bias[cb + 32 + c], b3v = bias[cb + 48 + c];
#pragma unroll
    for (int r = 0; r < 4; r++) {
        float v0 = a0[r] + b0, v1 = a1[r] + b1v;
        float v2 = a2[r] + b2v, v3 = a3[r] + b3v;
        if (flags & 1) {
            v0 = gelu_f(v0); v1 = gelu_f(v1); v2 = gelu_f(v2); v3 = gelu_f(v3);
        }
        S[lrow + r][cb + c] = v0;       S[lrow + r][cb + 16 + c] = v1;
        S[lrow + r][cb + 32 + c] = v2;  S[lrow + r][cb + 48 + c] = v3;
    }
    __syncthreads();

    int row = tid >> 3, cg = tid & 7;          // 32 rows x 8 col-groups of 16
    int grow = blockIdx.x * 32 + row;
    int b = grow >> 11, t = (grow >> 3) & 255, n = grow & 7;
    int orow = (flags & 4) ? ((b * 8 + n) * 256 + t) : grow;
    float v[16];
#pragma unroll
    for (int j = 0; j < 16; j++) v[j] = S[row][cg * 16 + j];
    if (resf) {
        const float4* rp = (const float4*)(resf + (size_t)grow * 128 + cg * 16);
#pragma unroll
        for (int j4 = 0; j4 < 4; j4++) {
            float4 rv = rp[j4];
            v[4 * j4 + 0] += rv.x; v[4 * j4 + 1] += rv.y;
            v[4 * j4 + 2] += rv.z; v[4 * j4 + 3] += rv.w;
        }
    }
    float s = 0.0f;
#pragma unroll
    for (int j = 0; j < 16; j++) s += v[j];
    s += __shfl_xor(s, 1); s += __shfl_xor(s, 2); s += __shfl_xor(s, 4);
    float mean = s * (1.0f / 128.0f);
    float vs = 0.0f;
#pragma unroll
    for (int j = 0; j < 16; j++) { float d = v[j] - mean; vs += d * d; }
    vs += __shfl_xor(vs, 1); vs += __shfl_xor(vs, 2); vs += __shfl_xor(vs, 4);
    float rstd = rsqrtf(vs * (1.0f / 128.0f) + 1e-5f);
    float y[16];
#pragma unroll
    for (int j = 0; j < 16; j++) {
        int col = cg * 16 + j;
        y[j] = (v[j] - mean) * rstd * g[col] + be[col];
    }
    if (flags & 2) {                    // sinusoidal PE, added after LN
#pragma unroll
        for (int jj = 0; jj < 8; jj++) {
            int j2 = cg * 8 + jj;       // pair index = col>>1
            float freq = expf((float)(2 * j2) * (-9.210340371976184f / 128.0f));
            float ang = (float)t * freq;
            y[2 * jj] += sinf(ang);
            y[2 * jj + 1] += cosf(ang);
        }
    }
    if (outf) {
        float4* op = (float4*)(outf + (size_t)orow * 128 + cg * 16);
#pragma unroll
        for (int j4 = 0; j4 < 4; j4++) {
            float4 o; o.x = y[4 * j4]; o.y = y[4 * j4 + 1];
            o.z = y[4 * j4 + 2]; o.w = y[4 * j4 + 3];
            op[j4] = o;
        }
    }
    if (outh) {
        bf16x8* op = (bf16x8*)(outh + (size_t)orow * hs + cg * 16);
#pragma unroll
        for (int j8 = 0; j8 < 2; j8++) {
            bf16x8 o;
#pragma unroll
            for (int e = 0; e < 8; e++) o[e] = (bf16)y[8 * j8 + e];
            op[j8] = o;
        }
        if (catsrc) {                   // fill CAT[:,128:256] from xt order
            const bf16x8* cp = (const bf16x8*)(
                catsrc + ((size_t)(b * 8 + n) * 256 + t) * 128 + cg * 16);
            bf16x8* dp = (bf16x8*)(outh + (size_t)orow * 256 + 128 + cg * 16);
            dp[0] = cp[0]; dp[1] = cp[1];
        }
    }
}

// ---------------------------------------------------------------------------
// MFMA flash attention v6 (R10-proven): chain-free math, 64 q/wave, 4-way
// intra-block key-split, single LDS combine. XCD swizzle sh = bid % NSH.
// grid = NSH * (Lq/64); block = 256 thr = 4 waves.
// Qh [sh][Lq][32], Kh [sh][Lk][32], Vth [sh][32][Lk] (bf16, V transposed).
// Output ATTh[((sh>>2)*Lq + q)*128 + (sh&3)*32 + d] (bf16).
__global__ __launch_bounds__(256) void k_mattn(
    const bf16* __restrict__ Qh, const bf16* __restrict__ Kh,
    const bf16* __restrict__ Vth, bf16* __restrict__ ATTh,
    int Lq, int Lk, int NSH) {
    int sh = blockIdx.x % NSH;
    int qblk = blockIdx.x / NSH;
    int wv = threadIdx.x >> 6;
    int lane = threadIdx.x & 63;
    int c = lane & 15, g = lane >> 4;
    int q0 = qblk * 64;

    __shared__ float O_lds[4][64][36];   // +4 pad: b128 rw <=2-way aliased
    __shared__ float L_lds[4][64];

    const float scale = 0.17677669529663687f;  // 1/sqrt(32)
    const f32x4 zero = {0, 0, 0, 0};

    bf16x8 bq[4];
#pragma unroll
    for (int qt = 0; qt < 4; qt++)
        bq[qt] = *(const bf16x8*)(
            Qh + ((size_t)sh * Lq + q0 + qt * 16 + c) * 32 + g * 8);

    int klen = Lk >> 2;                  // keys per wave
    int kbeg = wv * klen;
    const bf16* Kbase = Kh + (size_t)sh * Lk * 32 + (size_t)kbeg * 32;
    const bf16* Vbase = Vth + (size_t)sh * 32 * Lk + kbeg;

    f32x4 oT[4][2];
#pragma unroll
    for (int qt = 0; qt < 4; qt++) { oT[qt][0] = zero; oT[qt][1] = zero; }
    float lsum[4] = {0, 0, 0, 0};

    int ntiles = klen >> 5;              // enc: 2, cross: 16
    bf16x8 ka = *(const bf16x8*)(Kbase + (size_t)c * 32 + g * 8);
    bf16x8 kb = *(const bf16x8*)(Kbase + (size_t)(16 + c) * 32 + g * 8);
    bf16x4 va0 = *(const bf16x4*)(Vbase + (size_t)c * Lk + g * 4);
    bf16x4 va1 = *(const bf16x4*)(Vbase + (size_t)c * Lk + 16 + g * 4);
    bf16x4 vb0 = *(const bf16x4*)(Vbase + (size_t)(16 + c) * Lk + g * 4);
    bf16x4 vb1 = *(const bf16x4*)(Vbase + (size_t)(16 + c) * Lk + 16 + g * 4);

    for (int t = 0; t < ntiles; t++) {
        bf16x8 cka = ka, ckb = kb;
        bf16x4 cva0 = va0, cva1 = va1, cvb0 = vb0, cvb1 = vb1;
        int nk0 = ((t + 1 < ntiles) ? (t + 1) : t) << 5;
        ka = *(const bf16x8*)(Kbase + (size_t)(nk0 + c) * 32 + g * 8);
        kb = *(const bf16x8*)(Kbase + (size_t)(nk0 + 16 + c) * 32 + g * 8);
        va0 = *(const bf16x4*)(Vbase + (size_t)c * Lk + nk0 + g * 4);
        va1 = *(const bf16x4*)(Vbase + (size_t)c * Lk + nk0 + 16 + g * 4);
        vb0 = *(const bf16x4*)(Vbase + (size_t)(16 + c) * Lk + nk0 + g * 4);
        vb1 = *(const bf16x4*)(Vbase + (size_t)(16 + c) * Lk + nk0 + 16 + g * 4);

#pragma unroll
        for (int qt = 0; qt < 4; qt++) {
            f32x4 s0 = __builtin_amdgcn_mfma_f32_16x16x32_bf16(cka, bq[qt], zero, 0, 0, 0);
            f32x4 s1 = __builtin_amdgcn_mfma_f32_16x16x32_bf16(ckb, bq[qt], zero, 0, 0, 0);
            bf16x4 p0, p1;
#pragma unroll
            for (int r = 0; r < 4; r++) {
                float e0 = __expf(s0[r] * scale);
                float e1 = __expf(s1[r] * scale);
                lsum[qt] += e0 + e1;
                p0[r] = (bf16)e0;
                p1[r] = (bf16)e1;
            }
            oT[qt][0] = pv_mfma16(cva0, p0, oT[qt][0]);
            oT[qt][0] = pv_mfma16(cva1, p1, oT[qt][0]);
            oT[qt][1] = pv_mfma16(cvb0, p0, oT[qt][1]);
            oT[qt][1] = pv_mfma16(cvb1, p1, oT[qt][1]);
        }
    }

#pragma unroll
    for (int qt = 0; qt < 4; qt++) {
        float s = lsum[qt];
        s += __shfl_xor(s, 16);
        s += __shfl_xor(s, 32);
        if (g == 0) L_lds[wv][qt * 16 + c] = s;
        *(f32x4*)&O_lds[wv][qt * 16 + c][g * 4] = oT[qt][0];
        *(f32x4*)&O_lds[wv][qt * 16 + c][16 + g * 4] = oT[qt][1];
    }
    __syncthreads();

    int tid = threadIdx.x;
    int ql = tid >> 2, dq = (tid & 3) * 8;
    float ltot = L_lds[0][ql] + L_lds[1][ql] + L_lds[2][ql] + L_lds[3][ql];
    float inv = 1.0f / ltot;
    float acc[8];
#pragma unroll
    for (int j = 0; j < 8; j++) acc[j] = 0.0f;
#pragma unroll
    for (int w = 0; w < 4; w++) {
        const float* p = &O_lds[w][ql][dq];
#pragma unroll
        for (int j = 0; j < 8; j++) acc[j] += p[j];
    }
    int h = sh & 3, sb = sh >> 2;
    bf16x8 o;
#pragma unroll
    for (int j = 0; j < 8; j++) o[j] = (bf16)(acc[j] * inv);
    *(bf16x8*)(ATTh + ((size_t)sb * Lq + q0 + ql) * 128 + h * 32 + dq) = o;
}

// ---------------------------------------------------------------------------
extern "C" void kernel_launch(void* const* d_in, const int* in_sizes, int n_in,
                              void* d_out, int out_size, void* d_ws, size_t ws_size,
                              hipStream_t stream) {
    const float* vs       = (const float*)d_in[0];
    const float* semb     = (const float*)d_in[1];
    const float* r5       = (const float*)d_in[2];
    const float* A55      = (const float*)d_in[3];
    const float* bl_bias  = (const float*)d_in[4];
    const float* nl_W1    = (const float*)d_in[5];
    const float* nl_b1    = (const float*)d_in[6];
    const float* nl_W2    = (const float*)d_in[7];
    const float* nl_b2    = (const float*)d_in[8];
    const float* mlp_W1   = (const float*)d_in[9];
    const float* mlp_b1   = (const float*)d_in[10];
    const float* mlp_W2   = (const float*)d_in[11];
    const float* mlp_b2   = (const float*)d_in[12];
    const float* mlp_ln_g = (const float*)d_in[13];
    const float* mlp_ln_b = (const float*)d_in[14];
    const float* enc_qkv_W = (const float*)d_in[15];
    const float* enc_qkv_b = (const float*)d_in[16];
    const float* enc_out_W = (const float*)d_in[17];
    const float* enc_out_b = (const float*)d_in[18];
    const float* enc_ln1_g = (const float*)d_in[19];
    const float* enc_ln1_b = (const float*)d_in[20];
    const float* enc_ff_W1 = (const float*)d_in[21];
    const float* enc_ff_b1 = (const float*)d_in[22];
    const float* enc_ff_W2 = (const float*)d_in[23];
    const float* enc_ff_b2 = (const float*)d_in[24];
    const float* enc_ln2_g = (const float*)d_in[25];
    const float* enc_ln2_b = (const float*)d_in[26];
    const float* ca_Wq = (const float*)d_in[27];
    const float* ca_bq = (const float*)d_in[28];
    const float* ca_Wk = (const float*)d_in[29];
    const float* ca_bk = (const float*)d_in[30];
    const float* ca_Wv = (const float*)d_in[31];
    const float* ca_bv = (const float*)d_in[32];
    const float* ca_Wo = (const float*)d_in[33];
    const float* ca_bo = (const float*)d_in[34];
    const float* ca_ln1_g = (const float*)d_in[35];
    const float* ca_ln1_b = (const float*)d_in[36];
    const float* ca_ff_W1 = (const float*)d_in[37];
    const float* ca_ff_b1 = (const float*)d_in[38];
    const float* ca_ff_W2 = (const float*)d_in[39];
    const float* ca_ff_b2 = (const float*)d_in[40];
    const float* ca_ln2_g = (const float*)d_in[41];
    const float* ca_ln2_b = (const float*)d_in[42];
    float* out = (float*)d_out;

    // Workspace layout (byte offsets, 256-aligned)
    char* base = (char*)d_ws;
    float* b1w   = (float*)(base + 0);          //  32 KB
    float* X0    = (float*)(base + 163840);     //   4 MB
    float* X1    = (float*)(base + 4358144);    //   4 MB
    char*  QKVr  = base + 8552448;              //  12 MB region
    bf16*  Wpk   = (bf16*) (base + 25329664);   // 1.03 MB
    float* bpk   = (float*)(base + 26411008);   //   1 KB
    bf16*  X0h   = (bf16*) (base + 26412032);   //   2 MB
    bf16*  X1h   = (bf16*) (base + 28509184);   //   2 MB
    bf16*  sembh = (bf16*) (base + 30606336);   //   2 MB
    bf16*  ATTh  = (bf16*) (base + 32703488);   //   2 MB
    bf16*  Qh    = (bf16*)QKVr;                 //   2 MB
    bf16*  Kh    = (bf16*)(QKVr + 2097152);     //   2 MB
    bf16*  Vth   = (bf16*)(QKVr + 4194304);     //   2 MB
    bf16*  CATh  = (bf16*)QKVr;                 //   4 MB (after attn done)
    bf16*  Hh    = (bf16*)(QKVr + 4194304);     //  <=8 MB (after attn done)

    const int NTOK = B_ * T_ * N_;  // 8192

    // Prep (weights + semb cast + bias pack), one launch
    k_prep<<<dim3(6209), dim3(256), 0, stream>>>(
        enc_qkv_W, enc_out_W, enc_ff_W1, enc_ff_W2, ca_Wq, ca_Wk, ca_Wv, ca_Wo,
        ca_ff_W1, ca_ff_W2, mlp_W2, semb, ca_bk, ca_bv, Wpk, sembh, bpk);

    // Residual features + token MLP (resid fused into mlp1; mlp2 fused w/ LN)
    k_b1<<<dim3((B_ * (T_ - 1) + 63) / 64), dim3(64), 0, stream>>>(
        vs, r5, A55, bl_bias, nl_W1, nl_b1, nl_W2, nl_b2, b1w);
    k_mlp1<<<dim3(NTOK), dim3(128), 0, stream>>>(vs, b1w, mlp_W1, mlp_b1,
                                                 (bf16*)X1h);
    k_gemm_ln<<<dim3(256), dim3(256), 0, stream>>>(
        (bf16*)X1h, Wpk + 524288, mlp_b2, 128, nullptr, mlp_ln_g, mlp_ln_b,
        X0, X0h, 128, nullptr, 1 | 2 | 4);

    // Encoder layers
    for (int i = 0; i < LENC_; i++) {
        k_gemm4<<<dim3(768), dim3(256), 0, stream>>>(
            X0h, Wpk + i * 49152, enc_qkv_b + i * 384, nullptr, nullptr,
            Qh, Kh, Vth, NTOK, 384, 128, 0, 1);
        k_mattn<<<dim3(512), dim3(256), 0, stream>>>(
            Qh, Kh, Vth, ATTh, 256, 256, 128);
        k_gemm_ln<<<dim3(256), dim3(256), 0, stream>>>(
            ATTh, Wpk + 98304 + i * 16384, enc_out_b + i * 128, 128, X0,
            enc_ln1_g + i * 128, enc_ln1_b + i * 128, X1, X1h, 128, nullptr, 0);
        k_gemm4<<<dim3(512), dim3(256), 0, stream>>>(
            X1h, Wpk + 131072 + i * 32768, enc_ff_b1 + i * 256, nullptr, Hh,
            nullptr, nullptr, nullptr, NTOK, 256, 128, 1, 0);
        k_gemm_ln<<<dim3(256), dim3(256), 0, stream>>>(
            Hh, Wpk + 196608 + i * 32768, enc_ff_b2 + i * 128, 256, X1,
            enc_ln2_g + i * 128, enc_ln2_b + i * 128, X0, X0h, 128, nullptr, 0);
    }

    // Cross-attention (NSH = 16, Lq = Lk = 2048)
    k_gemm4<<<dim3(256), dim3(256), 0, stream>>>(
        sembh, Wpk + 262144, ca_bq, nullptr, nullptr, Qh, nullptr, nullptr,
        NTOK, 128, 128, 0, 2);
    k_gemm4<<<dim3(512), dim3(256), 0, stream>>>(
        X0h, Wpk + 278528, bpk, nullptr, nullptr, nullptr, Kh, Vth,
        NTOK, 256, 128, 0, 3);
    k_mattn<<<dim3(512), dim3(256), 0, stream>>>(
        Qh, Kh, Vth, ATTh, 2048, 2048, 16);
    // out-proj + residual(semb) + LN -> X1 fp32, CATh[:, :128] bf16 + cat fill
    k_gemm_ln<<<dim3(256), dim3(256), 0, stream>>>(
        ATTh, Wpk + 311296, ca_bo, 128, semb, ca_ln1_g, ca_ln1_b,
        X1, CATh, 256, X0h, 0);
    k_gemm4<<<dim3(1024), dim3(256), 0, stream>>>(
        CATh, Wpk + 327680, ca_ff_b1, nullptr, Hh, nullptr, nullptr, nullptr,
        NTOK, 512, 256, 1, 0);
    k_gemm_ln<<<dim3(256), dim3(256), 0, stream>>>(
        Hh, Wpk + 458752, ca_ff_b2, 512, X1, ca_ln2_g, ca_ln2_b,
        out, nullptr, 128, nullptr, 0);
}

// Round 12
// 338.219 us; speedup vs baseline: 1.3422x; 1.1055x over previous
//
#include <hip/hip_runtime.h>
#include <math.h>

// Problem constants
#define B_ 4
#define T_ 256
#define N_ 8
#define D_ 128
#define NH_ 4
#define HD_ 32
#define LENC_ 2
#define MLPH_ 32
#define NL_SCALE_ 0.1f

typedef __bf16 bf16;
typedef __attribute__((ext_vector_type(2))) __bf16 bf16x2;
typedef __attribute__((ext_vector_type(4))) __bf16 bf16x4;
typedef __attribute__((ext_vector_type(8))) __bf16 bf16x8;
typedef __attribute__((ext_vector_type(4))) float f32x4;

__device__ __forceinline__ f32x4 pv_mfma16(bf16x4 a, bf16x4 b, f32x4 c) {
#if __has_builtin(__builtin_amdgcn_mfma_f32_16x16x16_bf16)
    return __builtin_amdgcn_mfma_f32_16x16x16_bf16(a, b, c, 0, 0, 0);
#else
    typedef __attribute__((ext_vector_type(4))) short s4;
    union U { bf16x4 h; s4 s; };
    U ua, ub; ua.h = a; ub.h = b;
    return __builtin_amdgcn_mfma_f32_16x16x16bf16_1k(ua.s, ub.s, c, 0, 0, 0);
#endif
}

__device__ __forceinline__ float gelu_f(float x) {
    return 0.5f * x * (1.0f + erff(x * 0.7071067811865476f));
}

// ---------------------------------------------------------------------------
// Merged prep: weight pack fp32->bf16, state_emb->bf16, bias pack.
__global__ void k_prep(const float* __restrict__ eqkvW, const float* __restrict__ eoutW,
                       const float* __restrict__ eff1, const float* __restrict__ eff2,
                       const float* __restrict__ wq, const float* __restrict__ wk,
                       const float* __restrict__ wv, const float* __restrict__ wo,
                       const float* __restrict__ cff1, const float* __restrict__ cff2,
                       const float* __restrict__ mlpW2, const float* __restrict__ semb,
                       const float* __restrict__ bk, const float* __restrict__ bv,
                       bf16* __restrict__ Wpk, bf16* __restrict__ sembh,
                       float* __restrict__ bpk) {
    int i = blockIdx.x * 256 + threadIdx.x;
    if (i < 540672) {
        const float* src; int off;
        if      (i < 98304)  { src = eqkvW; off = 0; }
        else if (i < 131072) { src = eoutW; off = 98304; }
        else if (i < 196608) { src = eff1;  off = 131072; }
        else if (i < 262144) { src = eff2;  off = 196608; }
        else if (i < 278528) { src = wq;    off = 262144; }
        else if (i < 294912) { src = wk;    off = 278528; }
        else if (i < 311296) { src = wv;    off = 294912; }
        else if (i < 327680) { src = wo;    off = 311296; }
        else if (i < 458752) { src = cff1;  off = 327680; }
        else if (i < 524288) { src = cff2;  off = 458752; }
        else                 { src = mlpW2; off = 524288; }
        Wpk[i] = (bf16)src[i - off];
    } else if (i < 540672 + 1048576) {
        int j = i - 540672;
        sembh[j] = (bf16)semb[j];
    } else if (i < 540672 + 1048576 + 256) {
        int t = i - 540672 - 1048576;
        bpk[t] = (t < 128) ? bk[t] : bv[t - 128];
    }
}

// ---------------------------------------------------------------------------
// K1: b1[b,t,m], t in [0,T-1)
__global__ void k_b1(const float* __restrict__ vs, const float* __restrict__ r5,
                     const float* __restrict__ A55, const float* __restrict__ bl_bias,
                     const float* __restrict__ nlW1, const float* __restrict__ nlb1,
                     const float* __restrict__ nlW2, const float* __restrict__ nlb2,
                     float* __restrict__ b1w) {
    int idx = blockIdx.x * blockDim.x + threadIdx.x;
    if (idx >= B_ * (T_ - 1)) return;
    int b = idx / (T_ - 1), t = idx % (T_ - 1);
    float x[N_];
    for (int n = 0; n < N_; n++) x[n] = vs[(b * T_ + t) * N_ + n];
    float h[MLPH_];
    for (int j = 0; j < MLPH_; j++) {
        float a = nlb1[j];
        for (int n = 0; n < N_; n++) a += x[n] * nlW1[j * N_ + n];
        h[j] = gelu_f(a);
    }
    for (int m = 0; m < N_; m++) {
        float lin = r5[m];
        for (int n = 0; n < N_; n++) lin += x[n] * A55[m * N_ + n];
        float nl = nlb2[m];
        for (int j = 0; j < MLPH_; j++) nl += h[j] * nlW2[m * MLPH_ + j];
        b1w[idx * N_ + m] = lin + NL_SCALE_ * nl + bl_bias[m];
    }
}

// ---------------------------------------------------------------------------
// K3a: per-token MLP layer1 (16 -> 128, gelu) with residual features inline.
__global__ void k_mlp1(const float* __restrict__ vs, const float* __restrict__ b1w,
                       const float* __restrict__ W1, const float* __restrict__ b1,
                       bf16* __restrict__ H1h) {
    int tok = blockIdx.x;                  // b*2048 + t*8 + n
    int d = threadIdx.x;                   // 128
    int b = tok >> 11, t = (tok >> 3) & 255, n = tok & 7;
    __shared__ float f[16];
    if (d < 16) {
        const int SC[4] = {1, 2, 3, 5};
        int lag = d >> 2, si = d & 3, k = SC[si];
        int tp = t - lag;
        float r = 0.0f;
        if (tp >= 0 && tp < T_ - k) {
            float lx0 = logf(fmaxf(vs[(b * T_ + tp) * N_ + n], 1e-6f));
            float lx1 = logf(fmaxf(vs[(b * T_ + tp + k) * N_ + n], 1e-6f));
            float a = lx1 - lx0;
            a = fminf(fmaxf(a, -2.5f * (float)k), 2.0f * (float)k);
            float bk = 0.0f;
            for (int i = 0; i < k; i++) bk += b1w[(b * (T_ - 1) + tp + i) * N_ + n];
            r = a - bk;
        }
        f[d] = r;
    }
    __syncthreads();
    float a = b1[d];
    const float* w = W1 + d * 16;
#pragma unroll
    for (int c = 0; c < 16; c++) a += f[c] * w[c];
    H1h[(size_t)tok * 128 + d] = (bf16)gelu_f(a);
}

// ---------------------------------------------------------------------------
// Wide MFMA GEMM body: block = 64 rows x 64 cols, wave = 16 rows x 64 cols.
// Modes: 0 row-major; 1 enc QKV scatter; 2 cross Q scatter; 3 cross KV.
__device__ __forceinline__ void gemm4_body(
    int bid, const bf16* __restrict__ A, const bf16* __restrict__ W,
    const float* __restrict__ bias, float* __restrict__ Cf,
    bf16* __restrict__ Ch, bf16* __restrict__ dq, bf16* __restrict__ dk,
    bf16* __restrict__ dvv, int N, int K, int act, int mode) {
    int lane = threadIdx.x & 63;
    int wv = threadIdx.x >> 6;
    int c = lane & 15, g = lane >> 4;
    int nN = N >> 6;
    int tn = bid % nN, tm = bid / nN;
    int row0 = tm * 64 + wv * 16;
    int cb = tn * 64;

    const bf16x8* Ap  = (const bf16x8*)(A + (size_t)(row0 + c) * K) + g;
    const bf16x8* Wp0 = (const bf16x8*)(W + (size_t)(cb + c) * K) + g;
    const bf16x8* Wp1 = (const bf16x8*)(W + (size_t)(cb + 16 + c) * K) + g;
    const bf16x8* Wp2 = (const bf16x8*)(W + (size_t)(cb + 32 + c) * K) + g;
    const bf16x8* Wp3 = (const bf16x8*)(W + (size_t)(cb + 48 + c) * K) + g;
    f32x4 a0 = {0, 0, 0, 0}, a1 = {0, 0, 0, 0};
    f32x4 a2 = {0, 0, 0, 0}, a3 = {0, 0, 0, 0};
    int nk = K >> 5;
    for (int k = 0; k < nk; k++) {
        bf16x8 av = Ap[k * 4];
        a0 = __builtin_amdgcn_mfma_f32_16x16x32_bf16(av, Wp0[k * 4], a0, 0, 0, 0);
        a1 = __builtin_amdgcn_mfma_f32_16x16x32_bf16(av, Wp1[k * 4], a1, 0, 0, 0);
        a2 = __builtin_amdgcn_mfma_f32_16x16x32_bf16(av, Wp2[k * 4], a2, 0, 0, 0);
        a3 = __builtin_amdgcn_mfma_f32_16x16x32_bf16(av, Wp3[k * 4], a3, 0, 0, 0);
    }
    int rowb = row0 + g * 4;
#pragma unroll
    for (int ct = 0; ct < 4; ct++) {
        f32x4 acc = (ct == 0) ? a0 : (ct == 1) ? a1 : (ct == 2) ? a2 : a3;
        int col = cb + ct * 16 + c;
        float bvv = bias[col];
#pragma unroll
        for (int i = 0; i < 4; i++) {
            float v = acc[i] + bvv;
            if (act) v = gelu_f(v);
            int row = rowb + i;
            if (mode == 0) {
                if (Cf) Cf[(size_t)row * N + col] = v;
                if (Ch) Ch[(size_t)row * N + col] = (bf16)v;
            } else if (mode == 1) {
                int s = row >> 8, t = row & 255;
                int h = (col >> 5) & 3, d = col & 31;
                int sh = s * 4 + h;
                if (col < 128)      dq[((size_t)sh * 256 + t) * 32 + d] = (bf16)v;
                else if (col < 256) dk[((size_t)sh * 256 + t) * 32 + d] = (bf16)v;
                else                dvv[((size_t)sh * 32 + d) * 256 + t] = (bf16)v;
            } else if (mode == 2) {
                int b = row >> 11, ll = row & 2047;
                int h = col >> 5, d = col & 31;
                dq[((size_t)(b * 4 + h) * 2048 + ll) * 32 + d] = (bf16)v;
            } else {
                int b = row >> 11, n = (row >> 8) & 7, t = row & 255;
                int ll = t * 8 + n;
                int h = (col >> 5) & 3, d = col & 31;
                if (col < 128) dk[((size_t)(b * 4 + h) * 2048 + ll) * 32 + d] = (bf16)v;
                else           dvv[((size_t)(b * 4 + h) * 32 + d) * 2048 + ll] = (bf16)v;
            }
        }
    }
}

__global__ __launch_bounds__(256) void k_gemm4(
    const bf16* __restrict__ A, const bf16* __restrict__ W,
    const float* __restrict__ bias, bf16* __restrict__ dq,
    bf16* __restrict__ dk, bf16* __restrict__ dvv, int N, int K, int mode) {
    gemm4_body(blockIdx.x, A, W, bias, nullptr, nullptr, dq, dk, dvv,
               N, K, 0, mode);
}

// Cross Q-proj (blocks 0..255) + KV-proj (blocks 256..767) in one dispatch.
__global__ __launch_bounds__(256) void k_qkvc(
    const bf16* __restrict__ sembh, const bf16* __restrict__ Wq,
    const float* __restrict__ bq, const bf16* __restrict__ X0h,
    const bf16* __restrict__ Wkv, const float* __restrict__ bkv,
    bf16* __restrict__ Qh, bf16* __restrict__ Kh, bf16* __restrict__ Vth) {
    if (blockIdx.x < 256)
        gemm4_body(blockIdx.x, sembh, Wq, bq, nullptr, nullptr,
                   Qh, nullptr, nullptr, 128, 128, 0, 2);
    else
        gemm4_body(blockIdx.x - 256, X0h, Wkv, bkv, nullptr, nullptr,
                   nullptr, Kh, Vth, 256, 128, 0, 3);
}

// ---------------------------------------------------------------------------
// Fused GEMM(N=128) + [gelu] + LayerNorm + [PE] + writes (used for mlp W2).
// flags: 1=gelu-before-LN, 2=add-PE-after-LN, 4=transpose-out-row (xt order).
__global__ __launch_bounds__(256) void k_gemm_ln(
    const bf16* __restrict__ A, const bf16* __restrict__ W,
    const float* __restrict__ bias, int K,
    const float* __restrict__ resf,
    const float* __restrict__ g, const float* __restrict__ be,
    float* __restrict__ outf, bf16* __restrict__ outh, int hs, int flags) {
    __shared__ float S[32][132];
    int tid = threadIdx.x;
    int w = tid >> 6, lane = tid & 63;
    int c = lane & 15, gq = lane >> 4;
    int r0 = blockIdx.x * 32 + (w >> 1) * 16;
    int cb = (w & 1) * 64;

    const bf16x8* Ap  = (const bf16x8*)(A + (size_t)(r0 + c) * K) + gq;
    const bf16x8* Wp0 = (const bf16x8*)(W + (size_t)(cb + c) * K) + gq;
    const bf16x8* Wp1 = (const bf16x8*)(W + (size_t)(cb + 16 + c) * K) + gq;
    const bf16x8* Wp2 = (const bf16x8*)(W + (size_t)(cb + 32 + c) * K) + gq;
    const bf16x8* Wp3 = (const bf16x8*)(W + (size_t)(cb + 48 + c) * K) + gq;
    f32x4 a0 = {0, 0, 0, 0}, a1 = {0, 0, 0, 0};
    f32x4 a2 = {0, 0, 0, 0}, a3 = {0, 0, 0, 0};
    int nk = K >> 5;
    for (int k = 0; k < nk; k++) {
        bf16x8 av = Ap[k * 4];
        a0 = __builtin_amdgcn_mfma_f32_16x16x32_bf16(av, Wp0[k * 4], a0, 0, 0, 0);
        a1 = __builtin_amdgcn_mfma_f32_16x16x32_bf16(av, Wp1[k * 4], a1, 0, 0, 0);
        a2 = __builtin_amdgcn_mfma_f32_16x16x32_bf16(av, Wp2[k * 4], a2, 0, 0, 0);
        a3 = __builtin_amdgcn_mfma_f32_16x16x32_bf16(av, Wp3[k * 4], a3, 0, 0, 0);
    }
    int lrow = (w >> 1) * 16 + gq * 4;
    float b0 = bias[cb + c], b1v = bias[cb + 16 + c];
    float b2v = bias[cb + 32 + c], b3v = bias[cb + 48 + c];
#pragma unroll
    for (int r = 0; r < 4; r++) {
        float v0 = a0[r] + b0, v1 = a1[r] + b1v;
        float v2 = a2[r] + b2v, v3 = a3[r] + b3v;
        if (flags & 1) {
            v0 = gelu_f(v0); v1 = gelu_f(v1); v2 = gelu_f(v2); v3 = gelu_f(v3);
        }
        S[lrow + r][cb + c] = v0;       S[lrow + r][cb + 16 + c] = v1;
        S[lrow + r][cb + 32 + c] = v2;  S[lrow + r][cb + 48 + c] = v3;
    }
    __syncthreads();

    int row = tid >> 3, cg = tid & 7;
    int grow = blockIdx.x * 32 + row;
    int b = grow >> 11, t = (grow >> 3) & 255, n = grow & 7;
    int orow = (flags & 4) ? ((b * 8 + n) * 256 + t) : grow;
    float v[16];
#pragma unroll
    for (int j = 0; j < 16; j++) v[j] = S[row][cg * 16 + j];
    if (resf) {
        const float4* rp = (const float4*)(resf + (size_t)grow * 128 + cg * 16);
#pragma unroll
        for (int j4 = 0; j4 < 4; j4++) {
            float4 rv = rp[j4];
            v[4 * j4 + 0] += rv.x; v[4 * j4 + 1] += rv.y;
            v[4 * j4 + 2] += rv.z; v[4 * j4 + 3] += rv.w;
        }
    }
    float s = 0.0f;
#pragma unroll
    for (int j = 0; j < 16; j++) s += v[j];
    s += __shfl_xor(s, 1); s += __shfl_xor(s, 2); s += __shfl_xor(s, 4);
    float mean = s * (1.0f / 128.0f);
    float vs = 0.0f;
#pragma unroll
    for (int j = 0; j < 16; j++) { float d = v[j] - mean; vs += d * d; }
    vs += __shfl_xor(vs, 1); vs += __shfl_xor(vs, 2); vs += __shfl_xor(vs, 4);
    float rstd = rsqrtf(vs * (1.0f / 128.0f) + 1e-5f);
    float y[16];
#pragma unroll
    for (int j = 0; j < 16; j++) {
        int col = cg * 16 + j;
        y[j] = (v[j] - mean) * rstd * g[col] + be[col];
    }
    if (flags & 2) {
#pragma unroll
        for (int jj = 0; jj < 8; jj++) {
            int j2 = cg * 8 + jj;
            float freq = expf((float)(2 * j2) * (-9.210340371976184f / 128.0f));
            float ang = (float)t * freq;
            y[2 * jj] += sinf(ang);
            y[2 * jj + 1] += cosf(ang);
        }
    }
    if (outf) {
        float4* op = (float4*)(outf + (size_t)orow * 128 + cg * 16);
#pragma unroll
        for (int j4 = 0; j4 < 4; j4++) {
            float4 o; o.x = y[4 * j4]; o.y = y[4 * j4 + 1];
            o.z = y[4 * j4 + 2]; o.w = y[4 * j4 + 3];
            op[j4] = o;
        }
    }
    if (outh) {
        bf16x8* op = (bf16x8*)(outh + (size_t)orow * hs + cg * 16);
#pragma unroll
        for (int j8 = 0; j8 < 2; j8++) {
            bf16x8 o;
#pragma unroll
            for (int e = 0; e < 8; e++) o[e] = (bf16)y[8 * j8 + e];
            op[j8] = o;
        }
    }
}

// ---------------------------------------------------------------------------
// Encoder tail megafusion: outproj + res + LN1 + ff1(gelu) + ff2 + res + LN2.
// Row-local: block = 32 rows, all intermediates in LDS. grid = 256.
__global__ __launch_bounds__(256) void k_enc_tail(
    const bf16* __restrict__ ATTh, const bf16* __restrict__ Wo,
    const float* __restrict__ bo, const float* __restrict__ X0res,
    const float* __restrict__ g1, const float* __restrict__ be1,
    const bf16* __restrict__ W1, const float* __restrict__ bf1,
    const bf16* __restrict__ W2, const float* __restrict__ bf2,
    const float* __restrict__ g2, const float* __restrict__ be2,
    float* __restrict__ X0out, bf16* __restrict__ X0hout) {
    __shared__ float S[32][132];
    __shared__ float X1f[32][132];
    __shared__ bf16 X1h[32][136];
    __shared__ bf16 H[32][264];
    int tid = threadIdx.x;
    int w = tid >> 6, lane = tid & 63;
    int c = lane & 15, gq = lane >> 4;
    int r0l = (w >> 1) * 16;
    int cb = (w & 1) * 64;
    int blk = blockIdx.x;
    const f32x4 zero = {0, 0, 0, 0};

    // Phase 1: outproj (K=128, N=128), A = ATTh global
    {
        const bf16x8* Ap  = (const bf16x8*)(ATTh + (size_t)(blk * 32 + r0l + c) * 128) + gq;
        const bf16x8* Wp0 = (const bf16x8*)(Wo + (size_t)(cb + c) * 128) + gq;
        const bf16x8* Wp1 = (const bf16x8*)(Wo + (size_t)(cb + 16 + c) * 128) + gq;
        const bf16x8* Wp2 = (const bf16x8*)(Wo + (size_t)(cb + 32 + c) * 128) + gq;
        const bf16x8* Wp3 = (const bf16x8*)(Wo + (size_t)(cb + 48 + c) * 128) + gq;
        f32x4 a0 = zero, a1 = zero, a2 = zero, a3 = zero;
#pragma unroll
        for (int k = 0; k < 4; k++) {
            bf16x8 av = Ap[k * 4];
            a0 = __builtin_amdgcn_mfma_f32_16x16x32_bf16(av, Wp0[k * 4], a0, 0, 0, 0);
            a1 = __builtin_amdgcn_mfma_f32_16x16x32_bf16(av, Wp1[k * 4], a1, 0, 0, 0);
            a2 = __builtin_amdgcn_mfma_f32_16x16x32_bf16(av, Wp2[k * 4], a2, 0, 0, 0);
            a3 = __builtin_amdgcn_mfma_f32_16x16x32_bf16(av, Wp3[k * 4], a3, 0, 0, 0);
        }
        int lrow = r0l + gq * 4;
        float b0 = bo[cb + c], b1v = bo[cb + 16 + c];
        float b2v = bo[cb + 32 + c], b3v = bo[cb + 48 + c];
#pragma unroll
        for (int r = 0; r < 4; r++) {
            S[lrow + r][cb + c] = a0[r] + b0;
            S[lrow + r][cb + 16 + c] = a1[r] + b1v;
            S[lrow + r][cb + 32 + c] = a2[r] + b2v;
            S[lrow + r][cb + 48 + c] = a3[r] + b3v;
        }
    }
    __syncthreads();
    // Epilogue 1: + X0 residual, LN1 -> X1f (fp32) + X1h (bf16), LDS only
    {
        int row = tid >> 3, cg = tid & 7;
        float v[16];
        const float4* rp = (const float4*)(X0res + (size_t)(blk * 32 + row) * 128 + cg * 16);
#pragma unroll
        for (int j4 = 0; j4 < 4; j4++) {
            float4 rv = rp[j4];
            v[4 * j4 + 0] = S[row][cg * 16 + 4 * j4 + 0] + rv.x;
            v[4 * j4 + 1] = S[row][cg * 16 + 4 * j4 + 1] + rv.y;
            v[4 * j4 + 2] = S[row][cg * 16 + 4 * j4 + 2] + rv.z;
            v[4 * j4 + 3] = S[row][cg * 16 + 4 * j4 + 3] + rv.w;
        }
        float s = 0.0f;
#pragma unroll
        for (int j = 0; j < 16; j++) s += v[j];
        s += __shfl_xor(s, 1); s += __shfl_xor(s, 2); s += __shfl_xor(s, 4);
        float mean = s * (1.0f / 128.0f);
        float vs = 0.0f;
#pragma unroll
        for (int j = 0; j < 16; j++) { float d = v[j] - mean; vs += d * d; }
        vs += __shfl_xor(vs, 1); vs += __shfl_xor(vs, 2); vs += __shfl_xor(vs, 4);
        float rstd = rsqrtf(vs * (1.0f / 128.0f) + 1e-5f);
#pragma unroll
        for (int j = 0; j < 16; j++) {
            int col = cg * 16 + j;
            float y = (v[j] - mean) * rstd * g1[col] + be1[col];
            X1f[row][col] = y;
            X1h[row][col] = (bf16)y;
        }
    }
    __syncthreads();
    // Phase 2: ff1 (K=128, N=256), A = X1h LDS -> H (gelu, bf16)
    {
        bf16x8 af[4];
#pragma unroll
        for (int k = 0; k < 4; k++)
            af[k] = *(const bf16x8*)&X1h[r0l + c][k * 32 + gq * 8];
#pragma unroll
        for (int ci = 0; ci < 2; ci++) {
            int cb2 = cb + ci * 128;
            const bf16x8* Wp0 = (const bf16x8*)(W1 + (size_t)(cb2 + c) * 128) + gq;
            const bf16x8* Wp1 = (const bf16x8*)(W1 + (size_t)(cb2 + 16 + c) * 128) + gq;
            const bf16x8* Wp2 = (const bf16x8*)(W1 + (size_t)(cb2 + 32 + c) * 128) + gq;
            const bf16x8* Wp3 = (const bf16x8*)(W1 + (size_t)(cb2 + 48 + c) * 128) + gq;
            f32x4 a0 = zero, a1 = zero, a2 = zero, a3 = zero;
#pragma unroll
            for (int k = 0; k < 4; k++) {
                a0 = __builtin_amdgcn_mfma_f32_16x16x32_bf16(af[k], Wp0[k * 4], a0, 0, 0, 0);
                a1 = __builtin_amdgcn_mfma_f32_16x16x32_bf16(af[k], Wp1[k * 4], a1, 0, 0, 0);
                a2 = __builtin_amdgcn_mfma_f32_16x16x32_bf16(af[k], Wp2[k * 4], a2, 0, 0, 0);
                a3 = __builtin_amdgcn_mfma_f32_16x16x32_bf16(af[k], Wp3[k * 4], a3, 0, 0, 0);
            }
            int lrow = r0l + gq * 4;
#pragma unroll
            for (int r = 0; r < 4; r++) {
                H[lrow + r][cb2 + c]      = (bf16)gelu_f(a0[r] + bf1[cb2 + c]);
                H[lrow + r][cb2 + 16 + c] = (bf16)gelu_f(a1[r] + bf1[cb2 + 16 + c]);
                H[lrow + r][cb2 + 32 + c] = (bf16)gelu_f(a2[r] + bf1[cb2 + 32 + c]);
                H[lrow + r][cb2 + 48 + c] = (bf16)gelu_f(a3[r] + bf1[cb2 + 48 + c]);
            }
        }
    }
    __syncthreads();
    // Phase 3: ff2 (K=256, N=128), A = H LDS -> S
    {
        bf16x8 af[8];
#pragma unroll
        for (int k = 0; k < 8; k++)
            af[k] = *(const bf16x8*)&H[r0l + c][k * 32 + gq * 8];
        const bf16x8* Wp0 = (const bf16x8*)(W2 + (size_t)(cb + c) * 256) + gq;
        const bf16x8* Wp1 = (const bf16x8*)(W2 + (size_t)(cb + 16 + c) * 256) + gq;
        const bf16x8* Wp2 = (const bf16x8*)(W2 + (size_t)(cb + 32 + c) * 256) + gq;
        const bf16x8* Wp3 = (const bf16x8*)(W2 + (size_t)(cb + 48 + c) * 256) + gq;
        f32x4 a0 = zero, a1 = zero, a2 = zero, a3 = zero;
#pragma unroll
        for (int k = 0; k < 8; k++) {
            a0 = __builtin_amdgcn_mfma_f32_16x16x32_bf16(af[k], Wp0[k * 4], a0, 0, 0, 0);
            a1 = __builtin_amdgcn_mfma_f32_16x16x32_bf16(af[k], Wp1[k * 4], a1, 0, 0, 0);
            a2 = __builtin_amdgcn_mfma_f32_16x16x32_bf16(af[k], Wp2[k * 4], a2, 0, 0, 0);
            a3 = __builtin_amdgcn_mfma_f32_16x16x32_bf16(af[k], Wp3[k * 4], a3, 0, 0, 0);
        }
        int lrow = r0l + gq * 4;
        float b0 = bf2[cb + c], b1v = bf2[cb + 16 + c];
        float b2v = bf2[cb + 32 + c], b3v = bf2[cb + 48 + c];
#pragma unroll
        for (int r = 0; r < 4; r++) {
            S[lrow + r][cb + c] = a0[r] + b0;
            S[lrow + r][cb + 16 + c] = a1[r] + b1v;
            S[lrow + r][cb + 32 + c] = a2[r] + b2v;
            S[lrow + r][cb + 48 + c] = a3[r] + b3v;
        }
    }
    __syncthreads();
    // Epilogue 3: + X1 residual, LN2 -> X0out fp32 + X0hout bf16 (global)
    {
        int row = tid >> 3, cg = tid & 7;
        float v[16];
#pragma unroll
        for (int j = 0; j < 16; j++)
            v[j] = S[row][cg * 16 + j] + X1f[row][cg * 16 + j];
        float s = 0.0f;
#pragma unroll
        for (int j = 0; j < 16; j++) s += v[j];
        s += __shfl_xor(s, 1); s += __shfl_xor(s, 2); s += __shfl_xor(s, 4);
        float mean = s * (1.0f / 128.0f);
        float vs = 0.0f;
#pragma unroll
        for (int j = 0; j < 16; j++) { float d = v[j] - mean; vs += d * d; }
        vs += __shfl_xor(vs, 1); vs += __shfl_xor(vs, 2); vs += __shfl_xor(vs, 4);
        float rstd = rsqrtf(vs * (1.0f / 128.0f) + 1e-5f);
        size_t grow = (size_t)(blk * 32 + row);
        float4* of = (float4*)(X0out + grow * 128 + cg * 16);
        bf16x8* oh = (bf16x8*)(X0hout + grow * 128 + cg * 16);
        float y[16];
#pragma unroll
        for (int j = 0; j < 16; j++) {
            int col = cg * 16 + j;
            y[j] = (v[j] - mean) * rstd * g2[col] + be2[col];
        }
#pragma unroll
        for (int j4 = 0; j4 < 4; j4++) {
            float4 o; o.x = y[4 * j4]; o.y = y[4 * j4 + 1];
            o.z = y[4 * j4 + 2]; o.w = y[4 * j4 + 3];
            of[j4] = o;
        }
#pragma unroll
        for (int j8 = 0; j8 < 2; j8++) {
            bf16x8 o;
#pragma unroll
            for (int e = 0; e < 8; e++) o[e] = (bf16)y[8 * j8 + e];
            oh[j8] = o;
        }
    }
}

// ---------------------------------------------------------------------------
// Cross tail megafusion: outproj + res(semb) + LN1 -> s1; concat(s1, enc-out)
// -> ff1(512, gelu) -> ff2 -> +s1 -> final LN -> d_out. grid = 256.
__global__ __launch_bounds__(256) void k_cross_tail(
    const bf16* __restrict__ ATTh, const bf16* __restrict__ Wo,
    const float* __restrict__ bo, const float* __restrict__ semb,
    const float* __restrict__ g1, const float* __restrict__ be1,
    const bf16* __restrict__ X0h, const bf16* __restrict__ W1,
    const float* __restrict__ bf1, const bf16* __restrict__ W2,
    const float* __restrict__ bf2, const float* __restrict__ g2,
    const float* __restrict__ be2, float* __restrict__ outp) {
    __shared__ float S[32][132];
    __shared__ bf16 s1h[32][136];
    __shared__ bf16 H[32][520];
    int tid = threadIdx.x;
    int w = tid >> 6, lane = tid & 63;
    int c = lane & 15, gq = lane >> 4;
    int r0l = (w >> 1) * 16;
    int cb = (w & 1) * 64;
    int blk = blockIdx.x;
    const f32x4 zero = {0, 0, 0, 0};

    // Prefetch CAT second-half A-frags from X0h (xt-order remap, read-only)
    bf16x8 agl[4];
    {
        int tr = blk * 32 + r0l + c;
        int b = tr >> 11, t = (tr >> 3) & 255, n = tr & 7;
        const bf16* xrow = X0h + ((size_t)((b * 8 + n) * 256 + t)) * 128;
#pragma unroll
        for (int k = 0; k < 4; k++)
            agl[k] = *(const bf16x8*)(xrow + k * 32 + gq * 8);
    }

    // Phase 1: outproj (K=128, N=128), A = ATTh global
    {
        const bf16x8* Ap  = (const bf16x8*)(ATTh + (size_t)(blk * 32 + r0l + c) * 128) + gq;
        const bf16x8* Wp0 = (const bf16x8*)(Wo + (size_t)(cb + c) * 128) + gq;
        const bf16x8* Wp1 = (const bf16x8*)(Wo + (size_t)(cb + 16 + c) * 128) + gq;
        const bf16x8* Wp2 = (const bf16x8*)(Wo + (size_t)(cb + 32 + c) * 128) + gq;
        const bf16x8* Wp3 = (const bf16x8*)(Wo + (size_t)(cb + 48 + c) * 128) + gq;
        f32x4 a0 = zero, a1 = zero, a2 = zero, a3 = zero;
#pragma unroll
        for (int k = 0; k < 4; k++) {
            bf16x8 av = Ap[k * 4];
            a0 = __builtin_amdgcn_mfma_f32_16x16x32_bf16(av, Wp0[k * 4], a0, 0, 0, 0);
            a1 = __builtin_amdgcn_mfma_f32_16x16x32_bf16(av, Wp1[k * 4], a1, 0, 0, 0);
            a2 = __builtin_amdgcn_mfma_f32_16x16x32_bf16(av, Wp2[k * 4], a2, 0, 0, 0);
            a3 = __builtin_amdgcn_mfma_f32_16x16x32_bf16(av, Wp3[k * 4], a3, 0, 0, 0);
        }
        int lrow = r0l + gq * 4;
        float b0 = bo[cb + c], b1v = bo[cb + 16 + c];
        float b2v = bo[cb + 32 + c], b3v = bo[cb + 48 + c];
#pragma unroll
        for (int r = 0; r < 4; r++) {
            S[lrow + r][cb + c] = a0[r] + b0;
            S[lrow + r][cb + 16 + c] = a1[r] + b1v;
            S[lrow + r][cb + 32 + c] = a2[r] + b2v;
            S[lrow + r][cb + 48 + c] = a3[r] + b3v;
        }
    }
    __syncthreads();
    // Epilogue 1: + semb residual, LN1 -> s1h (bf16 LDS)
    {
        int row = tid >> 3, cg = tid & 7;
        float v[16];
        const float4* rp = (const float4*)(semb + (size_t)(blk * 32 + row) * 128 + cg * 16);
#pragma unroll
        for (int j4 = 0; j4 < 4; j4++) {
            float4 rv = rp[j4];
            v[4 * j4 + 0] = S[row][cg * 16 + 4 * j4 + 0] + rv.x;
            v[4 * j4 + 1] = S[row][cg * 16 + 4 * j4 + 1] + rv.y;
            v[4 * j4 + 2] = S[row][cg * 16 + 4 * j4 + 2] + rv.z;
            v[4 * j4 + 3] = S[row][cg * 16 + 4 * j4 + 3] + rv.w;
        }
        float s = 0.0f;
#pragma unroll
        for (int j = 0; j < 16; j++) s += v[j];
        s += __shfl_xor(s, 1); s += __shfl_xor(s, 2); s += __shfl_xor(s, 4);
        float mean = s * (1.0f / 128.0f);
        float vs = 0.0f;
#pragma unroll
        for (int j = 0; j < 16; j++) { float d = v[j] - mean; vs += d * d; }
        vs += __shfl_xor(vs, 1); vs += __shfl_xor(vs, 2); vs += __shfl_xor(vs, 4);
        float rstd = rsqrtf(vs * (1.0f / 128.0f) + 1e-5f);
#pragma unroll
        for (int j = 0; j < 16; j++) {
            int col = cg * 16 + j;
            s1h[row][col] = (bf16)((v[j] - mean) * rstd * g1[col] + be1[col]);
        }
    }
    __syncthreads();
    // Phase 2: ff1 (K=256: cols 0-127 from s1h, 128-255 from agl; N=512)
    {
        bf16x8 afl[4];
#pragma unroll
        for (int k = 0; k < 4; k++)
            afl[k] = *(const bf16x8*)&s1h[r0l + c][k * 32 + gq * 8];
#pragma unroll
        for (int ci = 0; ci < 4; ci++) {
            int cb2 = cb + ci * 128;
            const bf16x8* Wp0 = (const bf16x8*)(W1 + (size_t)(cb2 + c) * 256) + gq;
            const bf16x8* Wp1 = (const bf16x8*)(W1 + (size_t)(cb2 + 16 + c) * 256) + gq;
            const bf16x8* Wp2 = (const bf16x8*)(W1 + (size_t)(cb2 + 32 + c) * 256) + gq;
            const bf16x8* Wp3 = (const bf16x8*)(W1 + (size_t)(cb2 + 48 + c) * 256) + gq;
            f32x4 a0 = zero, a1 = zero, a2 = zero, a3 = zero;
#pragma unroll
            for (int k = 0; k < 8; k++) {
                bf16x8 av = (k < 4) ? afl[k] : agl[k - 4];
                a0 = __builtin_amdgcn_mfma_f32_16x16x32_bf16(av, Wp0[k * 4], a0, 0, 0, 0);
                a1 = __builtin_amdgcn_mfma_f32_16x16x32_bf16(av, Wp1[k * 4], a1, 0, 0, 0);
                a2 = __builtin_amdgcn_mfma_f32_16x16x32_bf16(av, Wp2[k * 4], a2, 0, 0, 0);
                a3 = __builtin_amdgcn_mfma_f32_16x16x32_bf16(av, Wp3[k * 4], a3, 0, 0, 0);
            }
            int lrow = r0l + gq * 4;
#pragma unroll
            for (int r = 0; r < 4; r++) {
                H[lrow + r][cb2 + c]      = (bf16)gelu_f(a0[r] + bf1[cb2 + c]);
                H[lrow + r][cb2 + 16 + c] = (bf16)gelu_f(a1[r] + bf1[cb2 + 16 + c]);
                H[lrow + r][cb2 + 32 + c] = (bf16)gelu_f(a2[r] + bf1[cb2 + 32 + c]);
                H[lrow + r][cb2 + 48 + c] = (bf16)gelu_f(a3[r] + bf1[cb2 + 48 + c]);
            }
        }
    }
    __syncthreads();
    // Phase 3: ff2 (K=512, N=128), A = H LDS -> S
    {
        const bf16x8* Wp0 = (const bf16x8*)(W2 + (size_t)(cb + c) * 512) + gq;
        const bf16x8* Wp1 = (const bf16x8*)(W2 + (size_t)(cb + 16 + c) * 512) + gq;
        const bf16x8* Wp2 = (const bf16x8*)(W2 + (size_t)(cb + 32 + c) * 512) + gq;
        const bf16x8* Wp3 = (const bf16x8*)(W2 + (size_t)(cb + 48 + c) * 512) + gq;
        f32x4 a0 = zero, a1 = zero, a2 = zero, a3 = zero;
#pragma unroll
        for (int k = 0; k < 16; k++) {
            bf16x8 av = *(const bf16x8*)&H[r0l + c][k * 32 + gq * 8];
            a0 = __builtin_amdgcn_mfma_f32_16x16x32_bf16(av, Wp0[k * 4], a0, 0, 0, 0);
            a1 = __builtin_amdgcn_mfma_f32_16x16x32_bf16(av, Wp1[k * 4], a1, 0, 0, 0);
            a2 = __builtin_amdgcn_mfma_f32_16x16x32_bf16(av, Wp2[k * 4], a2, 0, 0, 0);
            a3 = __builtin_amdgcn_mfma_f32_16x16x32_bf16(av, Wp3[k * 4], a3, 0, 0, 0);
        }
        int lrow = r0l + gq * 4;
        float b0 = bf2[cb + c], b1v = bf2[cb + 16 + c];
        float b2v = bf2[cb + 32 + c], b3v = bf2[cb + 48 + c];
#pragma unroll
        for (int r = 0; r < 4; r++) {
            S[lrow + r][cb + c] = a0[r] + b0;
            S[lrow + r][cb + 16 + c] = a1[r] + b1v;
            S[lrow + r][cb + 32 + c] = a2[r] + b2v;
            S[lrow + r][cb + 48 + c] = a3[r] + b3v;
        }
    }
    __syncthreads();
    // Epilogue 3: + s1 residual (bf16), final LN -> outp (fp32)
    {
        int row = tid >> 3, cg = tid & 7;
        float v[16];
#pragma unroll
        for (int j = 0; j < 16; j++)
            v[j] = S[row][cg * 16 + j] + (float)s1h[row][cg * 16 + j];
        float s = 0.0f;
#pragma unroll
        for (int j = 0; j < 16; j++) s += v[j];
        s += __shfl_xor(s, 1); s += __shfl_xor(s, 2); s += __shfl_xor(s, 4);
        float mean = s * (1.0f / 128.0f);
        float vs = 0.0f;
#pragma unroll
        for (int j = 0; j < 16; j++) { float d = v[j] - mean; vs += d * d; }
        vs += __shfl_xor(vs, 1); vs += __shfl_xor(vs, 2); vs += __shfl_xor(vs, 4);
        float rstd = rsqrtf(vs * (1.0f / 128.0f) + 1e-5f);
        float4* of = (float4*)(outp + (size_t)(blk * 32 + row) * 128 + cg * 16);
#pragma unroll
        for (int j4 = 0; j4 < 4; j4++) {
            float4 o;
#pragma unroll
            for (int e = 0; e < 4; e++) {
                int col = cg * 16 + 4 * j4 + e;
                ((float*)&o)[e] = (v[4 * j4 + e] - mean) * rstd * g2[col] + be2[col];
            }
            of[j4] = o;
        }
    }
}

// ---------------------------------------------------------------------------
// MFMA flash attention v6 (R10-proven): chain-free math, 64 q/wave, 4-way
// intra-block key-split, single LDS combine. XCD swizzle sh = bid % NSH.
__global__ __launch_bounds__(256) void k_mattn(
    const bf16* __restrict__ Qh, const bf16* __restrict__ Kh,
    const bf16* __restrict__ Vth, bf16* __restrict__ ATTh,
    int Lq, int Lk, int NSH) {
    int sh = blockIdx.x % NSH;
    int qblk = blockIdx.x / NSH;
    int wv = threadIdx.x >> 6;
    int lane = threadIdx.x & 63;
    int c = lane & 15, g = lane >> 4;
    int q0 = qblk * 64;

    __shared__ float O_lds[4][64][36];
    __shared__ float L_lds[4][64];

    const float scale = 0.17677669529663687f;  // 1/sqrt(32)
    const f32x4 zero = {0, 0, 0, 0};

    bf16x8 bq[4];
#pragma unroll
    for (int qt = 0; qt < 4; qt++)
        bq[qt] = *(const bf16x8*)(
            Qh + ((size_t)sh * Lq + q0 + qt * 16 + c) * 32 + g * 8);

    int klen = Lk >> 2;
    int kbeg = wv * klen;
    const bf16* Kbase = Kh + (size_t)sh * Lk * 32 + (size_t)kbeg * 32;
    const bf16* Vbase = Vth + (size_t)sh * 32 * Lk + kbeg;

    f32x4 oT[4][2];
#pragma unroll
    for (int qt = 0; qt < 4; qt++) { oT[qt][0] = zero; oT[qt][1] = zero; }
    float lsum[4] = {0, 0, 0, 0};

    int ntiles = klen >> 5;
    bf16x8 ka = *(const bf16x8*)(Kbase + (size_t)c * 32 + g * 8);
    bf16x8 kb = *(const bf16x8*)(Kbase + (size_t)(16 + c) * 32 + g * 8);
    bf16x4 va0 = *(const bf16x4*)(Vbase + (size_t)c * Lk + g * 4);
    bf16x4 va1 = *(const bf16x4*)(Vbase + (size_t)c * Lk + 16 + g * 4);
    bf16x4 vb0 = *(const bf16x4*)(Vbase + (size_t)(16 + c) * Lk + g * 4);
    bf16x4 vb1 = *(const bf16x4*)(Vbase + (size_t)(16 + c) * Lk + 16 + g * 4);

    for (int t = 0; t < ntiles; t++) {
        bf16x8 cka = ka, ckb = kb;
        bf16x4 cva0 = va0, cva1 = va1, cvb0 = vb0, cvb1 = vb1;
        int nk0 = ((t + 1 < ntiles) ? (t + 1) : t) << 5;
        ka = *(const bf16x8*)(Kbase + (size_t)(nk0 + c) * 32 + g * 8);
        kb = *(const bf16x8*)(Kbase + (size_t)(nk0 + 16 + c) * 32 + g * 8);
        va0 = *(const bf16x4*)(Vbase + (size_t)c * Lk + nk0 + g * 4);
        va1 = *(const bf16x4*)(Vbase + (size_t)c * Lk + nk0 + 16 + g * 4);
        vb0 = *(const bf16x4*)(Vbase + (size_t)(16 + c) * Lk + nk0 + g * 4);
        vb1 = *(const bf16x4*)(Vbase + (size_t)(16 + c) * Lk + nk0 + 16 + g * 4);

#pragma unroll
        for (int qt = 0; qt < 4; qt++) {
            f32x4 s0 = __builtin_amdgcn_mfma_f32_16x16x32_bf16(cka, bq[qt], zero, 0, 0, 0);
            f32x4 s1 = __builtin_amdgcn_mfma_f32_16x16x32_bf16(ckb, bq[qt], zero, 0, 0, 0);
            bf16x4 p0, p1;
#pragma unroll
            for (int r = 0; r < 4; r++) {
                float e0 = __expf(s0[r] * scale);
                float e1 = __expf(s1[r] * scale);
                lsum[qt] += e0 + e1;
                p0[r] = (bf16)e0;
                p1[r] = (bf16)e1;
            }
            oT[qt][0] = pv_mfma16(cva0, p0, oT[qt][0]);
            oT[qt][0] = pv_mfma16(cva1, p1, oT[qt][0]);
            oT[qt][1] = pv_mfma16(cvb0, p0, oT[qt][1]);
            oT[qt][1] = pv_mfma16(cvb1, p1, oT[qt][1]);
        }
    }

#pragma unroll
    for (int qt = 0; qt < 4; qt++) {
        float s = lsum[qt];
        s += __shfl_xor(s, 16);
        s += __shfl_xor(s, 32);
        if (g == 0) L_lds[wv][qt * 16 + c] = s;
        *(f32x4*)&O_lds[wv][qt * 16 + c][g * 4] = oT[qt][0];
        *(f32x4*)&O_lds[wv][qt * 16 + c][16 + g * 4] = oT[qt][1];
    }
    __syncthreads();

    int tid = threadIdx.x;
    int ql = tid >> 2, dq = (tid & 3) * 8;
    float ltot = L_lds[0][ql] + L_lds[1][ql] + L_lds[2][ql] + L_lds[3][ql];
    float inv = 1.0f / ltot;
    float acc[8];
#pragma unroll
    for (int j = 0; j < 8; j++) acc[j] = 0.0f;
#pragma unroll
    for (int w = 0; w < 4; w++) {
        const float* p = &O_lds[w][ql][dq];
#pragma unroll
        for (int j = 0; j < 8; j++) acc[j] += p[j];
    }
    int h = sh & 3, sb = sh >> 2;
    bf16x8 o;
#pragma unroll
    for (int j = 0; j < 8; j++) o[j] = (bf16)(acc[j] * inv);
    *(bf16x8*)(ATTh + ((size_t)sb * Lq + q0 + ql) * 128 + h * 32 + dq) = o;
}

// ---------------------------------------------------------------------------
extern "C" void kernel_launch(void* const* d_in, const int* in_sizes, int n_in,
                              void* d_out, int out_size, void* d_ws, size_t ws_size,
                              hipStream_t stream) {
    const float* vs       = (const float*)d_in[0];
    const float* semb     = (const float*)d_in[1];
    const float* r5       = (const float*)d_in[2];
    const float* A55      = (const float*)d_in[3];
    const float* bl_bias  = (const float*)d_in[4];
    const float* nl_W1    = (const float*)d_in[5];
    const float* nl_b1    = (const float*)d_in[6];
    const float* nl_W2    = (const float*)d_in[7];
    const float* nl_b2    = (const float*)d_in[8];
    const float* mlp_W1   = (const float*)d_in[9];
    const float* mlp_b1   = (const float*)d_in[10];
    const float* mlp_W2   = (const float*)d_in[11];
    const float* mlp_b2   = (const float*)d_in[12];
    const float* mlp_ln_g = (const float*)d_in[13];
    const float* mlp_ln_b = (const float*)d_in[14];
    const float* enc_qkv_W = (const float*)d_in[15];
    const float* enc_qkv_b = (const float*)d_in[16];
    const float* enc_out_W = (const float*)d_in[17];
    const float* enc_out_b = (const float*)d_in[18];
    const float* enc_ln1_g = (const float*)d_in[19];
    const float* enc_ln1_b = (const float*)d_in[20];
    const float* enc_ff_W1 = (const float*)d_in[21];
    const float* enc_ff_b1 = (const float*)d_in[22];
    const float* enc_ff_W2 = (const float*)d_in[23];
    const float* enc_ff_b2 = (const float*)d_in[24];
    const float* enc_ln2_g = (const float*)d_in[25];
    const float* enc_ln2_b = (const float*)d_in[26];
    const float* ca_Wq = (const float*)d_in[27];
    const float* ca_bq = (const float*)d_in[28];
    const float* ca_Wk = (const float*)d_in[29];
    const float* ca_bk = (const float*)d_in[30];
    const float* ca_Wv = (const float*)d_in[31];
    const float* ca_bv = (const float*)d_in[32];
    const float* ca_Wo = (const float*)d_in[33];
    const float* ca_bo = (const float*)d_in[34];
    const float* ca_ln1_g = (const float*)d_in[35];
    const float* ca_ln1_b = (const float*)d_in[36];
    const float* ca_ff_W1 = (const float*)d_in[37];
    const float* ca_ff_b1 = (const float*)d_in[38];
    const float* ca_ff_W2 = (const float*)d_in[39];
    const float* ca_ff_b2 = (const float*)d_in[40];
    const float* ca_ln2_g = (const float*)d_in[41];
    const float* ca_ln2_b = (const float*)d_in[42];
    float* out = (float*)d_out;

    // Workspace layout (byte offsets, 256-aligned)
    char* base = (char*)d_ws;
    float* b1w   = (float*)(base + 0);          //  32 KB
    float* X0    = (float*)(base + 163840);     //   4 MB
    char*  QKVr  = base + 8552448;              //  12 MB region
    bf16*  Wpk   = (bf16*) (base + 25329664);   // 1.03 MB
    float* bpk   = (float*)(base + 26411008);   //   1 KB
    bf16*  X0h   = (bf16*) (base + 26412032);   //   2 MB
    bf16*  X1h   = (bf16*) (base + 28509184);   //   2 MB (mlp1 scratch)
    bf16*  sembh = (bf16*) (base + 30606336);   //   2 MB
    bf16*  ATTh  = (bf16*) (base + 32703488);   //   2 MB
    bf16*  Qh    = (bf16*)QKVr;                 //   2 MB
    bf16*  Kh    = (bf16*)(QKVr + 2097152);     //   2 MB
    bf16*  Vth   = (bf16*)(QKVr + 4194304);     //   2 MB

    const int NTOK = B_ * T_ * N_;  // 8192

    // Prep (weights + semb cast + bias pack), one launch
    k_prep<<<dim3(6209), dim3(256), 0, stream>>>(
        enc_qkv_W, enc_out_W, enc_ff_W1, enc_ff_W2, ca_Wq, ca_Wk, ca_Wv, ca_Wo,
        ca_ff_W1, ca_ff_W2, mlp_W2, semb, ca_bk, ca_bv, Wpk, sembh, bpk);

    // Residual features + token MLP
    k_b1<<<dim3((B_ * (T_ - 1) + 63) / 64), dim3(64), 0, stream>>>(
        vs, r5, A55, bl_bias, nl_W1, nl_b1, nl_W2, nl_b2, b1w);
    k_mlp1<<<dim3(NTOK), dim3(128), 0, stream>>>(vs, b1w, mlp_W1, mlp_b1, X1h);
    k_gemm_ln<<<dim3(256), dim3(256), 0, stream>>>(
        X1h, Wpk + 524288, mlp_b2, 128, nullptr, mlp_ln_g, mlp_ln_b,
        X0, X0h, 128, 1 | 2 | 4);

    // Encoder layers: QKV -> attn -> fused tail
    for (int i = 0; i < LENC_; i++) {
        k_gemm4<<<dim3(768), dim3(256), 0, stream>>>(
            X0h, Wpk + i * 49152, enc_qkv_b + i * 384, Qh, Kh, Vth, 384, 128, 1);
        k_mattn<<<dim3(512), dim3(256), 0, stream>>>(
            Qh, Kh, Vth, ATTh, 256, 256, 128);
        k_enc_tail<<<dim3(256), dim3(256), 0, stream>>>(
            ATTh, Wpk + 98304 + i * 16384, enc_out_b + i * 128, X0,
            enc_ln1_g + i * 128, enc_ln1_b + i * 128,
            Wpk + 131072 + i * 32768, enc_ff_b1 + i * 256,
            Wpk + 196608 + i * 32768, enc_ff_b2 + i * 128,
            enc_ln2_g + i * 128, enc_ln2_b + i * 128, X0, X0h);
    }

    // Cross-attention: Q+KV (one dispatch) -> attn -> fused tail -> out
    k_qkvc<<<dim3(768), dim3(256), 0, stream>>>(
        sembh, Wpk + 262144, ca_bq, X0h, Wpk + 278528, bpk, Qh, Kh, Vth);
    k_mattn<<<dim3(512), dim3(256), 0, stream>>>(
        Qh, Kh, Vth, ATTh, 2048, 2048, 16);
    k_cross_tail<<<dim3(256), dim3(256), 0, stream>>>(
        ATTh, Wpk + 311296, ca_bo, semb, ca_ln1_g, ca_ln1_b, X0h,
        Wpk + 327680, ca_ff_b1, Wpk + 458752, ca_ff_b2,
        ca_ln2_g, ca_ln2_b, out);
}

// Round 13
// 337.142 us; speedup vs baseline: 1.3465x; 1.0032x over previous
//
#include <hip/hip_runtime.h>
#include <math.h>

// Problem constants
#define B_ 4
#define T_ 256
#define N_ 8
#define D_ 128
#define NH_ 4
#define HD_ 32
#define LENC_ 2
#define MLPH_ 32
#define NL_SCALE_ 0.1f

typedef __bf16 bf16;
typedef __attribute__((ext_vector_type(2))) __bf16 bf16x2;
typedef __attribute__((ext_vector_type(4))) __bf16 bf16x4;
typedef __attribute__((ext_vector_type(8))) __bf16 bf16x8;
typedef __attribute__((ext_vector_type(4))) float f32x4;

__device__ __forceinline__ f32x4 pv_mfma16(bf16x4 a, bf16x4 b, f32x4 c) {
#if __has_builtin(__builtin_amdgcn_mfma_f32_16x16x16_bf16)
    return __builtin_amdgcn_mfma_f32_16x16x16_bf16(a, b, c, 0, 0, 0);
#else
    typedef __attribute__((ext_vector_type(4))) short s4;
    union U { bf16x4 h; s4 s; };
    U ua, ub; ua.h = a; ub.h = b;
    return __builtin_amdgcn_mfma_f32_16x16x16bf16_1k(ua.s, ub.s, c, 0, 0, 0);
#endif
}

__device__ __forceinline__ float gelu_f(float x) {
    return 0.5f * x * (1.0f + erff(x * 0.7071067811865476f));
}

// ---------------------------------------------------------------------------
// Merged prep (blocks 0..6208) + b1 baseline (blocks 6209..6212).
__global__ void k_prep_b1(const float* __restrict__ eqkvW, const float* __restrict__ eoutW,
                          const float* __restrict__ eff1, const float* __restrict__ eff2,
                          const float* __restrict__ wq, const float* __restrict__ wk,
                          const float* __restrict__ wv, const float* __restrict__ wo,
                          const float* __restrict__ cff1, const float* __restrict__ cff2,
                          const float* __restrict__ mlpW2, const float* __restrict__ semb,
                          const float* __restrict__ bk, const float* __restrict__ bv,
                          bf16* __restrict__ Wpk, bf16* __restrict__ sembh,
                          float* __restrict__ bpk,
                          const float* __restrict__ vs, const float* __restrict__ r5,
                          const float* __restrict__ A55, const float* __restrict__ bl_bias,
                          const float* __restrict__ nlW1, const float* __restrict__ nlb1,
                          const float* __restrict__ nlW2, const float* __restrict__ nlb2,
                          float* __restrict__ b1w) {
    if (blockIdx.x < 6209) {
        int i = blockIdx.x * 256 + threadIdx.x;
        if (i < 540672) {
            const float* src; int off;
            if      (i < 98304)  { src = eqkvW; off = 0; }
            else if (i < 131072) { src = eoutW; off = 98304; }
            else if (i < 196608) { src = eff1;  off = 131072; }
            else if (i < 262144) { src = eff2;  off = 196608; }
            else if (i < 278528) { src = wq;    off = 262144; }
            else if (i < 294912) { src = wk;    off = 278528; }
            else if (i < 311296) { src = wv;    off = 294912; }
            else if (i < 327680) { src = wo;    off = 311296; }
            else if (i < 458752) { src = cff1;  off = 327680; }
            else if (i < 524288) { src = cff2;  off = 458752; }
            else                 { src = mlpW2; off = 524288; }
            Wpk[i] = (bf16)src[i - off];
        } else if (i < 540672 + 1048576) {
            int j = i - 540672;
            sembh[j] = (bf16)semb[j];
        } else if (i < 540672 + 1048576 + 256) {
            int t = i - 540672 - 1048576;
            bpk[t] = (t < 128) ? bk[t] : bv[t - 128];
        }
        return;
    }
    int idx = (blockIdx.x - 6209) * 256 + threadIdx.x;
    if (idx >= B_ * (T_ - 1)) return;
    int b = idx / (T_ - 1), t = idx % (T_ - 1);
    float x[N_];
    for (int n = 0; n < N_; n++) x[n] = vs[(b * T_ + t) * N_ + n];
    float h[MLPH_];
    for (int j = 0; j < MLPH_; j++) {
        float a = nlb1[j];
        for (int n = 0; n < N_; n++) a += x[n] * nlW1[j * N_ + n];
        h[j] = gelu_f(a);
    }
    for (int m = 0; m < N_; m++) {
        float lin = r5[m];
        for (int n = 0; n < N_; n++) lin += x[n] * A55[m * N_ + n];
        float nl = nlb2[m];
        for (int j = 0; j < MLPH_; j++) nl += h[j] * nlW2[m * MLPH_ + j];
        b1w[idx * N_ + m] = lin + NL_SCALE_ * nl + bl_bias[m];
    }
}

// ---------------------------------------------------------------------------
// Fused: residual features + mlp1 (16->128, gelu) in LDS prologue, then
// GEMM W2 (K=128,N=128) + gelu + LN + PE + transpose-write. grid = 256.
__global__ __launch_bounds__(256) void k_mlp_ln(
    const float* __restrict__ vs, const float* __restrict__ b1w,
    const float* __restrict__ W1, const float* __restrict__ b1,
    const bf16* __restrict__ W2, const float* __restrict__ bias,
    const float* __restrict__ g, const float* __restrict__ be,
    float* __restrict__ outf, bf16* __restrict__ outh) {
    __shared__ float F[32][16];
    __shared__ bf16 H1[32][136];
    __shared__ float S[32][132];
    int tid = threadIdx.x;
    int blk = blockIdx.x;
    // Phase 0a: features F[row][feat] for rows blk*32..+31
#pragma unroll
    for (int e = tid; e < 512; e += 256) {
        int row = e >> 4, feat = e & 15;
        int grow = blk * 32 + row;
        int b = grow >> 11, t = (grow >> 3) & 255, n = grow & 7;
        const int SC[4] = {1, 2, 3, 5};
        int lag = feat >> 2, si = feat & 3, k = SC[si];
        int tp = t - lag;
        float r = 0.0f;
        if (tp >= 0 && tp < T_ - k) {
            float lx0 = logf(fmaxf(vs[(b * T_ + tp) * N_ + n], 1e-6f));
            float lx1 = logf(fmaxf(vs[(b * T_ + tp + k) * N_ + n], 1e-6f));
            float a = lx1 - lx0;
            a = fminf(fmaxf(a, -2.5f * (float)k), 2.0f * (float)k);
            float bk = 0.0f;
            for (int i = 0; i < k; i++) bk += b1w[(b * (T_ - 1) + tp + i) * N_ + n];
            r = a - bk;
        }
        F[row][feat] = r;
    }
    __syncthreads();
    // Phase 0b: H1[row][d] = gelu(b1[d] + F[row] . W1[d])
    {
        int row = tid >> 3, cg = tid & 7;
        float f[16];
#pragma unroll
        for (int c = 0; c < 16; c++) f[c] = F[row][c];
#pragma unroll
        for (int j = 0; j < 16; j++) {
            int d = cg * 16 + j;
            float a = b1[d];
            const float* w = W1 + d * 16;
#pragma unroll
            for (int c = 0; c < 16; c++) a += f[c] * w[c];
            H1[row][d] = (bf16)gelu_f(a);
        }
    }
    __syncthreads();
    // Phase 1: GEMM (K=128, N=128), A from H1 LDS
    int w = tid >> 6, lane = tid & 63;
    int c = lane & 15, gq = lane >> 4;
    int r0l = (w >> 1) * 16;
    int cb = (w & 1) * 64;
    const f32x4 zero = {0, 0, 0, 0};
    {
        const bf16x8* Wp0 = (const bf16x8*)(W2 + (size_t)(cb + c) * 128) + gq;
        const bf16x8* Wp1 = (const bf16x8*)(W2 + (size_t)(cb + 16 + c) * 128) + gq;
        const bf16x8* Wp2 = (const bf16x8*)(W2 + (size_t)(cb + 32 + c) * 128) + gq;
        const bf16x8* Wp3 = (const bf16x8*)(W2 + (size_t)(cb + 48 + c) * 128) + gq;
        f32x4 a0 = zero, a1 = zero, a2 = zero, a3 = zero;
#pragma unroll
        for (int k = 0; k < 4; k++) {
            bf16x8 av = *(const bf16x8*)&H1[r0l + c][k * 32 + gq * 8];
            a0 = __builtin_amdgcn_mfma_f32_16x16x32_bf16(av, Wp0[k * 4], a0, 0, 0, 0);
            a1 = __builtin_amdgcn_mfma_f32_16x16x32_bf16(av, Wp1[k * 4], a1, 0, 0, 0);
            a2 = __builtin_amdgcn_mfma_f32_16x16x32_bf16(av, Wp2[k * 4], a2, 0, 0, 0);
            a3 = __builtin_amdgcn_mfma_f32_16x16x32_bf16(av, Wp3[k * 4], a3, 0, 0, 0);
        }
        int lrow = r0l + gq * 4;
#pragma unroll
        for (int r = 0; r < 4; r++) {
            S[lrow + r][cb + c]      = gelu_f(a0[r] + bias[cb + c]);
            S[lrow + r][cb + 16 + c] = gelu_f(a1[r] + bias[cb + 16 + c]);
            S[lrow + r][cb + 32 + c] = gelu_f(a2[r] + bias[cb + 32 + c]);
            S[lrow + r][cb + 48 + c] = gelu_f(a3[r] + bias[cb + 48 + c]);
        }
    }
    __syncthreads();
    // Epilogue: LN + PE, transpose-write (xt order)
    {
        int row = tid >> 3, cg = tid & 7;
        int grow = blk * 32 + row;
        int b = grow >> 11, t = (grow >> 3) & 255, n = grow & 7;
        int orow = (b * 8 + n) * 256 + t;
        float v[16];
#pragma unroll
        for (int j = 0; j < 16; j++) v[j] = S[row][cg * 16 + j];
        float s = 0.0f;
#pragma unroll
        for (int j = 0; j < 16; j++) s += v[j];
        s += __shfl_xor(s, 1); s += __shfl_xor(s, 2); s += __shfl_xor(s, 4);
        float mean = s * (1.0f / 128.0f);
        float vs2 = 0.0f;
#pragma unroll
        for (int j = 0; j < 16; j++) { float d = v[j] - mean; vs2 += d * d; }
        vs2 += __shfl_xor(vs2, 1); vs2 += __shfl_xor(vs2, 2); vs2 += __shfl_xor(vs2, 4);
        float rstd = rsqrtf(vs2 * (1.0f / 128.0f) + 1e-5f);
        float y[16];
#pragma unroll
        for (int j = 0; j < 16; j++) {
            int col = cg * 16 + j;
            y[j] = (v[j] - mean) * rstd * g[col] + be[col];
        }
#pragma unroll
        for (int jj = 0; jj < 8; jj++) {
            int j2 = cg * 8 + jj;
            float freq = expf((float)(2 * j2) * (-9.210340371976184f / 128.0f));
            float ang = (float)t * freq;
            y[2 * jj] += sinf(ang);
            y[2 * jj + 1] += cosf(ang);
        }
        float4* of = (float4*)(outf + (size_t)orow * 128 + cg * 16);
        bf16x8* oh = (bf16x8*)(outh + (size_t)orow * 128 + cg * 16);
#pragma unroll
        for (int j4 = 0; j4 < 4; j4++) {
            float4 o; o.x = y[4 * j4]; o.y = y[4 * j4 + 1];
            o.z = y[4 * j4 + 2]; o.w = y[4 * j4 + 3];
            of[j4] = o;
        }
#pragma unroll
        for (int j8 = 0; j8 < 2; j8++) {
            bf16x8 o;
#pragma unroll
            for (int e = 0; e < 8; e++) o[e] = (bf16)y[8 * j8 + e];
            oh[j8] = o;
        }
    }
}

// ---------------------------------------------------------------------------
// Fused encoder QKV + attention: one block per (seq,head). Block computes its
// own Q/K/V slice (256 rows x 96 head-cols, K=128) into LDS, then runs the
// chain-free attention (wave = 64 q x all 256 keys, LDS-resident).
// grid = 128, 256 threads. Output ATTh[(s*256+q)*128 + h*32 + d].
__global__ __launch_bounds__(256) void k_enc_attn(
    const bf16* __restrict__ X0h, const bf16* __restrict__ Wqkv,
    const float* __restrict__ bqkv, bf16* __restrict__ ATTh) {
    int sh = blockIdx.x;
    int s = sh >> 2, h = sh & 3;
    __shared__ bf16 Ql[256][40];    // pad->80B rows: b128 16B-aligned, 2-way
    __shared__ bf16 Kl[256][40];
    __shared__ bf16 Vt[32][264];    // V transposed; 528B rows
    int tid = threadIdx.x;
    int wv = tid >> 6, lane = tid & 63;
    int c = lane & 15, g = lane >> 4;
    const f32x4 zero = {0, 0, 0, 0};

    // Phase 1: QKV slice. Wave wv: rows wv*64..+63 (4 row-tiles), 6 col-tiles
    // (Q: h*32+{0,16}; K: 128+h*32+{0,16}; V: 256+h*32+{0,16}).
    {
        const bf16* Wq0 = Wqkv + (size_t)(h * 32 + c) * 128;
        const bf16* Wq1 = Wqkv + (size_t)(h * 32 + 16 + c) * 128;
        const bf16* Wk0 = Wqkv + (size_t)(128 + h * 32 + c) * 128;
        const bf16* Wk1 = Wqkv + (size_t)(128 + h * 32 + 16 + c) * 128;
        const bf16* Wv0 = Wqkv + (size_t)(256 + h * 32 + c) * 128;
        const bf16* Wv1 = Wqkv + (size_t)(256 + h * 32 + 16 + c) * 128;
        float bq0 = bqkv[h * 32 + c], bq1 = bqkv[h * 32 + 16 + c];
        float bk0 = bqkv[128 + h * 32 + c], bk1 = bqkv[128 + h * 32 + 16 + c];
        float bv0 = bqkv[256 + h * 32 + c], bv1 = bqkv[256 + h * 32 + 16 + c];
#pragma unroll
        for (int rb = 0; rb < 4; rb++) {
            int row0 = wv * 64 + rb * 16;
            const bf16x8* Ap = (const bf16x8*)(X0h + (size_t)(s * 256 + row0 + c) * 128) + g;
            f32x4 aq0 = zero, aq1 = zero, ak0 = zero, ak1 = zero, av0 = zero, av1 = zero;
#pragma unroll
            for (int k = 0; k < 4; k++) {
                bf16x8 av = Ap[k * 4];
                aq0 = __builtin_amdgcn_mfma_f32_16x16x32_bf16(av, *((const bf16x8*)Wq0 + k * 4 + g), aq0, 0, 0, 0);
                aq1 = __builtin_amdgcn_mfma_f32_16x16x32_bf16(av, *((const bf16x8*)Wq1 + k * 4 + g), aq1, 0, 0, 0);
                ak0 = __builtin_amdgcn_mfma_f32_16x16x32_bf16(av, *((const bf16x8*)Wk0 + k * 4 + g), ak0, 0, 0, 0);
                ak1 = __builtin_amdgcn_mfma_f32_16x16x32_bf16(av, *((const bf16x8*)Wk1 + k * 4 + g), ak1, 0, 0, 0);
                av0 = __builtin_amdgcn_mfma_f32_16x16x32_bf16(av, *((const bf16x8*)Wv0 + k * 4 + g), av0, 0, 0, 0);
                av1 = __builtin_amdgcn_mfma_f32_16x16x32_bf16(av, *((const bf16x8*)Wv1 + k * 4 + g), av1, 0, 0, 0);
            }
            int lr = row0 + g * 4;
#pragma unroll
            for (int i = 0; i < 4; i++) {
                Ql[lr + i][c] = (bf16)(aq0[i] + bq0);
                Ql[lr + i][16 + c] = (bf16)(aq1[i] + bq1);
                Kl[lr + i][c] = (bf16)(ak0[i] + bk0);
                Kl[lr + i][16 + c] = (bf16)(ak1[i] + bk1);
                Vt[c][lr + i] = (bf16)(av0[i] + bv0);
                Vt[16 + c][lr + i] = (bf16)(av1[i] + bv1);
            }
        }
    }
    __syncthreads();

    // Phase 2: attention. Wave wv: queries wv*64..+63 (4 q-tiles), 8 k-tiles.
    const float scale = 0.17677669529663687f;  // 1/sqrt(32)
    int q0 = wv * 64;
    bf16x8 bq[4];
#pragma unroll
    for (int qt = 0; qt < 4; qt++)
        bq[qt] = *(const bf16x8*)&Ql[q0 + qt * 16 + c][g * 8];
    f32x4 oT[4][2];
#pragma unroll
    for (int qt = 0; qt < 4; qt++) { oT[qt][0] = zero; oT[qt][1] = zero; }
    float lsum[4] = {0, 0, 0, 0};
#pragma unroll
    for (int t = 0; t < 8; t++) {
        int k0 = t * 32;
        bf16x8 ka = *(const bf16x8*)&Kl[k0 + c][g * 8];
        bf16x8 kb = *(const bf16x8*)&Kl[k0 + 16 + c][g * 8];
        bf16x4 va0 = *(const bf16x4*)&Vt[c][k0 + g * 4];
        bf16x4 va1 = *(const bf16x4*)&Vt[c][k0 + 16 + g * 4];
        bf16x4 vb0 = *(const bf16x4*)&Vt[16 + c][k0 + g * 4];
        bf16x4 vb1 = *(const bf16x4*)&Vt[16 + c][k0 + 16 + g * 4];
#pragma unroll
        for (int qt = 0; qt < 4; qt++) {
            f32x4 s0 = __builtin_amdgcn_mfma_f32_16x16x32_bf16(ka, bq[qt], zero, 0, 0, 0);
            f32x4 s1 = __builtin_amdgcn_mfma_f32_16x16x32_bf16(kb, bq[qt], zero, 0, 0, 0);
            bf16x4 p0, p1;
#pragma unroll
            for (int r = 0; r < 4; r++) {
                float e0 = __expf(s0[r] * scale);
                float e1 = __expf(s1[r] * scale);
                lsum[qt] += e0 + e1;
                p0[r] = (bf16)e0;
                p1[r] = (bf16)e1;
            }
            oT[qt][0] = pv_mfma16(va0, p0, oT[qt][0]);
            oT[qt][0] = pv_mfma16(va1, p1, oT[qt][0]);
            oT[qt][1] = pv_mfma16(vb0, p0, oT[qt][1]);
            oT[qt][1] = pv_mfma16(vb1, p1, oT[qt][1]);
        }
    }
#pragma unroll
    for (int qt = 0; qt < 4; qt++) {
        float sm = lsum[qt];
        sm += __shfl_xor(sm, 16);
        sm += __shfl_xor(sm, 32);
        float inv = 1.0f / sm;
        size_t rbase = ((size_t)s * 256 + q0 + qt * 16 + c) * 128 + h * 32;
#pragma unroll
        for (int r = 0; r < 4; r++) {
            ATTh[rbase + g * 4 + r] = (bf16)(oT[qt][0][r] * inv);
            ATTh[rbase + 16 + g * 4 + r] = (bf16)(oT[qt][1][r] * inv);
        }
    }
}

// ---------------------------------------------------------------------------
// Wide MFMA GEMM body for cross Q/KV scatter modes.
__device__ __forceinline__ void gemm4_body(
    int bid, const bf16* __restrict__ A, const bf16* __restrict__ W,
    const float* __restrict__ bias, bf16* __restrict__ dq,
    bf16* __restrict__ dk, bf16* __restrict__ dvv, int N, int K, int mode) {
    int lane = threadIdx.x & 63;
    int wv = threadIdx.x >> 6;
    int c = lane & 15, g = lane >> 4;
    int nN = N >> 6;
    int tn = bid % nN, tm = bid / nN;
    int row0 = tm * 64 + wv * 16;
    int cb = tn * 64;

    const bf16x8* Ap  = (const bf16x8*)(A + (size_t)(row0 + c) * K) + g;
    const bf16x8* Wp0 = (const bf16x8*)(W + (size_t)(cb + c) * K) + g;
    const bf16x8* Wp1 = (const bf16x8*)(W + (size_t)(cb + 16 + c) * K) + g;
    const bf16x8* Wp2 = (const bf16x8*)(W + (size_t)(cb + 32 + c) * K) + g;
    const bf16x8* Wp3 = (const bf16x8*)(W + (size_t)(cb + 48 + c) * K) + g;
    f32x4 a0 = {0, 0, 0, 0}, a1 = {0, 0, 0, 0};
    f32x4 a2 = {0, 0, 0, 0}, a3 = {0, 0, 0, 0};
    int nk = K >> 5;
    for (int k = 0; k < nk; k++) {
        bf16x8 av = Ap[k * 4];
        a0 = __builtin_amdgcn_mfma_f32_16x16x32_bf16(av, Wp0[k * 4], a0, 0, 0, 0);
        a1 = __builtin_amdgcn_mfma_f32_16x16x32_bf16(av, Wp1[k * 4], a1, 0, 0, 0);
        a2 = __builtin_amdgcn_mfma_f32_16x16x32_bf16(av, Wp2[k * 4], a2, 0, 0, 0);
        a3 = __builtin_amdgcn_mfma_f32_16x16x32_bf16(av, Wp3[k * 4], a3, 0, 0, 0);
    }
    int rowb = row0 + g * 4;
#pragma unroll
    for (int ct = 0; ct < 4; ct++) {
        f32x4 acc = (ct == 0) ? a0 : (ct == 1) ? a1 : (ct == 2) ? a2 : a3;
        int col = cb + ct * 16 + c;
        float bvv = bias[col];
#pragma unroll
        for (int i = 0; i < 4; i++) {
            float v = acc[i] + bvv;
            int row = rowb + i;
            if (mode == 2) {
                int b = row >> 11, ll = row & 2047;
                int hh = col >> 5, d = col & 31;
                dq[((size_t)(b * 4 + hh) * 2048 + ll) * 32 + d] = (bf16)v;
            } else {
                int b = row >> 11, n = (row >> 8) & 7, t = row & 255;
                int ll = t * 8 + n;
                int hh = (col >> 5) & 3, d = col & 31;
                if (col < 128) dk[((size_t)(b * 4 + hh) * 2048 + ll) * 32 + d] = (bf16)v;
                else           dvv[((size_t)(b * 4 + hh) * 32 + d) * 2048 + ll] = (bf16)v;
            }
        }
    }
}

// Cross Q-proj (blocks 0..255) + KV-proj (blocks 256..767) in one dispatch.
__global__ __launch_bounds__(256) void k_qkvc(
    const bf16* __restrict__ sembh, const bf16* __restrict__ Wq,
    const float* __restrict__ bq, const bf16* __restrict__ X0h,
    const bf16* __restrict__ Wkv, const float* __restrict__ bkv,
    bf16* __restrict__ Qh, bf16* __restrict__ Kh, bf16* __restrict__ Vth) {
    if (blockIdx.x < 256)
        gemm4_body(blockIdx.x, sembh, Wq, bq, Qh, nullptr, nullptr, 128, 128, 2);
    else
        gemm4_body(blockIdx.x - 256, X0h, Wkv, bkv, nullptr, Kh, Vth, 256, 128, 3);
}

// ---------------------------------------------------------------------------
// Encoder tail megafusion (R12-proven): outproj+res+LN1+ff1+ff2+res+LN2.
__global__ __launch_bounds__(256) void k_enc_tail(
    const bf16* __restrict__ ATTh, const bf16* __restrict__ Wo,
    const float* __restrict__ bo, const float* __restrict__ X0res,
    const float* __restrict__ g1, const float* __restrict__ be1,
    const bf16* __restrict__ W1, const float* __restrict__ bf1,
    const bf16* __restrict__ W2, const float* __restrict__ bf2,
    const float* __restrict__ g2, const float* __restrict__ be2,
    float* __restrict__ X0out, bf16* __restrict__ X0hout) {
    __shared__ float S[32][132];
    __shared__ float X1f[32][132];
    __shared__ bf16 X1h[32][136];
    __shared__ bf16 H[32][264];
    int tid = threadIdx.x;
    int w = tid >> 6, lane = tid & 63;
    int c = lane & 15, gq = lane >> 4;
    int r0l = (w >> 1) * 16;
    int cb = (w & 1) * 64;
    int blk = blockIdx.x;
    const f32x4 zero = {0, 0, 0, 0};

    {
        const bf16x8* Ap  = (const bf16x8*)(ATTh + (size_t)(blk * 32 + r0l + c) * 128) + gq;
        const bf16x8* Wp0 = (const bf16x8*)(Wo + (size_t)(cb + c) * 128) + gq;
        const bf16x8* Wp1 = (const bf16x8*)(Wo + (size_t)(cb + 16 + c) * 128) + gq;
        const bf16x8* Wp2 = (const bf16x8*)(Wo + (size_t)(cb + 32 + c) * 128) + gq;
        const bf16x8* Wp3 = (const bf16x8*)(Wo + (size_t)(cb + 48 + c) * 128) + gq;
        f32x4 a0 = zero, a1 = zero, a2 = zero, a3 = zero;
#pragma unroll
        for (int k = 0; k < 4; k++) {
            bf16x8 av = Ap[k * 4];
            a0 = __builtin_amdgcn_mfma_f32_16x16x32_bf16(av, Wp0[k * 4], a0, 0, 0, 0);
            a1 = __builtin_amdgcn_mfma_f32_16x16x32_bf16(av, Wp1[k * 4], a1, 0, 0, 0);
            a2 = __builtin_amdgcn_mfma_f32_16x16x32_bf16(av, Wp2[k * 4], a2, 0, 0, 0);
            a3 = __builtin_amdgcn_mfma_f32_16x16x32_bf16(av, Wp3[k * 4], a3, 0, 0, 0);
        }
        int lrow = r0l + gq * 4;
        float b0 = bo[cb + c], b1v = bo[cb + 16 + c];
        float b2v = bo[cb + 32 + c], b3v = bo[cb + 48 + c];
#pragma unroll
        for (int r = 0; r < 4; r++) {
            S[lrow + r][cb + c] = a0[r] + b0;
            S[lrow + r][cb + 16 + c] = a1[r] + b1v;
            S[lrow + r][cb + 32 + c] = a2[r] + b2v;
            S[lrow + r][cb + 48 + c] = a3[r] + b3v;
        }
    }
    __syncthreads();
    {
        int row = tid >> 3, cg = tid & 7;
        float v[16];
        const float4* rp = (const float4*)(X0res + (size_t)(blk * 32 + row) * 128 + cg * 16);
#pragma unroll
        for (int j4 = 0; j4 < 4; j4++) {
            float4 rv = rp[j4];
            v[4 * j4 + 0] = S[row][cg * 16 + 4 * j4 + 0] + rv.x;
            v[4 * j4 + 1] = S[row][cg * 16 + 4 * j4 + 1] + rv.y;
            v[4 * j4 + 2] = S[row][cg * 16 + 4 * j4 + 2] + rv.z;
            v[4 * j4 + 3] = S[row][cg * 16 + 4 * j4 + 3] + rv.w;
        }
        float s = 0.0f;
#pragma unroll
        for (int j = 0; j < 16; j++) s += v[j];
        s += __shfl_xor(s, 1); s += __shfl_xor(s, 2); s += __shfl_xor(s, 4);
        float mean = s * (1.0f / 128.0f);
        float vs = 0.0f;
#pragma unroll
        for (int j = 0; j < 16; j++) { float d = v[j] - mean; vs += d * d; }
        vs += __shfl_xor(vs, 1); vs += __shfl_xor(vs, 2); vs += __shfl_xor(vs, 4);
        float rstd = rsqrtf(vs * (1.0f / 128.0f) + 1e-5f);
#pragma unroll
        for (int j = 0; j < 16; j++) {
            int col = cg * 16 + j;
            float y = (v[j] - mean) * rstd * g1[col] + be1[col];
            X1f[row][col] = y;
            X1h[row][col] = (bf16)y;
        }
    }
    __syncthreads();
    {
        bf16x8 af[4];
#pragma unroll
        for (int k = 0; k < 4; k++)
            af[k] = *(const bf16x8*)&X1h[r0l + c][k * 32 + gq * 8];
#pragma unroll
        for (int ci = 0; ci < 2; ci++) {
            int cb2 = cb + ci * 128;
            const bf16x8* Wp0 = (const bf16x8*)(W1 + (size_t)(cb2 + c) * 128) + gq;
            const bf16x8* Wp1 = (const bf16x8*)(W1 + (size_t)(cb2 + 16 + c) * 128) + gq;
            const bf16x8* Wp2 = (const bf16x8*)(W1 + (size_t)(cb2 + 32 + c) * 128) + gq;
            const bf16x8* Wp3 = (const bf16x8*)(W1 + (size_t)(cb2 + 48 + c) * 128) + gq;
            f32x4 a0 = zero, a1 = zero, a2 = zero, a3 = zero;
#pragma unroll
            for (int k = 0; k < 4; k++) {
                a0 = __builtin_amdgcn_mfma_f32_16x16x32_bf16(af[k], Wp0[k * 4], a0, 0, 0, 0);
                a1 = __builtin_amdgcn_mfma_f32_16x16x32_bf16(af[k], Wp1[k * 4], a1, 0, 0, 0);
                a2 = __builtin_amdgcn_mfma_f32_16x16x32_bf16(af[k], Wp2[k * 4], a2, 0, 0, 0);
                a3 = __builtin_amdgcn_mfma_f32_16x16x32_bf16(af[k], Wp3[k * 4], a3, 0, 0, 0);
            }
            int lrow = r0l + gq * 4;
#pragma unroll
            for (int r = 0; r < 4; r++) {
                H[lrow + r][cb2 + c]      = (bf16)gelu_f(a0[r] + bf1[cb2 + c]);
                H[lrow + r][cb2 + 16 + c] = (bf16)gelu_f(a1[r] + bf1[cb2 + 16 + c]);
                H[lrow + r][cb2 + 32 + c] = (bf16)gelu_f(a2[r] + bf1[cb2 + 32 + c]);
                H[lrow + r][cb2 + 48 + c] = (bf16)gelu_f(a3[r] + bf1[cb2 + 48 + c]);
            }
        }
    }
    __syncthreads();
    {
        bf16x8 af[8];
#pragma unroll
        for (int k = 0; k < 8; k++)
            af[k] = *(const bf16x8*)&H[r0l + c][k * 32 + gq * 8];
        const bf16x8* Wp0 = (const bf16x8*)(W2 + (size_t)(cb + c) * 256) + gq;
        const bf16x8* Wp1 = (const bf16x8*)(W2 + (size_t)(cb + 16 + c) * 256) + gq;
        const bf16x8* Wp2 = (const bf16x8*)(W2 + (size_t)(cb + 32 + c) * 256) + gq;
        const bf16x8* Wp3 = (const bf16x8*)(W2 + (size_t)(cb + 48 + c) * 256) + gq;
        f32x4 a0 = zero, a1 = zero, a2 = zero, a3 = zero;
#pragma unroll
        for (int k = 0; k < 8; k++) {
            a0 = __builtin_amdgcn_mfma_f32_16x16x32_bf16(af[k], Wp0[k * 4], a0, 0, 0, 0);
            a1 = __builtin_amdgcn_mfma_f32_16x16x32_bf16(af[k], Wp1[k * 4], a1, 0, 0, 0);
            a2 = __builtin_amdgcn_mfma_f32_16x16x32_bf16(af[k], Wp2[k * 4], a2, 0, 0, 0);
            a3 = __builtin_amdgcn_mfma_f32_16x16x32_bf16(af[k], Wp3[k * 4], a3, 0, 0, 0);
        }
        int lrow = r0l + gq * 4;
        float b0 = bf2[cb + c], b1v = bf2[cb + 16 + c];
        float b2v = bf2[cb + 32 + c], b3v = bf2[cb + 48 + c];
#pragma unroll
        for (int r = 0; r < 4; r++) {
            S[lrow + r][cb + c] = a0[r] + b0;
            S[lrow + r][cb + 16 + c] = a1[r] + b1v;
            S[lrow + r][cb + 32 + c] = a2[r] + b2v;
            S[lrow + r][cb + 48 + c] = a3[r] + b3v;
        }
    }
    __syncthreads();
    {
        int row = tid >> 3, cg = tid & 7;
        float v[16];
#pragma unroll
        for (int j = 0; j < 16; j++)
            v[j] = S[row][cg * 16 + j] + X1f[row][cg * 16 + j];
        float s = 0.0f;
#pragma unroll
        for (int j = 0; j < 16; j++) s += v[j];
        s += __shfl_xor(s, 1); s += __shfl_xor(s, 2); s += __shfl_xor(s, 4);
        float mean = s * (1.0f / 128.0f);
        float vs = 0.0f;
#pragma unroll
        for (int j = 0; j < 16; j++) { float d = v[j] - mean; vs += d * d; }
        vs += __shfl_xor(vs, 1); vs += __shfl_xor(vs, 2); vs += __shfl_xor(vs, 4);
        float rstd = rsqrtf(vs * (1.0f / 128.0f) + 1e-5f);
        size_t grow = (size_t)(blk * 32 + row);
        float4* of = (float4*)(X0out + grow * 128 + cg * 16);
        bf16x8* oh = (bf16x8*)(X0hout + grow * 128 + cg * 16);
        float y[16];
#pragma unroll
        for (int j = 0; j < 16; j++) {
            int col = cg * 16 + j;
            y[j] = (v[j] - mean) * rstd * g2[col] + be2[col];
        }
#pragma unroll
        for (int j4 = 0; j4 < 4; j4++) {
            float4 o; o.x = y[4 * j4]; o.y = y[4 * j4 + 1];
            o.z = y[4 * j4 + 2]; o.w = y[4 * j4 + 3];
            of[j4] = o;
        }
#pragma unroll
        for (int j8 = 0; j8 < 2; j8++) {
            bf16x8 o;
#pragma unroll
            for (int e = 0; e < 8; e++) o[e] = (bf16)y[8 * j8 + e];
            oh[j8] = o;
        }
    }
}

// ---------------------------------------------------------------------------
// Cross tail megafusion (R12-proven).
__global__ __launch_bounds__(256) void k_cross_tail(
    const bf16* __restrict__ ATTh, const bf16* __restrict__ Wo,
    const float* __restrict__ bo, const float* __restrict__ semb,
    const float* __restrict__ g1, const float* __restrict__ be1,
    const bf16* __restrict__ X0h, const bf16* __restrict__ W1,
    const float* __restrict__ bf1, const bf16* __restrict__ W2,
    const float* __restrict__ bf2, const float* __restrict__ g2,
    const float* __restrict__ be2, float* __restrict__ outp) {
    __shared__ float S[32][132];
    __shared__ bf16 s1h[32][136];
    __shared__ bf16 H[32][520];
    int tid = threadIdx.x;
    int w = tid >> 6, lane = tid & 63;
    int c = lane & 15, gq = lane >> 4;
    int r0l = (w >> 1) * 16;
    int cb = (w & 1) * 64;
    int blk = blockIdx.x;
    const f32x4 zero = {0, 0, 0, 0};

    bf16x8 agl[4];
    {
        int tr = blk * 32 + r0l + c;
        int b = tr >> 11, t = (tr >> 3) & 255, n = tr & 7;
        const bf16* xrow = X0h + ((size_t)((b * 8 + n) * 256 + t)) * 128;
#pragma unroll
        for (int k = 0; k < 4; k++)
            agl[k] = *(const bf16x8*)(xrow + k * 32 + gq * 8);
    }

    {
        const bf16x8* Ap  = (const bf16x8*)(ATTh + (size_t)(blk * 32 + r0l + c) * 128) + gq;
        const bf16x8* Wp0 = (const bf16x8*)(Wo + (size_t)(cb + c) * 128) + gq;
        const bf16x8* Wp1 = (const bf16x8*)(Wo + (size_t)(cb + 16 + c) * 128) + gq;
        const bf16x8* Wp2 = (const bf16x8*)(Wo + (size_t)(cb + 32 + c) * 128) + gq;
        const bf16x8* Wp3 = (const bf16x8*)(Wo + (size_t)(cb + 48 + c) * 128) + gq;
        f32x4 a0 = zero, a1 = zero, a2 = zero, a3 = zero;
#pragma unroll
        for (int k = 0; k < 4; k++) {
            bf16x8 av = Ap[k * 4];
            a0 = __builtin_amdgcn_mfma_f32_16x16x32_bf16(av, Wp0[k * 4], a0, 0, 0, 0);
            a1 = __builtin_amdgcn_mfma_f32_16x16x32_bf16(av, Wp1[k * 4], a1, 0, 0, 0);
            a2 = __builtin_amdgcn_mfma_f32_16x16x32_bf16(av, Wp2[k * 4], a2, 0, 0, 0);
            a3 = __builtin_amdgcn_mfma_f32_16x16x32_bf16(av, Wp3[k * 4], a3, 0, 0, 0);
        }
        int lrow = r0l + gq * 4;
        float b0 = bo[cb + c], b1v = bo[cb + 16 + c];
        float b2v = bo[cb + 32 + c], b3v = bo[cb + 48 + c];
#pragma unroll
        for (int r = 0; r < 4; r++) {
            S[lrow + r][cb + c] = a0[r] + b0;
            S[lrow + r][cb + 16 + c] = a1[r] + b1v;
            S[lrow + r][cb + 32 + c] = a2[r] + b2v;
            S[lrow + r][cb + 48 + c] = a3[r] + b3v;
        }
    }
    __syncthreads();
    {
        int row = tid >> 3, cg = tid & 7;
        float v[16];
        const float4* rp = (const float4*)(semb + (size_t)(blk * 32 + row) * 128 + cg * 16);
#pragma unroll
        for (int j4 = 0; j4 < 4; j4++) {
            float4 rv = rp[j4];
            v[4 * j4 + 0] = S[row][cg * 16 + 4 * j4 + 0] + rv.x;
            v[4 * j4 + 1] = S[row][cg * 16 + 4 * j4 + 1] + rv.y;
            v[4 * j4 + 2] = S[row][cg * 16 + 4 * j4 + 2] + rv.z;
            v[4 * j4 + 3] = S[row][cg * 16 + 4 * j4 + 3] + rv.w;
        }
        float s = 0.0f;
#pragma unroll
        for (int j = 0; j < 16; j++) s += v[j];
        s += __shfl_xor(s, 1); s += __shfl_xor(s, 2); s += __shfl_xor(s, 4);
        float mean = s * (1.0f / 128.0f);
        float vs = 0.0f;
#pragma unroll
        for (int j = 0; j < 16; j++) { float d = v[j] - mean; vs += d * d; }
        vs += __shfl_xor(vs, 1); vs += __shfl_xor(vs, 2); vs += __shfl_xor(vs, 4);
        float rstd = rsqrtf(vs * (1.0f / 128.0f) + 1e-5f);
#pragma unroll
        for (int j = 0; j < 16; j++) {
            int col = cg * 16 + j;
            s1h[row][col] = (bf16)((v[j] - mean) * rstd * g1[col] + be1[col]);
        }
    }
    __syncthreads();
    {
        bf16x8 afl[4];
#pragma unroll
        for (int k = 0; k < 4; k++)
            afl[k] = *(const bf16x8*)&s1h[r0l + c][k * 32 + gq * 8];
#pragma unroll
        for (int ci = 0; ci < 4; ci++) {
            int cb2 = cb + ci * 128;
            const bf16x8* Wp0 = (const bf16x8*)(W1 + (size_t)(cb2 + c) * 256) + gq;
            const bf16x8* Wp1 = (const bf16x8*)(W1 + (size_t)(cb2 + 16 + c) * 256) + gq;
            const bf16x8* Wp2 = (const bf16x8*)(W1 + (size_t)(cb2 + 32 + c) * 256) + gq;
            const bf16x8* Wp3 = (const bf16x8*)(W1 + (size_t)(cb2 + 48 + c) * 256) + gq;
            f32x4 a0 = zero, a1 = zero, a2 = zero, a3 = zero;
#pragma unroll
            for (int k = 0; k < 8; k++) {
                bf16x8 av = (k < 4) ? afl[k] : agl[k - 4];
                a0 = __builtin_amdgcn_mfma_f32_16x16x32_bf16(av, Wp0[k * 4], a0, 0, 0, 0);
                a1 = __builtin_amdgcn_mfma_f32_16x16x32_bf16(av, Wp1[k * 4], a1, 0, 0, 0);
                a2 = __builtin_amdgcn_mfma_f32_16x16x32_bf16(av, Wp2[k * 4], a2, 0, 0, 0);
                a3 = __builtin_amdgcn_mfma_f32_16x16x32_bf16(av, Wp3[k * 4], a3, 0, 0, 0);
            }
            int lrow = r0l + gq * 4;
#pragma unroll
            for (int r = 0; r < 4; r++) {
                H[lrow + r][cb2 + c]      = (bf16)gelu_f(a0[r] + bf1[cb2 + c]);
                H[lrow + r][cb2 + 16 + c] = (bf16)gelu_f(a1[r] + bf1[cb2 + 16 + c]);
                H[lrow + r][cb2 + 32 + c] = (bf16)gelu_f(a2[r] + bf1[cb2 + 32 + c]);
                H[lrow + r][cb2 + 48 + c] = (bf16)gelu_f(a3[r] + bf1[cb2 + 48 + c]);
            }
        }
    }
    __syncthreads();
    {
        const bf16x8* Wp0 = (const bf16x8*)(W2 + (size_t)(cb + c) * 512) + gq;
        const bf16x8* Wp1 = (const bf16x8*)(W2 + (size_t)(cb + 16 + c) * 512) + gq;
        const bf16x8* Wp2 = (const bf16x8*)(W2 + (size_t)(cb + 32 + c) * 512) + gq;
        const bf16x8* Wp3 = (const bf16x8*)(W2 + (size_t)(cb + 48 + c) * 512) + gq;
        f32x4 a0 = zero, a1 = zero, a2 = zero, a3 = zero;
#pragma unroll
        for (int k = 0; k < 16; k++) {
            bf16x8 av = *(const bf16x8*)&H[r0l + c][k * 32 + gq * 8];
            a0 = __builtin_amdgcn_mfma_f32_16x16x32_bf16(av, Wp0[k * 4], a0, 0, 0, 0);
            a1 = __builtin_amdgcn_mfma_f32_16x16x32_bf16(av, Wp1[k * 4], a1, 0, 0, 0);
            a2 = __builtin_amdgcn_mfma_f32_16x16x32_bf16(av, Wp2[k * 4], a2, 0, 0, 0);
            a3 = __builtin_amdgcn_mfma_f32_16x16x32_bf16(av, Wp3[k * 4], a3, 0, 0, 0);
        }
        int lrow = r0l + gq * 4;
        float b0 = bf2[cb + c], b1v = bf2[cb + 16 + c];
        float b2v = bf2[cb + 32 + c], b3v = bf2[cb + 48 + c];
#pragma unroll
        for (int r = 0; r < 4; r++) {
            S[lrow + r][cb + c] = a0[r] + b0;
            S[lrow + r][cb + 16 + c] = a1[r] + b1v;
            S[lrow + r][cb + 32 + c] = a2[r] + b2v;
            S[lrow + r][cb + 48 + c] = a3[r] + b3v;
        }
    }
    __syncthreads();
    {
        int row = tid >> 3, cg = tid & 7;
        float v[16];
#pragma unroll
        for (int j = 0; j < 16; j++)
            v[j] = S[row][cg * 16 + j] + (float)s1h[row][cg * 16 + j];
        float s = 0.0f;
#pragma unroll
        for (int j = 0; j < 16; j++) s += v[j];
        s += __shfl_xor(s, 1); s += __shfl_xor(s, 2); s += __shfl_xor(s, 4);
        float mean = s * (1.0f / 128.0f);
        float vs = 0.0f;
#pragma unroll
        for (int j = 0; j < 16; j++) { float d = v[j] - mean; vs += d * d; }
        vs += __shfl_xor(vs, 1); vs += __shfl_xor(vs, 2); vs += __shfl_xor(vs, 4);
        float rstd = rsqrtf(vs * (1.0f / 128.0f) + 1e-5f);
        float4* of = (float4*)(outp + (size_t)(blk * 32 + row) * 128 + cg * 16);
#pragma unroll
        for (int j4 = 0; j4 < 4; j4++) {
            float4 o;
#pragma unroll
            for (int e = 0; e < 4; e++) {
                int col = cg * 16 + 4 * j4 + e;
                ((float*)&o)[e] = (v[4 * j4 + e] - mean) * rstd * g2[col] + be2[col];
            }
            of[j4] = o;
        }
    }
}

// ---------------------------------------------------------------------------
// Cross attention (R10-proven v6): 64 q/wave, 4-way key-split, LDS combine.
__global__ __launch_bounds__(256) void k_mattn(
    const bf16* __restrict__ Qh, const bf16* __restrict__ Kh,
    const bf16* __restrict__ Vth, bf16* __restrict__ ATTh,
    int Lq, int Lk, int NSH) {
    int sh = blockIdx.x % NSH;
    int qblk = blockIdx.x / NSH;
    int wv = threadIdx.x >> 6;
    int lane = threadIdx.x & 63;
    int c = lane & 15, g = lane >> 4;
    int q0 = qblk * 64;

    __shared__ float O_lds[4][64][36];
    __shared__ float L_lds[4][64];

    const float scale = 0.17677669529663687f;
    const f32x4 zero = {0, 0, 0, 0};

    bf16x8 bq[4];
#pragma unroll
    for (int qt = 0; qt < 4; qt++)
        bq[qt] = *(const bf16x8*)(
            Qh + ((size_t)sh * Lq + q0 + qt * 16 + c) * 32 + g * 8);

    int klen = Lk >> 2;
    int kbeg = wv * klen;
    const bf16* Kbase = Kh + (size_t)sh * Lk * 32 + (size_t)kbeg * 32;
    const bf16* Vbase = Vth + (size_t)sh * 32 * Lk + kbeg;

    f32x4 oT[4][2];
#pragma unroll
    for (int qt = 0; qt < 4; qt++) { oT[qt][0] = zero; oT[qt][1] = zero; }
    float lsum[4] = {0, 0, 0, 0};

    int ntiles = klen >> 5;
    bf16x8 ka = *(const bf16x8*)(Kbase + (size_t)c * 32 + g * 8);
    bf16x8 kb = *(const bf16x8*)(Kbase + (size_t)(16 + c) * 32 + g * 8);
    bf16x4 va0 = *(const bf16x4*)(Vbase + (size_t)c * Lk + g * 4);
    bf16x4 va1 = *(const bf16x4*)(Vbase + (size_t)c * Lk + 16 + g * 4);
    bf16x4 vb0 = *(const bf16x4*)(Vbase + (size_t)(16 + c) * Lk + g * 4);
    bf16x4 vb1 = *(const bf16x4*)(Vbase + (size_t)(16 + c) * Lk + 16 + g * 4);

    for (int t = 0; t < ntiles; t++) {
        bf16x8 cka = ka, ckb = kb;
        bf16x4 cva0 = va0, cva1 = va1, cvb0 = vb0, cvb1 = vb1;
        int nk0 = ((t + 1 < ntiles) ? (t + 1) : t) << 5;
        ka = *(const bf16x8*)(Kbase + (size_t)(nk0 + c) * 32 + g * 8);
        kb = *(const bf16x8*)(Kbase + (size_t)(nk0 + 16 + c) * 32 + g * 8);
        va0 = *(const bf16x4*)(Vbase + (size_t)c * Lk + nk0 + g * 4);
        va1 = *(const bf16x4*)(Vbase + (size_t)c * Lk + nk0 + 16 + g * 4);
        vb0 = *(const bf16x4*)(Vbase + (size_t)(16 + c) * Lk + nk0 + g * 4);
        vb1 = *(const bf16x4*)(Vbase + (size_t)(16 + c) * Lk + nk0 + 16 + g * 4);

#pragma unroll
        for (int qt = 0; qt < 4; qt++) {
            f32x4 s0 = __builtin_amdgcn_mfma_f32_16x16x32_bf16(cka, bq[qt], zero, 0, 0, 0);
            f32x4 s1 = __builtin_amdgcn_mfma_f32_16x16x32_bf16(ckb, bq[qt], zero, 0, 0, 0);
            bf16x4 p0, p1;
#pragma unroll
            for (int r = 0; r < 4; r++) {
                float e0 = __expf(s0[r] * scale);
                float e1 = __expf(s1[r] * scale);
                lsum[qt] += e0 + e1;
                p0[r] = (bf16)e0;
                p1[r] = (bf16)e1;
            }
            oT[qt][0] = pv_mfma16(cva0, p0, oT[qt][0]);
            oT[qt][0] = pv_mfma16(cva1, p1, oT[qt][0]);
            oT[qt][1] = pv_mfma16(cvb0, p0, oT[qt][1]);
            oT[qt][1] = pv_mfma16(cvb1, p1, oT[qt][1]);
        }
    }

#pragma unroll
    for (int qt = 0; qt < 4; qt++) {
        float s = lsum[qt];
        s += __shfl_xor(s, 16);
        s += __shfl_xor(s, 32);
        if (g == 0) L_lds[wv][qt * 16 + c] = s;
        *(f32x4*)&O_lds[wv][qt * 16 + c][g * 4] = oT[qt][0];
        *(f32x4*)&O_lds[wv][qt * 16 + c][16 + g * 4] = oT[qt][1];
    }
    __syncthreads();

    int tid = threadIdx.x;
    int ql = tid >> 2, dq = (tid & 3) * 8;
    float ltot = L_lds[0][ql] + L_lds[1][ql] + L_lds[2][ql] + L_lds[3][ql];
    float inv = 1.0f / ltot;
    float acc[8];
#pragma unroll
    for (int j = 0; j < 8; j++) acc[j] = 0.0f;
#pragma unroll
    for (int w = 0; w < 4; w++) {
        const float* p = &O_lds[w][ql][dq];
#pragma unroll
        for (int j = 0; j < 8; j++) acc[j] += p[j];
    }
    int h = sh & 3, sb = sh >> 2;
    bf16x8 o;
#pragma unroll
    for (int j = 0; j < 8; j++) o[j] = (bf16)(acc[j] * inv);
    *(bf16x8*)(ATTh + ((size_t)sb * Lq + q0 + ql) * 128 + h * 32 + dq) = o;
}

// ---------------------------------------------------------------------------
extern "C" void kernel_launch(void* const* d_in, const int* in_sizes, int n_in,
                              void* d_out, int out_size, void* d_ws, size_t ws_size,
                              hipStream_t stream) {
    const float* vs       = (const float*)d_in[0];
    const float* semb     = (const float*)d_in[1];
    const float* r5       = (const float*)d_in[2];
    const float* A55      = (const float*)d_in[3];
    const float* bl_bias  = (const float*)d_in[4];
    const float* nl_W1    = (const float*)d_in[5];
    const float* nl_b1    = (const float*)d_in[6];
    const float* nl_W2    = (const float*)d_in[7];
    const float* nl_b2    = (const float*)d_in[8];
    const float* mlp_W1   = (const float*)d_in[9];
    const float* mlp_b1   = (const float*)d_in[10];
    const float* mlp_W2   = (const float*)d_in[11];
    const float* mlp_b2   = (const float*)d_in[12];
    const float* mlp_ln_g = (const float*)d_in[13];
    const float* mlp_ln_b = (const float*)d_in[14];
    const float* enc_qkv_W = (const float*)d_in[15];
    const float* enc_qkv_b = (const float*)d_in[16];
    const float* enc_out_W = (const float*)d_in[17];
    const float* enc_out_b = (const float*)d_in[18];
    const float* enc_ln1_g = (const float*)d_in[19];
    const float* enc_ln1_b = (const float*)d_in[20];
    const float* enc_ff_W1 = (const float*)d_in[21];
    const float* enc_ff_b1 = (const float*)d_in[22];
    const float* enc_ff_W2 = (const float*)d_in[23];
    const float* enc_ff_b2 = (const float*)d_in[24];
    const float* enc_ln2_g = (const float*)d_in[25];
    const float* enc_ln2_b = (const float*)d_in[26];
    const float* ca_Wq = (const float*)d_in[27];
    const float* ca_bq = (const float*)d_in[28];
    const float* ca_Wk = (const float*)d_in[29];
    const float* ca_bk = (const float*)d_in[30];
    const float* ca_Wv = (const float*)d_in[31];
    const float* ca_bv = (const float*)d_in[32];
    const float* ca_Wo = (const float*)d_in[33];
    const float* ca_bo = (const float*)d_in[34];
    const float* ca_ln1_g = (const float*)d_in[35];
    const float* ca_ln1_b = (const float*)d_in[36];
    const float* ca_ff_W1 = (const float*)d_in[37];
    const float* ca_ff_b1 = (const float*)d_in[38];
    const float* ca_ff_W2 = (const float*)d_in[39];
    const float* ca_ff_b2 = (const float*)d_in[40];
    const float* ca_ln2_g = (const float*)d_in[41];
    const float* ca_ln2_b = (const float*)d_in[42];
    float* out = (float*)d_out;

    // Workspace layout (byte offsets, 256-aligned)
    char* base = (char*)d_ws;
    float* b1w   = (float*)(base + 0);          //  32 KB
    float* X0    = (float*)(base + 163840);     //   4 MB
    char*  QKVr  = base + 8552448;              //   6 MB region (cross QKV)
    bf16*  Wpk   = (bf16*) (base + 25329664);   // 1.03 MB
    float* bpk   = (float*)(base + 26411008);   //   1 KB
    bf16*  X0h   = (bf16*) (base + 26412032);   //   2 MB
    bf16*  sembh = (bf16*) (base + 30606336);   //   2 MB
    bf16*  ATTh  = (bf16*) (base + 32703488);   //   2 MB
    bf16*  Qh    = (bf16*)QKVr;                 //   2 MB
    bf16*  Kh    = (bf16*)(QKVr + 2097152);     //   2 MB
    bf16*  Vth   = (bf16*)(QKVr + 4194304);     //   2 MB

    // 1. prep + b1 (merged)
    k_prep_b1<<<dim3(6213), dim3(256), 0, stream>>>(
        enc_qkv_W, enc_out_W, enc_ff_W1, enc_ff_W2, ca_Wq, ca_Wk, ca_Wv, ca_Wo,
        ca_ff_W1, ca_ff_W2, mlp_W2, semb, ca_bk, ca_bv, Wpk, sembh, bpk,
        vs, r5, A55, bl_bias, nl_W1, nl_b1, nl_W2, nl_b2, b1w);

    // 2. features + mlp1 + mlp W2 + gelu + LN + PE (merged)
    k_mlp_ln<<<dim3(256), dim3(256), 0, stream>>>(
        vs, b1w, mlp_W1, mlp_b1, Wpk + 524288, mlp_b2, mlp_ln_g, mlp_ln_b,
        X0, X0h);

    // 3-6. Encoder layers: fused QKV+attention, then fused tail
    for (int i = 0; i < LENC_; i++) {
        k_enc_attn<<<dim3(128), dim3(256), 0, stream>>>(
            X0h, Wpk + i * 49152, enc_qkv_b + i * 384, ATTh);
        k_enc_tail<<<dim3(256), dim3(256), 0, stream>>>(
            ATTh, Wpk + 98304 + i * 16384, enc_out_b + i * 128, X0,
            enc_ln1_g + i * 128, enc_ln1_b + i * 128,
            Wpk + 131072 + i * 32768, enc_ff_b1 + i * 256,
            Wpk + 196608 + i * 32768, enc_ff_b2 + i * 128,
            enc_ln2_g + i * 128, enc_ln2_b + i * 128, X0, X0h);
    }

    // 7-9. Cross: Q+KV -> attention -> fused tail -> out
    k_qkvc<<<dim3(768), dim3(256), 0, stream>>>(
        sembh, Wpk + 262144, ca_bq, X0h, Wpk + 278528, bpk, Qh, Kh, Vth);
    k_mattn<<<dim3(512), dim3(256), 0, stream>>>(
        Qh, Kh, Vth, ATTh, 2048, 2048, 16);
    k_cross_tail<<<dim3(256), dim3(256), 0, stream>>>(
        ATTh, Wpk + 311296, ca_bo, semb, ca_ln1_g, ca_ln1_b, X0h,
        Wpk + 327680, ca_ff_b1, Wpk + 458752, ca_ff_b2,
        ca_ln2_g, ca_ln2_b, out);
}

// Round 14
// 306.133 us; speedup vs baseline: 1.4829x; 1.1013x over previous
//
#include <hip/hip_runtime.h>
#include <math.h>

// Problem constants
#define B_ 4
#define T_ 256
#define N_ 8
#define D_ 128
#define NH_ 4
#define HD_ 32
#define LENC_ 2
#define MLPH_ 32
#define NL_SCALE_ 0.1f

typedef __bf16 bf16;
typedef __attribute__((ext_vector_type(2))) __bf16 bf16x2;
typedef __attribute__((ext_vector_type(4))) __bf16 bf16x4;
typedef __attribute__((ext_vector_type(8))) __bf16 bf16x8;
typedef __attribute__((ext_vector_type(4))) float f32x4;

__device__ __forceinline__ f32x4 pv_mfma16(bf16x4 a, bf16x4 b, f32x4 c) {
#if __has_builtin(__builtin_amdgcn_mfma_f32_16x16x16_bf16)
    return __builtin_amdgcn_mfma_f32_16x16x16_bf16(a, b, c, 0, 0, 0);
#else
    typedef __attribute__((ext_vector_type(4))) short s4;
    union U { bf16x4 h; s4 s; };
    U ua, ub; ua.h = a; ub.h = b;
    return __builtin_amdgcn_mfma_f32_16x16x16bf16_1k(ua.s, ub.s, c, 0, 0, 0);
#endif
}

__device__ __forceinline__ float gelu_f(float x) {
    return 0.5f * x * (1.0f + erff(x * 0.7071067811865476f));
}

// ---------------------------------------------------------------------------
// Merged prep (blocks 0..6208) + b1 baseline (blocks 6209..6212).
__global__ void k_prep_b1(const float* __restrict__ eqkvW, const float* __restrict__ eoutW,
                          const float* __restrict__ eff1, const float* __restrict__ eff2,
                          const float* __restrict__ wq, const float* __restrict__ wk,
                          const float* __restrict__ wv, const float* __restrict__ wo,
                          const float* __restrict__ cff1, const float* __restrict__ cff2,
                          const float* __restrict__ mlpW2, const float* __restrict__ semb,
                          const float* __restrict__ bk, const float* __restrict__ bv,
                          bf16* __restrict__ Wpk, bf16* __restrict__ sembh,
                          float* __restrict__ bpk,
                          const float* __restrict__ vs, const float* __restrict__ r5,
                          const float* __restrict__ A55, const float* __restrict__ bl_bias,
                          const float* __restrict__ nlW1, const float* __restrict__ nlb1,
                          const float* __restrict__ nlW2, const float* __restrict__ nlb2,
                          float* __restrict__ b1w) {
    if (blockIdx.x < 6209) {
        int i = blockIdx.x * 256 + threadIdx.x;
        if (i < 540672) {
            const float* src; int off;
            if      (i < 98304)  { src = eqkvW; off = 0; }
            else if (i < 131072) { src = eoutW; off = 98304; }
            else if (i < 196608) { src = eff1;  off = 131072; }
            else if (i < 262144) { src = eff2;  off = 196608; }
            else if (i < 278528) { src = wq;    off = 262144; }
            else if (i < 294912) { src = wk;    off = 278528; }
            else if (i < 311296) { src = wv;    off = 294912; }
            else if (i < 327680) { src = wo;    off = 311296; }
            else if (i < 458752) { src = cff1;  off = 327680; }
            else if (i < 524288) { src = cff2;  off = 458752; }
            else                 { src = mlpW2; off = 524288; }
            Wpk[i] = (bf16)src[i - off];
        } else if (i < 540672 + 1048576) {
            int j = i - 540672;
            sembh[j] = (bf16)semb[j];
        } else if (i < 540672 + 1048576 + 256) {
            int t = i - 540672 - 1048576;
            bpk[t] = (t < 128) ? bk[t] : bv[t - 128];
        }
        return;
    }
    int idx = (blockIdx.x - 6209) * 256 + threadIdx.x;
    if (idx >= B_ * (T_ - 1)) return;
    int b = idx / (T_ - 1), t = idx % (T_ - 1);
    float x[N_];
    for (int n = 0; n < N_; n++) x[n] = vs[(b * T_ + t) * N_ + n];
    float h[MLPH_];
    for (int j = 0; j < MLPH_; j++) {
        float a = nlb1[j];
        for (int n = 0; n < N_; n++) a += x[n] * nlW1[j * N_ + n];
        h[j] = gelu_f(a);
    }
    for (int m = 0; m < N_; m++) {
        float lin = r5[m];
        for (int n = 0; n < N_; n++) lin += x[n] * A55[m * N_ + n];
        float nl = nlb2[m];
        for (int j = 0; j < MLPH_; j++) nl += h[j] * nlW2[m * MLPH_ + j];
        b1w[idx * N_ + m] = lin + NL_SCALE_ * nl + bl_bias[m];
    }
}

// ---------------------------------------------------------------------------
// Fused: features + mlp1 + W2 GEMM + gelu + LN + PE + transpose write.
// 16 rows/block, grid = 512 (2 blocks/CU).
__global__ __launch_bounds__(256) void k_mlp_ln(
    const float* __restrict__ vs, const float* __restrict__ b1w,
    const float* __restrict__ W1, const float* __restrict__ b1,
    const bf16* __restrict__ W2, const float* __restrict__ bias,
    const float* __restrict__ g, const float* __restrict__ be,
    float* __restrict__ outf, bf16* __restrict__ outh) {
    __shared__ float F[16][16];
    __shared__ bf16 H1[16][136];
    __shared__ float S[16][132];
    int tid = threadIdx.x;
    int blk = blockIdx.x;
    // Phase 0a: one feature per thread (16 rows x 16 feats)
    {
        int row = tid >> 4, feat = tid & 15;
        int grow = blk * 16 + row;
        int b = grow >> 11, t = (grow >> 3) & 255, n = grow & 7;
        const int SC[4] = {1, 2, 3, 5};
        int lag = feat >> 2, si = feat & 3, k = SC[si];
        int tp = t - lag;
        float r = 0.0f;
        if (tp >= 0 && tp < T_ - k) {
            float lx0 = logf(fmaxf(vs[(b * T_ + tp) * N_ + n], 1e-6f));
            float lx1 = logf(fmaxf(vs[(b * T_ + tp + k) * N_ + n], 1e-6f));
            float a = lx1 - lx0;
            a = fminf(fmaxf(a, -2.5f * (float)k), 2.0f * (float)k);
            float bk = 0.0f;
            for (int i = 0; i < k; i++) bk += b1w[(b * (T_ - 1) + tp + i) * N_ + n];
            r = a - bk;
        }
        F[row][feat] = r;
    }
    __syncthreads();
    // Phase 0b: H1[row][d] = gelu(b1[d] + F[row] . W1[d]); 8 cols/thread
    {
        int row = tid >> 4, cg = tid & 15;
        float f[16];
#pragma unroll
        for (int c = 0; c < 16; c++) f[c] = F[row][c];
#pragma unroll
        for (int j = 0; j < 8; j++) {
            int d = cg * 8 + j;
            float a = b1[d];
            const float* w = W1 + d * 16;
#pragma unroll
            for (int c = 0; c < 16; c++) a += f[c] * w[c];
            H1[row][d] = (bf16)gelu_f(a);
        }
    }
    __syncthreads();
    // Phase 1: GEMM (K=128, N=128). Wave wv: rows 0..15, cols wv*32 (2 tiles).
    int w = tid >> 6, lane = tid & 63;
    int c = lane & 15, gq = lane >> 4;
    int cb = w * 32;
    const f32x4 zero = {0, 0, 0, 0};
    {
        const bf16x8* Wp0 = (const bf16x8*)(W2 + (size_t)(cb + c) * 128) + gq;
        const bf16x8* Wp1 = (const bf16x8*)(W2 + (size_t)(cb + 16 + c) * 128) + gq;
        f32x4 a0 = zero, a1 = zero;
#pragma unroll
        for (int k = 0; k < 4; k++) {
            bf16x8 av = *(const bf16x8*)&H1[c][k * 32 + gq * 8];
            a0 = __builtin_amdgcn_mfma_f32_16x16x32_bf16(av, Wp0[k * 4], a0, 0, 0, 0);
            a1 = __builtin_amdgcn_mfma_f32_16x16x32_bf16(av, Wp1[k * 4], a1, 0, 0, 0);
        }
#pragma unroll
        for (int r = 0; r < 4; r++) {
            S[gq * 4 + r][cb + c]      = gelu_f(a0[r] + bias[cb + c]);
            S[gq * 4 + r][cb + 16 + c] = gelu_f(a1[r] + bias[cb + 16 + c]);
        }
    }
    __syncthreads();
    // Epilogue: LN + PE, transpose write. 16 threads/row, 8 cols each.
    {
        int row = tid >> 4, cg = tid & 15;
        int grow = blk * 16 + row;
        int b = grow >> 11, t = (grow >> 3) & 255, n = grow & 7;
        int orow = (b * 8 + n) * 256 + t;
        float v[8];
#pragma unroll
        for (int j = 0; j < 8; j++) v[j] = S[row][cg * 8 + j];
        float s = 0.0f;
#pragma unroll
        for (int j = 0; j < 8; j++) s += v[j];
        s += __shfl_xor(s, 1); s += __shfl_xor(s, 2);
        s += __shfl_xor(s, 4); s += __shfl_xor(s, 8);
        float mean = s * (1.0f / 128.0f);
        float vs2 = 0.0f;
#pragma unroll
        for (int j = 0; j < 8; j++) { float d = v[j] - mean; vs2 += d * d; }
        vs2 += __shfl_xor(vs2, 1); vs2 += __shfl_xor(vs2, 2);
        vs2 += __shfl_xor(vs2, 4); vs2 += __shfl_xor(vs2, 8);
        float rstd = rsqrtf(vs2 * (1.0f / 128.0f) + 1e-5f);
        float y[8];
#pragma unroll
        for (int j = 0; j < 8; j++) {
            int col = cg * 8 + j;
            y[j] = (v[j] - mean) * rstd * g[col] + be[col];
        }
#pragma unroll
        for (int jj = 0; jj < 4; jj++) {
            int j2 = cg * 4 + jj;            // pair index = col>>1
            float freq = expf((float)(2 * j2) * (-9.210340371976184f / 128.0f));
            float ang = (float)t * freq;
            y[2 * jj] += sinf(ang);
            y[2 * jj + 1] += cosf(ang);
        }
        float4* of = (float4*)(outf + (size_t)orow * 128 + cg * 8);
        of[0] = (float4){y[0], y[1], y[2], y[3]};
        of[1] = (float4){y[4], y[5], y[6], y[7]};
        bf16x8 o;
#pragma unroll
        for (int e = 0; e < 8; e++) o[e] = (bf16)y[e];
        *(bf16x8*)(outh + (size_t)orow * 128 + cg * 8) = o;
    }
}

// ---------------------------------------------------------------------------
// Fused encoder QKV + attention v2: block = (seq-head, query-half).
// Block computes full K/V slice + its 128-query Q slice into LDS, then
// chain-free attention (wave = 32 q x 256 keys). grid = 256, 256 thr.
__global__ __launch_bounds__(256) void k_enc_attn(
    const bf16* __restrict__ X0h, const bf16* __restrict__ Wqkv,
    const float* __restrict__ bqkv, bf16* __restrict__ ATTh) {
    int sh = blockIdx.x & 127;
    int qh = blockIdx.x >> 7;       // query half 0/1
    int s = sh >> 2, h = sh & 3;
    __shared__ bf16 Ql[128][40];
    __shared__ bf16 Kl[256][40];
    __shared__ bf16 Vt[32][264];
    int tid = threadIdx.x;
    int wv = tid >> 6, lane = tid & 63;
    int c = lane & 15, g = lane >> 4;
    const f32x4 zero = {0, 0, 0, 0};

    const bf16* Wq0 = Wqkv + (size_t)(h * 32 + c) * 128;
    const bf16* Wq1 = Wqkv + (size_t)(h * 32 + 16 + c) * 128;
    const bf16* Wk0 = Wqkv + (size_t)(128 + h * 32 + c) * 128;
    const bf16* Wk1 = Wqkv + (size_t)(128 + h * 32 + 16 + c) * 128;
    const bf16* Wv0 = Wqkv + (size_t)(256 + h * 32 + c) * 128;
    const bf16* Wv1 = Wqkv + (size_t)(256 + h * 32 + 16 + c) * 128;
    float bq0 = bqkv[h * 32 + c], bq1 = bqkv[h * 32 + 16 + c];
    float bk0 = bqkv[128 + h * 32 + c], bk1 = bqkv[128 + h * 32 + 16 + c];
    float bv0 = bqkv[256 + h * 32 + c], bv1 = bqkv[256 + h * 32 + 16 + c];

    // Phase 1a: K+V for all 256 keys (wave wv: rows wv*64..+63)
#pragma unroll
    for (int rb = 0; rb < 4; rb++) {
        int row0 = wv * 64 + rb * 16;
        const bf16x8* Ap = (const bf16x8*)(X0h + (size_t)(s * 256 + row0 + c) * 128) + g;
        f32x4 ak0 = zero, ak1 = zero, av0 = zero, av1 = zero;
#pragma unroll
        for (int k = 0; k < 4; k++) {
            bf16x8 av = Ap[k * 4];
            ak0 = __builtin_amdgcn_mfma_f32_16x16x32_bf16(av, *((const bf16x8*)Wk0 + k * 4 + g), ak0, 0, 0, 0);
            ak1 = __builtin_amdgcn_mfma_f32_16x16x32_bf16(av, *((const bf16x8*)Wk1 + k * 4 + g), ak1, 0, 0, 0);
            av0 = __builtin_amdgcn_mfma_f32_16x16x32_bf16(av, *((const bf16x8*)Wv0 + k * 4 + g), av0, 0, 0, 0);
            av1 = __builtin_amdgcn_mfma_f32_16x16x32_bf16(av, *((const bf16x8*)Wv1 + k * 4 + g), av1, 0, 0, 0);
        }
        int lr = row0 + g * 4;
#pragma unroll
        for (int i = 0; i < 4; i++) {
            Kl[lr + i][c] = (bf16)(ak0[i] + bk0);
            Kl[lr + i][16 + c] = (bf16)(ak1[i] + bk1);
            Vt[c][lr + i] = (bf16)(av0[i] + bv0);
            Vt[16 + c][lr + i] = (bf16)(av1[i] + bv1);
        }
    }
    // Phase 1b: Q for this block's 128 queries (wave wv: rows wv*32..+31)
#pragma unroll
    for (int qb = 0; qb < 2; qb++) {
        int row0q = wv * 32 + qb * 16;
        const bf16x8* Ap = (const bf16x8*)(
            X0h + (size_t)(s * 256 + qh * 128 + row0q + c) * 128) + g;
        f32x4 aq0 = zero, aq1 = zero;
#pragma unroll
        for (int k = 0; k < 4; k++) {
            bf16x8 av = Ap[k * 4];
            aq0 = __builtin_amdgcn_mfma_f32_16x16x32_bf16(av, *((const bf16x8*)Wq0 + k * 4 + g), aq0, 0, 0, 0);
            aq1 = __builtin_amdgcn_mfma_f32_16x16x32_bf16(av, *((const bf16x8*)Wq1 + k * 4 + g), aq1, 0, 0, 0);
        }
        int lr = row0q + g * 4;
#pragma unroll
        for (int i = 0; i < 4; i++) {
            Ql[lr + i][c] = (bf16)(aq0[i] + bq0);
            Ql[lr + i][16 + c] = (bf16)(aq1[i] + bq1);
        }
    }
    __syncthreads();

    // Phase 2: attention. Wave wv: 32 queries (2 q-tiles), 8 k-tiles.
    const float scale = 0.17677669529663687f;  // 1/sqrt(32)
    int q0l = wv * 32;
    bf16x8 bq[2];
#pragma unroll
    for (int qt = 0; qt < 2; qt++)
        bq[qt] = *(const bf16x8*)&Ql[q0l + qt * 16 + c][g * 8];
    f32x4 oT[2][2];
#pragma unroll
    for (int qt = 0; qt < 2; qt++) { oT[qt][0] = zero; oT[qt][1] = zero; }
    float lsum[2] = {0, 0};
#pragma unroll
    for (int t = 0; t < 8; t++) {
        int k0 = t * 32;
        bf16x8 ka = *(const bf16x8*)&Kl[k0 + c][g * 8];
        bf16x8 kb = *(const bf16x8*)&Kl[k0 + 16 + c][g * 8];
        bf16x4 va0 = *(const bf16x4*)&Vt[c][k0 + g * 4];
        bf16x4 va1 = *(const bf16x4*)&Vt[c][k0 + 16 + g * 4];
        bf16x4 vb0 = *(const bf16x4*)&Vt[16 + c][k0 + g * 4];
        bf16x4 vb1 = *(const bf16x4*)&Vt[16 + c][k0 + 16 + g * 4];
#pragma unroll
        for (int qt = 0; qt < 2; qt++) {
            f32x4 s0 = __builtin_amdgcn_mfma_f32_16x16x32_bf16(ka, bq[qt], zero, 0, 0, 0);
            f32x4 s1 = __builtin_amdgcn_mfma_f32_16x16x32_bf16(kb, bq[qt], zero, 0, 0, 0);
            bf16x4 p0, p1;
#pragma unroll
            for (int r = 0; r < 4; r++) {
                float e0 = __expf(s0[r] * scale);
                float e1 = __expf(s1[r] * scale);
                lsum[qt] += e0 + e1;
                p0[r] = (bf16)e0;
                p1[r] = (bf16)e1;
            }
            oT[qt][0] = pv_mfma16(va0, p0, oT[qt][0]);
            oT[qt][0] = pv_mfma16(va1, p1, oT[qt][0]);
            oT[qt][1] = pv_mfma16(vb0, p0, oT[qt][1]);
            oT[qt][1] = pv_mfma16(vb1, p1, oT[qt][1]);
        }
    }
#pragma unroll
    for (int qt = 0; qt < 2; qt++) {
        float sm = lsum[qt];
        sm += __shfl_xor(sm, 16);
        sm += __shfl_xor(sm, 32);
        float inv = 1.0f / sm;
        size_t rbase = ((size_t)s * 256 + qh * 128 + q0l + qt * 16 + c) * 128 + h * 32;
#pragma unroll
        for (int r = 0; r < 4; r++) {
            ATTh[rbase + g * 4 + r] = (bf16)(oT[qt][0][r] * inv);
            ATTh[rbase + 16 + g * 4 + r] = (bf16)(oT[qt][1][r] * inv);
        }
    }
}

// ---------------------------------------------------------------------------
// Wide MFMA GEMM body for cross Q/KV scatter modes (R11-proven).
__device__ __forceinline__ void gemm4_body(
    int bid, const bf16* __restrict__ A, const bf16* __restrict__ W,
    const float* __restrict__ bias, bf16* __restrict__ dq,
    bf16* __restrict__ dk, bf16* __restrict__ dvv, int N, int K, int mode) {
    int lane = threadIdx.x & 63;
    int wv = threadIdx.x >> 6;
    int c = lane & 15, g = lane >> 4;
    int nN = N >> 6;
    int tn = bid % nN, tm = bid / nN;
    int row0 = tm * 64 + wv * 16;
    int cb = tn * 64;

    const bf16x8* Ap  = (const bf16x8*)(A + (size_t)(row0 + c) * K) + g;
    const bf16x8* Wp0 = (const bf16x8*)(W + (size_t)(cb + c) * K) + g;
    const bf16x8* Wp1 = (const bf16x8*)(W + (size_t)(cb + 16 + c) * K) + g;
    const bf16x8* Wp2 = (const bf16x8*)(W + (size_t)(cb + 32 + c) * K) + g;
    const bf16x8* Wp3 = (const bf16x8*)(W + (size_t)(cb + 48 + c) * K) + g;
    f32x4 a0 = {0, 0, 0, 0}, a1 = {0, 0, 0, 0};
    f32x4 a2 = {0, 0, 0, 0}, a3 = {0, 0, 0, 0};
    int nk = K >> 5;
    for (int k = 0; k < nk; k++) {
        bf16x8 av = Ap[k * 4];
        a0 = __builtin_amdgcn_mfma_f32_16x16x32_bf16(av, Wp0[k * 4], a0, 0, 0, 0);
        a1 = __builtin_amdgcn_mfma_f32_16x16x32_bf16(av, Wp1[k * 4], a1, 0, 0, 0);
        a2 = __builtin_amdgcn_mfma_f32_16x16x32_bf16(av, Wp2[k * 4], a2, 0, 0, 0);
        a3 = __builtin_amdgcn_mfma_f32_16x16x32_bf16(av, Wp3[k * 4], a3, 0, 0, 0);
    }
    int rowb = row0 + g * 4;
#pragma unroll
    for (int ct = 0; ct < 4; ct++) {
        f32x4 acc = (ct == 0) ? a0 : (ct == 1) ? a1 : (ct == 2) ? a2 : a3;
        int col = cb + ct * 16 + c;
        float bvv = bias[col];
#pragma unroll
        for (int i = 0; i < 4; i++) {
            float v = acc[i] + bvv;
            int row = rowb + i;
            if (mode == 2) {
                int b = row >> 11, ll = row & 2047;
                int hh = col >> 5, d = col & 31;
                dq[((size_t)(b * 4 + hh) * 2048 + ll) * 32 + d] = (bf16)v;
            } else {
                int b = row >> 11, n = (row >> 8) & 7, t = row & 255;
                int ll = t * 8 + n;
                int hh = (col >> 5) & 3, d = col & 31;
                if (col < 128) dk[((size_t)(b * 4 + hh) * 2048 + ll) * 32 + d] = (bf16)v;
                else           dvv[((size_t)(b * 4 + hh) * 32 + d) * 2048 + ll] = (bf16)v;
            }
        }
    }
}

// Cross Q-proj (blocks 0..255) + KV-proj (blocks 256..767) in one dispatch.
__global__ __launch_bounds__(256) void k_qkvc(
    const bf16* __restrict__ sembh, const bf16* __restrict__ Wq,
    const float* __restrict__ bq, const bf16* __restrict__ X0h,
    const bf16* __restrict__ Wkv, const float* __restrict__ bkv,
    bf16* __restrict__ Qh, bf16* __restrict__ Kh, bf16* __restrict__ Vth) {
    if (blockIdx.x < 256)
        gemm4_body(blockIdx.x, sembh, Wq, bq, Qh, nullptr, nullptr, 128, 128, 2);
    else
        gemm4_body(blockIdx.x - 256, X0h, Wkv, bkv, nullptr, Kh, Vth, 256, 128, 3);
}

// ---------------------------------------------------------------------------
// Encoder tail v2: 16 rows/block, grid 512. Wave wv: rows 0..15, col strips.
__global__ __launch_bounds__(256) void k_enc_tail(
    const bf16* __restrict__ ATTh, const bf16* __restrict__ Wo,
    const float* __restrict__ bo, const float* __restrict__ X0res,
    const float* __restrict__ g1, const float* __restrict__ be1,
    const bf16* __restrict__ W1, const float* __restrict__ bf1,
    const bf16* __restrict__ W2, const float* __restrict__ bf2,
    const float* __restrict__ g2, const float* __restrict__ be2,
    float* __restrict__ X0out, bf16* __restrict__ X0hout) {
    __shared__ float S[16][132];
    __shared__ float X1f[16][132];
    __shared__ bf16 X1h[16][136];
    __shared__ bf16 H[16][264];
    int tid = threadIdx.x;
    int w = tid >> 6, lane = tid & 63;
    int c = lane & 15, gq = lane >> 4;
    int blk = blockIdx.x;
    const f32x4 zero = {0, 0, 0, 0};

    // Phase 1: outproj (K=128, N=128). Wave wv cols w*32 (2 tiles).
    {
        int cb = w * 32;
        const bf16x8* Ap  = (const bf16x8*)(ATTh + (size_t)(blk * 16 + c) * 128) + gq;
        const bf16x8* Wp0 = (const bf16x8*)(Wo + (size_t)(cb + c) * 128) + gq;
        const bf16x8* Wp1 = (const bf16x8*)(Wo + (size_t)(cb + 16 + c) * 128) + gq;
        f32x4 a0 = zero, a1 = zero;
#pragma unroll
        for (int k = 0; k < 4; k++) {
            bf16x8 av = Ap[k * 4];
            a0 = __builtin_amdgcn_mfma_f32_16x16x32_bf16(av, Wp0[k * 4], a0, 0, 0, 0);
            a1 = __builtin_amdgcn_mfma_f32_16x16x32_bf16(av, Wp1[k * 4], a1, 0, 0, 0);
        }
#pragma unroll
        for (int r = 0; r < 4; r++) {
            S[gq * 4 + r][cb + c] = a0[r] + bo[cb + c];
            S[gq * 4 + r][cb + 16 + c] = a1[r] + bo[cb + 16 + c];
        }
    }
    __syncthreads();
    // Epilogue 1: + X0 residual, LN1 -> X1f + X1h (16 thr/row, 8 cols)
    {
        int row = tid >> 4, cg = tid & 15;
        float v[8];
        const float4* rp = (const float4*)(X0res + (size_t)(blk * 16 + row) * 128 + cg * 8);
        float4 r0 = rp[0], r1 = rp[1];
        v[0] = S[row][cg * 8 + 0] + r0.x; v[1] = S[row][cg * 8 + 1] + r0.y;
        v[2] = S[row][cg * 8 + 2] + r0.z; v[3] = S[row][cg * 8 + 3] + r0.w;
        v[4] = S[row][cg * 8 + 4] + r1.x; v[5] = S[row][cg * 8 + 5] + r1.y;
        v[6] = S[row][cg * 8 + 6] + r1.z; v[7] = S[row][cg * 8 + 7] + r1.w;
        float s = 0.0f;
#pragma unroll
        for (int j = 0; j < 8; j++) s += v[j];
        s += __shfl_xor(s, 1); s += __shfl_xor(s, 2);
        s += __shfl_xor(s, 4); s += __shfl_xor(s, 8);
        float mean = s * (1.0f / 128.0f);
        float vs = 0.0f;
#pragma unroll
        for (int j = 0; j < 8; j++) { float d = v[j] - mean; vs += d * d; }
        vs += __shfl_xor(vs, 1); vs += __shfl_xor(vs, 2);
        vs += __shfl_xor(vs, 4); vs += __shfl_xor(vs, 8);
        float rstd = rsqrtf(vs * (1.0f / 128.0f) + 1e-5f);
#pragma unroll
        for (int j = 0; j < 8; j++) {
            int col = cg * 8 + j;
            float y = (v[j] - mean) * rstd * g1[col] + be1[col];
            X1f[row][col] = y;
            X1h[row][col] = (bf16)y;
        }
    }
    __syncthreads();
    // Phase 2: ff1 (K=128, N=256). Wave wv cols w*64 (4 tiles).
    {
        int cb2 = w * 64;
        bf16x8 af[4];
#pragma unroll
        for (int k = 0; k < 4; k++)
            af[k] = *(const bf16x8*)&X1h[c][k * 32 + gq * 8];
        const bf16x8* Wp0 = (const bf16x8*)(W1 + (size_t)(cb2 + c) * 128) + gq;
        const bf16x8* Wp1 = (const bf16x8*)(W1 + (size_t)(cb2 + 16 + c) * 128) + gq;
        const bf16x8* Wp2 = (const bf16x8*)(W1 + (size_t)(cb2 + 32 + c) * 128) + gq;
        const bf16x8* Wp3 = (const bf16x8*)(W1 + (size_t)(cb2 + 48 + c) * 128) + gq;
        f32x4 a0 = zero, a1 = zero, a2 = zero, a3 = zero;
#pragma unroll
        for (int k = 0; k < 4; k++) {
            a0 = __builtin_amdgcn_mfma_f32_16x16x32_bf16(af[k], Wp0[k * 4], a0, 0, 0, 0);
            a1 = __builtin_amdgcn_mfma_f32_16x16x32_bf16(af[k], Wp1[k * 4], a1, 0, 0, 0);
            a2 = __builtin_amdgcn_mfma_f32_16x16x32_bf16(af[k], Wp2[k * 4], a2, 0, 0, 0);
            a3 = __builtin_amdgcn_mfma_f32_16x16x32_bf16(af[k], Wp3[k * 4], a3, 0, 0, 0);
        }
#pragma unroll
        for (int r = 0; r < 4; r++) {
            H[gq * 4 + r][cb2 + c]      = (bf16)gelu_f(a0[r] + bf1[cb2 + c]);
            H[gq * 4 + r][cb2 + 16 + c] = (bf16)gelu_f(a1[r] + bf1[cb2 + 16 + c]);
            H[gq * 4 + r][cb2 + 32 + c] = (bf16)gelu_f(a2[r] + bf1[cb2 + 32 + c]);
            H[gq * 4 + r][cb2 + 48 + c] = (bf16)gelu_f(a3[r] + bf1[cb2 + 48 + c]);
        }
    }
    __syncthreads();
    // Phase 3: ff2 (K=256, N=128). Wave wv cols w*32 (2 tiles).
    {
        int cb = w * 32;
        bf16x8 af[8];
#pragma unroll
        for (int k = 0; k < 8; k++)
            af[k] = *(const bf16x8*)&H[c][k * 32 + gq * 8];
        const bf16x8* Wp0 = (const bf16x8*)(W2 + (size_t)(cb + c) * 256) + gq;
        const bf16x8* Wp1 = (const bf16x8*)(W2 + (size_t)(cb + 16 + c) * 256) + gq;
        f32x4 a0 = zero, a1 = zero;
#pragma unroll
        for (int k = 0; k < 8; k++) {
            a0 = __builtin_amdgcn_mfma_f32_16x16x32_bf16(af[k], Wp0[k * 4], a0, 0, 0, 0);
            a1 = __builtin_amdgcn_mfma_f32_16x16x32_bf16(af[k], Wp1[k * 4], a1, 0, 0, 0);
        }
#pragma unroll
        for (int r = 0; r < 4; r++) {
            S[gq * 4 + r][cb + c] = a0[r] + bf2[cb + c];
            S[gq * 4 + r][cb + 16 + c] = a1[r] + bf2[cb + 16 + c];
        }
    }
    __syncthreads();
    // Epilogue 3: + X1 residual, LN2 -> global
    {
        int row = tid >> 4, cg = tid & 15;
        float v[8];
#pragma unroll
        for (int j = 0; j < 8; j++)
            v[j] = S[row][cg * 8 + j] + X1f[row][cg * 8 + j];
        float s = 0.0f;
#pragma unroll
        for (int j = 0; j < 8; j++) s += v[j];
        s += __shfl_xor(s, 1); s += __shfl_xor(s, 2);
        s += __shfl_xor(s, 4); s += __shfl_xor(s, 8);
        float mean = s * (1.0f / 128.0f);
        float vs = 0.0f;
#pragma unroll
        for (int j = 0; j < 8; j++) { float d = v[j] - mean; vs += d * d; }
        vs += __shfl_xor(vs, 1); vs += __shfl_xor(vs, 2);
        vs += __shfl_xor(vs, 4); vs += __shfl_xor(vs, 8);
        float rstd = rsqrtf(vs * (1.0f / 128.0f) + 1e-5f);
        size_t grow = (size_t)(blk * 16 + row);
        float y[8];
#pragma unroll
        for (int j = 0; j < 8; j++) {
            int col = cg * 8 + j;
            y[j] = (v[j] - mean) * rstd * g2[col] + be2[col];
        }
        float4* of = (float4*)(X0out + grow * 128 + cg * 8);
        of[0] = (float4){y[0], y[1], y[2], y[3]};
        of[1] = (float4){y[4], y[5], y[6], y[7]};
        bf16x8 o;
#pragma unroll
        for (int e = 0; e < 8; e++) o[e] = (bf16)y[e];
        *(bf16x8*)(X0hout + grow * 128 + cg * 8) = o;
    }
}

// ---------------------------------------------------------------------------
// Cross tail v2: 16 rows/block, grid 512.
__global__ __launch_bounds__(256) void k_cross_tail(
    const bf16* __restrict__ ATTh, const bf16* __restrict__ Wo,
    const float* __restrict__ bo, const float* __restrict__ semb,
    const float* __restrict__ g1, const float* __restrict__ be1,
    const bf16* __restrict__ X0h, const bf16* __restrict__ W1,
    const float* __restrict__ bf1, const bf16* __restrict__ W2,
    const float* __restrict__ bf2, const float* __restrict__ g2,
    const float* __restrict__ be2, float* __restrict__ outp) {
    __shared__ float S[16][132];
    __shared__ bf16 s1h[16][136];
    __shared__ bf16 H[16][520];
    int tid = threadIdx.x;
    int w = tid >> 6, lane = tid & 63;
    int c = lane & 15, gq = lane >> 4;
    int blk = blockIdx.x;
    const f32x4 zero = {0, 0, 0, 0};

    // Prefetch CAT second-half A-frags from X0h (xt-order remap)
    bf16x8 agl[4];
    {
        int tr = blk * 16 + c;
        int b = tr >> 11, t = (tr >> 3) & 255, n = tr & 7;
        const bf16* xrow = X0h + ((size_t)((b * 8 + n) * 256 + t)) * 128;
#pragma unroll
        for (int k = 0; k < 4; k++)
            agl[k] = *(const bf16x8*)(xrow + k * 32 + gq * 8);
    }

    // Phase 1: outproj (K=128, N=128). Wave wv cols w*32.
    {
        int cb = w * 32;
        const bf16x8* Ap  = (const bf16x8*)(ATTh + (size_t)(blk * 16 + c) * 128) + gq;
        const bf16x8* Wp0 = (const bf16x8*)(Wo + (size_t)(cb + c) * 128) + gq;
        const bf16x8* Wp1 = (const bf16x8*)(Wo + (size_t)(cb + 16 + c) * 128) + gq;
        f32x4 a0 = zero, a1 = zero;
#pragma unroll
        for (int k = 0; k < 4; k++) {
            bf16x8 av = Ap[k * 4];
            a0 = __builtin_amdgcn_mfma_f32_16x16x32_bf16(av, Wp0[k * 4], a0, 0, 0, 0);
            a1 = __builtin_amdgcn_mfma_f32_16x16x32_bf16(av, Wp1[k * 4], a1, 0, 0, 0);
        }
#pragma unroll
        for (int r = 0; r < 4; r++) {
            S[gq * 4 + r][cb + c] = a0[r] + bo[cb + c];
            S[gq * 4 + r][cb + 16 + c] = a1[r] + bo[cb + 16 + c];
        }
    }
    __syncthreads();
    // Epilogue 1: + semb residual, LN1 -> s1h
    {
        int row = tid >> 4, cg = tid & 15;
        float v[8];
        const float4* rp = (const float4*)(semb + (size_t)(blk * 16 + row) * 128 + cg * 8);
        float4 r0 = rp[0], r1 = rp[1];
        v[0] = S[row][cg * 8 + 0] + r0.x; v[1] = S[row][cg * 8 + 1] + r0.y;
        v[2] = S[row][cg * 8 + 2] + r0.z; v[3] = S[row][cg * 8 + 3] + r0.w;
        v[4] = S[row][cg * 8 + 4] + r1.x; v[5] = S[row][cg * 8 + 5] + r1.y;
        v[6] = S[row][cg * 8 + 6] + r1.z; v[7] = S[row][cg * 8 + 7] + r1.w;
        float s = 0.0f;
#pragma unroll
        for (int j = 0; j < 8; j++) s += v[j];
        s += __shfl_xor(s, 1); s += __shfl_xor(s, 2);
        s += __shfl_xor(s, 4); s += __shfl_xor(s, 8);
        float mean = s * (1.0f / 128.0f);
        float vs = 0.0f;
#pragma unroll
        for (int j = 0; j < 8; j++) { float d = v[j] - mean; vs += d * d; }
        vs += __shfl_xor(vs, 1); vs += __shfl_xor(vs, 2);
        vs += __shfl_xor(vs, 4); vs += __shfl_xor(vs, 8);
        float rstd = rsqrtf(vs * (1.0f / 128.0f) + 1e-5f);
#pragma unroll
        for (int j = 0; j < 8; j++) {
            int col = cg * 8 + j;
            s1h[row][col] = (bf16)((v[j] - mean) * rstd * g1[col] + be1[col]);
        }
    }
    __syncthreads();
    // Phase 2: ff1 (K=256 concat, N=512). Wave wv cols w*128 (2x4 tiles).
    {
        bf16x8 afl[4];
#pragma unroll
        for (int k = 0; k < 4; k++)
            afl[k] = *(const bf16x8*)&s1h[c][k * 32 + gq * 8];
#pragma unroll
        for (int ci = 0; ci < 2; ci++) {
            int cb2 = w * 128 + ci * 64;
            const bf16x8* Wp0 = (const bf16x8*)(W1 + (size_t)(cb2 + c) * 256) + gq;
            const bf16x8* Wp1 = (const bf16x8*)(W1 + (size_t)(cb2 + 16 + c) * 256) + gq;
            const bf16x8* Wp2 = (const bf16x8*)(W1 + (size_t)(cb2 + 32 + c) * 256) + gq;
            const bf16x8* Wp3 = (const bf16x8*)(W1 + (size_t)(cb2 + 48 + c) * 256) + gq;
            f32x4 a0 = zero, a1 = zero, a2 = zero, a3 = zero;
#pragma unroll
            for (int k = 0; k < 8; k++) {
                bf16x8 av = (k < 4) ? afl[k] : agl[k - 4];
                a0 = __builtin_amdgcn_mfma_f32_16x16x32_bf16(av, Wp0[k * 4], a0, 0, 0, 0);
                a1 = __builtin_amdgcn_mfma_f32_16x16x32_bf16(av, Wp1[k * 4], a1, 0, 0, 0);
                a2 = __builtin_amdgcn_mfma_f32_16x16x32_bf16(av, Wp2[k * 4], a2, 0, 0, 0);
                a3 = __builtin_amdgcn_mfma_f32_16x16x32_bf16(av, Wp3[k * 4], a3, 0, 0, 0);
            }
#pragma unroll
            for (int r = 0; r < 4; r++) {
                H[gq * 4 + r][cb2 + c]      = (bf16)gelu_f(a0[r] + bf1[cb2 + c]);
                H[gq * 4 + r][cb2 + 16 + c] = (bf16)gelu_f(a1[r] + bf1[cb2 + 16 + c]);
                H[gq * 4 + r][cb2 + 32 + c] = (bf16)gelu_f(a2[r] + bf1[cb2 + 32 + c]);
                H[gq * 4 + r][cb2 + 48 + c] = (bf16)gelu_f(a3[r] + bf1[cb2 + 48 + c]);
            }
        }
    }
    __syncthreads();
    // Phase 3: ff2 (K=512, N=128). Wave wv cols w*32 (2 tiles).
    {
        int cb = w * 32;
        const bf16x8* Wp0 = (const bf16x8*)(W2 + (size_t)(cb + c) * 512) + gq;
        const bf16x8* Wp1 = (const bf16x8*)(W2 + (size_t)(cb + 16 + c) * 512) + gq;
        f32x4 a0 = zero, a1 = zero;
#pragma unroll
        for (int k = 0; k < 16; k++) {
            bf16x8 av = *(const bf16x8*)&H[c][k * 32 + gq * 8];
            a0 = __builtin_amdgcn_mfma_f32_16x16x32_bf16(av, Wp0[k * 4], a0, 0, 0, 0);
            a1 = __builtin_amdgcn_mfma_f32_16x16x32_bf16(av, Wp1[k * 4], a1, 0, 0, 0);
        }
#pragma unroll
        for (int r = 0; r < 4; r++) {
            S[gq * 4 + r][cb + c] = a0[r] + bf2[cb + c];
            S[gq * 4 + r][cb + 16 + c] = a1[r] + bf2[cb + 16 + c];
        }
    }
    __syncthreads();
    // Epilogue 3: + s1 residual, final LN -> outp
    {
        int row = tid >> 4, cg = tid & 15;
        float v[8];
#pragma unroll
        for (int j = 0; j < 8; j++)
            v[j] = S[row][cg * 8 + j] + (float)s1h[row][cg * 8 + j];
        float s = 0.0f;
#pragma unroll
        for (int j = 0; j < 8; j++) s += v[j];
        s += __shfl_xor(s, 1); s += __shfl_xor(s, 2);
        s += __shfl_xor(s, 4); s += __shfl_xor(s, 8);
        float mean = s * (1.0f / 128.0f);
        float vs = 0.0f;
#pragma unroll
        for (int j = 0; j < 8; j++) { float d = v[j] - mean; vs += d * d; }
        vs += __shfl_xor(vs, 1); vs += __shfl_xor(vs, 2);
        vs += __shfl_xor(vs, 4); vs += __shfl_xor(vs, 8);
        float rstd = rsqrtf(vs * (1.0f / 128.0f) + 1e-5f);
        float y[8];
#pragma unroll
        for (int j = 0; j < 8; j++) {
            int col = cg * 8 + j;
            y[j] = (v[j] - mean) * rstd * g2[col] + be2[col];
        }
        float4* of = (float4*)(outp + (size_t)(blk * 16 + (tid >> 4)) * 128 + cg * 8);
        of[0] = (float4){y[0], y[1], y[2], y[3]};
        of[1] = (float4){y[4], y[5], y[6], y[7]};
    }
}

// ---------------------------------------------------------------------------
// Cross attention (R10-proven v6): 64 q/wave, 4-way key-split, LDS combine.
__global__ __launch_bounds__(256) void k_mattn(
    const bf16* __restrict__ Qh, const bf16* __restrict__ Kh,
    const bf16* __restrict__ Vth, bf16* __restrict__ ATTh,
    int Lq, int Lk, int NSH) {
    int sh = blockIdx.x % NSH;
    int qblk = blockIdx.x / NSH;
    int wv = threadIdx.x >> 6;
    int lane = threadIdx.x & 63;
    int c = lane & 15, g = lane >> 4;
    int q0 = qblk * 64;

    __shared__ float O_lds[4][64][36];
    __shared__ float L_lds[4][64];

    const float scale = 0.17677669529663687f;
    const f32x4 zero = {0, 0, 0, 0};

    bf16x8 bq[4];
#pragma unroll
    for (int qt = 0; qt < 4; qt++)
        bq[qt] = *(const bf16x8*)(
            Qh + ((size_t)sh * Lq + q0 + qt * 16 + c) * 32 + g * 8);

    int klen = Lk >> 2;
    int kbeg = wv * klen;
    const bf16* Kbase = Kh + (size_t)sh * Lk * 32 + (size_t)kbeg * 32;
    const bf16* Vbase = Vth + (size_t)sh * 32 * Lk + kbeg;

    f32x4 oT[4][2];
#pragma unroll
    for (int qt = 0; qt < 4; qt++) { oT[qt][0] = zero; oT[qt][1] = zero; }
    float lsum[4] = {0, 0, 0, 0};

    int ntiles = klen >> 5;
    bf16x8 ka = *(const bf16x8*)(Kbase + (size_t)c * 32 + g * 8);
    bf16x8 kb = *(const bf16x8*)(Kbase + (size_t)(16 + c) * 32 + g * 8);
    bf16x4 va0 = *(const bf16x4*)(Vbase + (size_t)c * Lk + g * 4);
    bf16x4 va1 = *(const bf16x4*)(Vbase + (size_t)c * Lk + 16 + g * 4);
    bf16x4 vb0 = *(const bf16x4*)(Vbase + (size_t)(16 + c) * Lk + g * 4);
    bf16x4 vb1 = *(const bf16x4*)(Vbase + (size_t)(16 + c) * Lk + 16 + g * 4);

    for (int t = 0; t < ntiles; t++) {
        bf16x8 cka = ka, ckb = kb;
        bf16x4 cva0 = va0, cva1 = va1, cvb0 = vb0, cvb1 = vb1;
        int nk0 = ((t + 1 < ntiles) ? (t + 1) : t) << 5;
        ka = *(const bf16x8*)(Kbase + (size_t)(nk0 + c) * 32 + g * 8);
        kb = *(const bf16x8*)(Kbase + (size_t)(nk0 + 16 + c) * 32 + g * 8);
        va0 = *(const bf16x4*)(Vbase + (size_t)c * Lk + nk0 + g * 4);
        va1 = *(const bf16x4*)(Vbase + (size_t)c * Lk + nk0 + 16 + g * 4);
        vb0 = *(const bf16x4*)(Vbase + (size_t)(16 + c) * Lk + nk0 + g * 4);
        vb1 = *(const bf16x4*)(Vbase + (size_t)(16 + c) * Lk + nk0 + 16 + g * 4);

#pragma unroll
        for (int qt = 0; qt < 4; qt++) {
            f32x4 s0 = __builtin_amdgcn_mfma_f32_16x16x32_bf16(cka, bq[qt], zero, 0, 0, 0);
            f32x4 s1 = __builtin_amdgcn_mfma_f32_16x16x32_bf16(ckb, bq[qt], zero, 0, 0, 0);
            bf16x4 p0, p1;
#pragma unroll
            for (int r = 0; r < 4; r++) {
                float e0 = __expf(s0[r] * scale);
                float e1 = __expf(s1[r] * scale);
                lsum[qt] += e0 + e1;
                p0[r] = (bf16)e0;
                p1[r] = (bf16)e1;
            }
            oT[qt][0] = pv_mfma16(cva0, p0, oT[qt][0]);
            oT[qt][0] = pv_mfma16(cva1, p1, oT[qt][0]);
            oT[qt][1] = pv_mfma16(cvb0, p0, oT[qt][1]);
            oT[qt][1] = pv_mfma16(cvb1, p1, oT[qt][1]);
        }
    }

#pragma unroll
    for (int qt = 0; qt < 4; qt++) {
        float s = lsum[qt];
        s += __shfl_xor(s, 16);
        s += __shfl_xor(s, 32);
        if (g == 0) L_lds[wv][qt * 16 + c] = s;
        *(f32x4*)&O_lds[wv][qt * 16 + c][g * 4] = oT[qt][0];
        *(f32x4*)&O_lds[wv][qt * 16 + c][16 + g * 4] = oT[qt][1];
    }
    __syncthreads();

    int tid = threadIdx.x;
    int ql = tid >> 2, dq = (tid & 3) * 8;
    float ltot = L_lds[0][ql] + L_lds[1][ql] + L_lds[2][ql] + L_lds[3][ql];
    float inv = 1.0f / ltot;
    float acc[8];
#pragma unroll
    for (int j = 0; j < 8; j++) acc[j] = 0.0f;
#pragma unroll
    for (int w = 0; w < 4; w++) {
        const float* p = &O_lds[w][ql][dq];
#pragma unroll
        for (int j = 0; j < 8; j++) acc[j] += p[j];
    }
    int h = sh & 3, sb = sh >> 2;
    bf16x8 o;
#pragma unroll
    for (int j = 0; j < 8; j++) o[j] = (bf16)(acc[j] * inv);
    *(bf16x8*)(ATTh + ((size_t)sb * Lq + q0 + ql) * 128 + h * 32 + dq) = o;
}

// ---------------------------------------------------------------------------
extern "C" void kernel_launch(void* const* d_in, const int* in_sizes, int n_in,
                              void* d_out, int out_size, void* d_ws, size_t ws_size,
                              hipStream_t stream) {
    const float* vs       = (const float*)d_in[0];
    const float* semb     = (const float*)d_in[1];
    const float* r5       = (const float*)d_in[2];
    const float* A55      = (const float*)d_in[3];
    const float* bl_bias  = (const float*)d_in[4];
    const float* nl_W1    = (const float*)d_in[5];
    const float* nl_b1    = (const float*)d_in[6];
    const float* nl_W2    = (const float*)d_in[7];
    const float* nl_b2    = (const float*)d_in[8];
    const float* mlp_W1   = (const float*)d_in[9];
    const float* mlp_b1   = (const float*)d_in[10];
    const float* mlp_W2   = (const float*)d_in[11];
    const float* mlp_b2   = (const float*)d_in[12];
    const float* mlp_ln_g = (const float*)d_in[13];
    const float* mlp_ln_b = (const float*)d_in[14];
    const float* enc_qkv_W = (const float*)d_in[15];
    const float* enc_qkv_b = (const float*)d_in[16];
    const float* enc_out_W = (const float*)d_in[17];
    const float* enc_out_b = (const float*)d_in[18];
    const float* enc_ln1_g = (const float*)d_in[19];
    const float* enc_ln1_b = (const float*)d_in[20];
    const float* enc_ff_W1 = (const float*)d_in[21];
    const float* enc_ff_b1 = (const float*)d_in[22];
    const float* enc_ff_W2 = (const float*)d_in[23];
    const float* enc_ff_b2 = (const float*)d_in[24];
    const float* enc_ln2_g = (const float*)d_in[25];
    const float* enc_ln2_b = (const float*)d_in[26];
    const float* ca_Wq = (const float*)d_in[27];
    const float* ca_bq = (const float*)d_in[28];
    const float* ca_Wk = (const float*)d_in[29];
    const float* ca_bk = (const float*)d_in[30];
    const float* ca_Wv = (const float*)d_in[31];
    const float* ca_bv = (const float*)d_in[32];
    const float* ca_Wo = (const float*)d_in[33];
    const float* ca_bo = (const float*)d_in[34];
    const float* ca_ln1_g = (const float*)d_in[35];
    const float* ca_ln1_b = (const float*)d_in[36];
    const float* ca_ff_W1 = (const float*)d_in[37];
    const float* ca_ff_b1 = (const float*)d_in[38];
    const float* ca_ff_W2 = (const float*)d_in[39];
    const float* ca_ff_b2 = (const float*)d_in[40];
    const float* ca_ln2_g = (const float*)d_in[41];
    const float* ca_ln2_b = (const float*)d_in[42];
    float* out = (float*)d_out;

    // Workspace layout (byte offsets, 256-aligned)
    char* base = (char*)d_ws;
    float* b1w   = (float*)(base + 0);          //  32 KB
    float* X0    = (float*)(base + 163840);     //   4 MB
    char*  QKVr  = base + 8552448;              //   6 MB region (cross QKV)
    bf16*  Wpk   = (bf16*) (base + 25329664);   // 1.03 MB
    float* bpk   = (float*)(base + 26411008);   //   1 KB
    bf16*  X0h   = (bf16*) (base + 26412032);   //   2 MB
    bf16*  sembh = (bf16*) (base + 30606336);   //   2 MB
    bf16*  ATTh  = (bf16*) (base + 32703488);   //   2 MB
    bf16*  Qh    = (bf16*)QKVr;                 //   2 MB
    bf16*  Kh    = (bf16*)(QKVr + 2097152);     //   2 MB
    bf16*  Vth   = (bf16*)(QKVr + 4194304);     //   2 MB

    // 1. prep + b1 (merged)
    k_prep_b1<<<dim3(6213), dim3(256), 0, stream>>>(
        enc_qkv_W, enc_out_W, enc_ff_W1, enc_ff_W2, ca_Wq, ca_Wk, ca_Wv, ca_Wo,
        ca_ff_W1, ca_ff_W2, mlp_W2, semb, ca_bk, ca_bv, Wpk, sembh, bpk,
        vs, r5, A55, bl_bias, nl_W1, nl_b1, nl_W2, nl_b2, b1w);

    // 2. features + mlp1 + mlp W2 + gelu + LN + PE (merged, 512 blocks)
    k_mlp_ln<<<dim3(512), dim3(256), 0, stream>>>(
        vs, b1w, mlp_W1, mlp_b1, Wpk + 524288, mlp_b2, mlp_ln_g, mlp_ln_b,
        X0, X0h);

    // 3-6. Encoder layers: fused QKV+attention (256 blocks), fused tail (512)
    for (int i = 0; i < LENC_; i++) {
        k_enc_attn<<<dim3(256), dim3(256), 0, stream>>>(
            X0h, Wpk + i * 49152, enc_qkv_b + i * 384, ATTh);
        k_enc_tail<<<dim3(512), dim3(256), 0, stream>>>(
            ATTh, Wpk + 98304 + i * 16384, enc_out_b + i * 128, X0,
            enc_ln1_g + i * 128, enc_ln1_b + i * 128,
            Wpk + 131072 + i * 32768, enc_ff_b1 + i * 256,
            Wpk + 196608 + i * 32768, enc_ff_b2 + i * 128,
            enc_ln2_g + i * 128, enc_ln2_b + i * 128, X0, X0h);
    }

    // 7-9. Cross: Q+KV -> attention -> fused tail (512 blocks) -> out
    k_qkvc<<<dim3(768), dim3(256), 0, stream>>>(
        sembh, Wpk + 262144, ca_bq, X0h, Wpk + 278528, bpk, Qh, Kh, Vth);
    k_mattn<<<dim3(512), dim3(256), 0, stream>>>(
        Qh, Kh, Vth, ATTh, 2048, 2048, 16);
    k_cross_tail<<<dim3(512), dim3(256), 0, stream>>>(
        ATTh, Wpk + 311296, ca_bo, semb, ca_ln1_g, ca_ln1_b, X0h,
        Wpk + 327680, ca_ff_b1, Wpk + 458752, ca_ff_b2,
        ca_ln2_g, ca_ln2_b, out);
}